// Round 4
// baseline (345.168 us; speedup 1.0000x reference)
//
#include <hip/hip_runtime.h>
#include <math.h>

#define VN 9
#define NVOX 131072
#define GS 96
static constexpr float INVS = 0.9999950000374997f; // 1/sqrt(1+1e-5)

typedef short bf16x8 __attribute__((ext_vector_type(8)));
typedef float f32x4v __attribute__((ext_vector_type(4)));

__device__ inline float4 ld4(const float* p){ return *reinterpret_cast<const float4*>(p); }

__device__ inline ushort f2b(float f){
  unsigned u = __float_as_uint(f);
  unsigned r = (u + 0x7fffu + ((u >> 16) & 1u)) >> 16;
  return (ushort)r;
}
__device__ inline float b2f(ushort s){ return __uint_as_float(((unsigned)s) << 16); }
__device__ inline float blo(unsigned u){ return __uint_as_float(u << 16); }
__device__ inline float bhi(unsigned u){ return __uint_as_float(u & 0xffff0000u); }

__device__ inline float4 ld4b(const ushort* p){
  uint2 u = *reinterpret_cast<const uint2*>(p);
  float4 r; r.x = blo(u.x); r.y = bhi(u.x); r.z = blo(u.y); r.w = bhi(u.y); return r;
}
__device__ inline void st4b(ushort* p, float4 v){
  uint2 u;
  u.x = (unsigned)f2b(v.x) | ((unsigned)f2b(v.y) << 16);
  u.y = (unsigned)f2b(v.z) | ((unsigned)f2b(v.w) << 16);
  *reinterpret_cast<uint2*>(p) = u;
}

// ---- weight prep helpers ----
__device__ inline void wprep2_dev(const float* __restrict__ w, ushort* __restrict__ o,
                                  int Cout, int Cin, int K, int CK, int CoutPad, int tid){
  int ci32 = tid & 31;
  int co = (tid >> 5) % CoutPad;
  int ck = (tid / (32*CoutPad)) % CK;
  int tap = tid / (32*CoutPad*CK);
  int ci = ck*32 + ci32;
  float v = 0.f;
  if (co < Cout && ci < Cin) v = w[(size_t)(co*Cin + ci)*K*K + tap];
  o[tid] = f2b(v);
}
__device__ inline void wprep_dev(const float* __restrict__ w, ushort* __restrict__ o, int tid){
  int k = tid >> 10;
  int r = tid & 1023;
  int co = r >> 5;
  int ci = r & 31;
  o[tid] = f2b(w[k*1024 + ci*32 + co]);
}

// ---- NCHW fp32 -> NHWC bf16 via LDS tile ----
__device__ inline void nhwc_tile_dev(const float* __restrict__ in, ushort* __restrict__ out,
                                     int C, int Cpad, int HW, int tile, int tilesPerV,
                                     float* lds, int tx){
  int v  = tile / tilesPerV;
  int p0 = (tile - v*tilesPerV) * 64;
  const float* ip = in + (size_t)v*C*HW + p0;
  int iters = Cpad >> 2;
  for (int i = 0; i < iters; ++i){
    int idx = i*256 + tx;
    int c = idx >> 6;
    int p = idx & 63;
    float val = 0.f;
    if (c < C && (p0 + p) < HW) val = ip[(size_t)c*HW + p];
    lds[c*65 + p] = val;
  }
  __syncthreads();
  int groups = Cpad >> 2;
  int tot = 64*groups;
  for (int basei = 0; basei < tot; basei += 256){
    int idx = basei + tx;
    if (idx < tot){
      int g  = idx % groups;
      int px = idx / groups;
      if ((p0 + px) < HW){
        float4 r;
        r.x = lds[(g*4+0)*65 + px];
        r.y = lds[(g*4+1)*65 + px];
        r.z = lds[(g*4+2)*65 + px];
        r.w = lds[(g*4+3)*65 + px];
        st4b(out + (size_t)(v*HW + p0 + px)*Cpad + g*4, r);
      }
    }
  }
}

// ---- mega prep kernel: weight preps + grid clear + NHWC transposes ----
__global__ __launch_bounds__(256) void k_prep(
    const float* wf1s, const float* wf2s, const float* wf4s, const float* wdns,
    const float* wp0s, const float* wp1s, const float* wp2s, const float* wp3s,
    const float* wes, const float* ws1s, const float* ws2s, const float* ws3s,
    ushort* wf1, ushort* wf2, ushort* wf4, ushort* wdn,
    ushort* wp0, ushort* wp1, ushort* wp2, ushort* wp3,
    ushort* w2e, ushort* w2s1, ushort* w2s2, ushort* w2s3,
    int* grid,
    const float* f1, const float* f2, const float* f4,
    ushort* o1, ushort* o2, ushort* o4){
  __shared__ float lds[96*65];
  int bid = blockIdx.x;
  int tx = threadIdx.x;
  if (bid < 270){ int t = bid*256+tx; if (t < 69120) wprep2_dev(wf1s, wf1, 80, 80, 3, 3, 80, t); return; }
  bid -= 270;
  if (bid < 108){ int t = bid*256+tx; if (t < 27648) wprep2_dev(wf2s, wf2, 40, 40, 3, 2, 48, t); return; }
  bid -= 108;
  if (bid < 36){ int t = bid*256+tx; if (t < 9216) wprep2_dev(wf4s, wf4, 24, 24, 3, 1, 32, t); return; }
  bid -= 36;
  if (bid < 20){ int t = bid*256+tx; if (t < 5120) wprep2_dev(wdns, wdn, 32, 144, 1, 5, 32, t); return; }
  bid -= 20;
  if (bid < 36){ int t = bid*256+tx; if (t < 9216) wprep2_dev(wp0s, wp0, 32, 32, 3, 1, 32, t); return; }
  bid -= 36;
  if (bid < 36){ int t = bid*256+tx; if (t < 9216) wprep2_dev(wp1s, wp1, 32, 32, 3, 1, 32, t); return; }
  bid -= 36;
  if (bid < 36){ int t = bid*256+tx; if (t < 9216) wprep2_dev(wp2s, wp2, 32, 32, 3, 1, 32, t); return; }
  bid -= 36;
  if (bid < 36){ int t = bid*256+tx; if (t < 9216) wprep2_dev(wp3s, wp3, 32, 32, 3, 1, 32, t); return; }
  bid -= 36;
  if (bid < 108){ int t = bid*256+tx; if (t < 27648) wprep_dev(wes, w2e, t); return; }
  bid -= 108;
  if (bid < 108){ int t = bid*256+tx; if (t < 27648) wprep_dev(ws1s, w2s1, t); return; }
  bid -= 108;
  if (bid < 108){ int t = bid*256+tx; if (t < 27648) wprep_dev(ws2s, w2s2, t); return; }
  bid -= 108;
  if (bid < 108){ int t = bid*256+tx; if (t < 27648) wprep_dev(ws3s, w2s3, t); return; }
  bid -= 108;
  if (bid < 3456){ int t = bid*256+tx; if (t < GS*GS*GS) grid[t] = -1; return; }
  bid -= 3456;
  if (bid < 171){ nhwc_tile_dev(f1, o1, 80, 96, 1200, bid, 19, lds, tx); return; }
  bid -= 171;
  if (bid < 675){ nhwc_tile_dev(f2, o2, 40, 64, 4800, bid, 75, lds, tx); return; }
  bid -= 675;
  if (bid < 2700){ nhwc_tile_dev(f4, o4, 24, 32, 19200, bid, 300, lds, tx); }
}

// ---- implicit-GEMM conv via MFMA, register path (for f1/f2/1x1) ----
// Operand-swapped: mfma(Bf, Af) -> D[row=co(q*4+r)][col=px(m)]; epilogue
// stores 4 consecutive channels per lane as one uint2.
template<int CK, int NT, int TAPS, int MT>
__device__ void conv_dev(
    const ushort* __restrict__ fin, const ushort* __restrict__ w2,
    const float* __restrict__ bias, ushort* __restrict__ outp,
    int H, int W, int total, int Cout, int outStride, int outOff,
    int bid, int tid){
  constexpr int CIN = CK*32;
  constexpr int COP = NT*16;
  int lane = tid & 63;
  int wave = tid >> 6;
  int vbase = bid*(MT*64) + wave*(MT*16);
  int m = lane & 15, q = lane >> 4;
  int HW = H*W;
  int p[MT], py[MT], px[MT]; bool pin[MT];
  #pragma unroll
  for (int t = 0; t < MT; ++t){
    int pp = vbase + t*16 + m;
    pin[t] = pp < total;
    if (pp > total-1) pp = total-1;
    p[t] = pp;
    int v = pp / HW; int rem = pp - v*HW;
    int y = rem / W;
    py[t] = y; px[t] = rem - y*W;
  }
  f32x4v acc[MT][NT];
  #pragma unroll
  for (int t = 0; t < MT; ++t)
    #pragma unroll
    for (int n = 0; n < NT; ++n) acc[t][n] = 0.f;
  bf16x8 z = (short)0;

  #pragma unroll 1
  for (int tap = 0; tap < TAPS; ++tap){
    int dy = (TAPS == 9) ? tap/3 - 1 : 0;
    int dx = (TAPS == 9) ? tap%3 - 1 : 0;
    int off = dy*W + dx;
    bool val[MT];
    #pragma unroll
    for (int t = 0; t < MT; ++t)
      val[t] = pin[t] && ((unsigned)(py[t]+dy) < (unsigned)H)
                      && ((unsigned)(px[t]+dx) < (unsigned)W);
    #pragma unroll
    for (int ck = 0; ck < CK; ++ck){
      bf16x8 Af[MT], Bf[NT];
      #pragma unroll
      for (int t = 0; t < MT; ++t){
        size_t idx = val[t] ? (size_t)(p[t]+off) : 0;
        bf16x8 a = *(const bf16x8*)(fin + idx*CIN + ck*32 + q*8);
        Af[t] = val[t] ? a : z;
      }
      #pragma unroll
      for (int n = 0; n < NT; ++n)
        Bf[n] = *(const bf16x8*)(w2 + ((size_t)((tap*CK+ck)*COP + n*16 + m))*32 + q*8);
      #pragma unroll
      for (int t = 0; t < MT; ++t)
        #pragma unroll
        for (int n = 0; n < NT; ++n)
          acc[t][n] = __builtin_amdgcn_mfma_f32_16x16x32_bf16(Bf[n], Af[t], acc[t][n], 0, 0, 0);
    }
  }

  #pragma unroll
  for (int n = 0; n < NT; ++n){
    int co4 = n*16 + q*4;
    bool cok = co4 < Cout;   // all Couts are multiples of 4
    float4 bs = cok ? ld4(bias + co4) : float4{0.f,0.f,0.f,0.f};
    #pragma unroll
    for (int t = 0; t < MT; ++t){
      int pp = vbase + t*16 + m;
      if (pp < total && cok){
        float4 v;
        v.x = fmaxf(acc[t][n][0] + bs.x, 0.f);
        v.y = fmaxf(acc[t][n][1] + bs.y, 0.f);
        v.z = fmaxf(acc[t][n][2] + bs.z, 0.f);
        v.w = fmaxf(acc[t][n][3] + bs.w, 0.f);
        st4b(outp + (size_t)pp*outStride + outOff + co4, v);
      }
    }
  }
}

template<int CK, int NT, int TAPS, int MT>
__global__ __launch_bounds__(256) void k_conv_mfma(
    const ushort* __restrict__ fin, const ushort* __restrict__ w2,
    const float* __restrict__ bias, ushort* __restrict__ outp,
    int H, int W, int total, int Cout, int outStride, int outOff){
  conv_dev<CK,NT,TAPS,MT>(fin, w2, bias, outp, H, W, total, Cout, outStride, outOff,
                          blockIdx.x, threadIdx.x);
}

// ---- LDS-tiled 3x3 conv, CIN=32. Tile TH x 16 px, halo patch (TH+2)x18x36 in LDS.
// Operand-swapped MFMA; uint2 stores/skip-loads.
template<int TH, int NT>
__device__ void conv_lds_dev(
    const ushort* __restrict__ fin, const ushort* __restrict__ w2,
    const float* __restrict__ bias, ushort* __restrict__ outp,
    int H, int W, int Cout, int outStride,
    const ushort* __restrict__ skipin, ushort* lds, int bid, int tid){
  constexpr int RPW = TH/4;
  constexpr int PS = 36;             // padded channel stride (18 banks -> 2-way free)
  int xtiles = W >> 4;
  int ytiles = (H + TH - 1) / TH;
  int v  = bid / (ytiles*xtiles);
  int rem = bid - v*(ytiles*xtiles);
  int ty = (rem / xtiles) * TH;
  int tx = (rem % xtiles) * 16;
  const ushort* ibase = fin + (size_t)v*H*W*32;
  // load halo patch (TH+2) x 18 x 32ch
  for (int i = tid; i < (TH+2)*18*4; i += 256){
    int chunk = i & 3;
    int pxi = i >> 2;
    int ly = pxi / 18, lx = pxi - ly*18;
    int gy = ty + ly - 1, gx = tx + lx - 1;
    uint4 d = {0,0,0,0};
    if ((unsigned)gy < (unsigned)H && (unsigned)gx < (unsigned)W)
      d = *(const uint4*)(ibase + ((size_t)gy*W + gx)*32 + chunk*8);
    *(uint4*)(lds + (size_t)(ly*18 + lx)*PS + chunk*8) = d;
  }
  __syncthreads();
  int lane = tid & 63;
  int wave = tid >> 6;
  int m = lane & 15, q = lane >> 4;
  f32x4v acc[RPW][NT];
  #pragma unroll
  for (int t = 0; t < RPW; ++t)
    #pragma unroll
    for (int n = 0; n < NT; ++n) acc[t][n] = 0.f;

  #pragma unroll 1
  for (int tap = 0; tap < 9; ++tap){
    int dy = tap/3 - 1, dx = tap%3 - 1;
    bf16x8 Af[RPW], Bf[NT];
    #pragma unroll
    for (int t = 0; t < RPW; ++t){
      int ly = wave*RPW + t + 1 + dy;
      int lx = m + 1 + dx;
      Af[t] = *(const bf16x8*)(lds + (size_t)(ly*18 + lx)*PS + q*8);
    }
    #pragma unroll
    for (int n = 0; n < NT; ++n)
      Bf[n] = *(const bf16x8*)(w2 + ((size_t)(tap*(NT*16) + n*16 + m))*32 + q*8);
    #pragma unroll
    for (int t = 0; t < RPW; ++t)
      #pragma unroll
      for (int n = 0; n < NT; ++n)
        acc[t][n] = __builtin_amdgcn_mfma_f32_16x16x32_bf16(Bf[n], Af[t], acc[t][n], 0, 0, 0);
  }

  // epilogue: lane m = px-in-tile, acc[t][n][r] = channel n*16+q*4+r
  #pragma unroll
  for (int n = 0; n < NT; ++n){
    int co4 = n*16 + q*4;
    bool cok = co4 < Cout;
    float4 bs = cok ? ld4(bias + co4) : float4{0.f,0.f,0.f,0.f};
    #pragma unroll
    for (int t = 0; t < RPW; ++t){
      int y = ty + wave*RPW + t;
      int x = tx + m;
      if (y < H && cok){
        size_t pp = (size_t)(v*H + y)*W + x;
        float4 val;
        val.x = fmaxf(acc[t][n][0] + bs.x, 0.f);
        val.y = fmaxf(acc[t][n][1] + bs.y, 0.f);
        val.z = fmaxf(acc[t][n][2] + bs.z, 0.f);
        val.w = fmaxf(acc[t][n][3] + bs.w, 0.f);
        if (skipin){
          float4 sk = ld4b(skipin + pp*32 + co4);
          val.x += sk.x; val.y += sk.y; val.z += sk.z; val.w += sk.w;
        }
        st4b(outp + pp*outStride + co4, val);
      }
    }
  }
}

// chain conv: TH=4 -> patch 6x18x36 = 7.8 KB, 675 blocks
__global__ __launch_bounds__(256) void k_conv_lds4(
    const ushort* __restrict__ fin, const ushort* __restrict__ w2,
    const float* __restrict__ bias, ushort* __restrict__ outp,
    const ushort* __restrict__ skipin){
  __shared__ ushort lds[6*18*36];
  conv_lds_dev<4,2>(fin, w2, bias, outp, 60, 80, 32, 32, skipin, lds, blockIdx.x, threadIdx.x);
}

// ---- scatter device: grid scatter + coords + count (samp recomputed in k_sample) ----
__device__ void scatter_dev(const int* __restrict__ coords, const int* __restrict__ stage,
                            int* __restrict__ grid, int* __restrict__ scn,
                            float* __restrict__ coords_out,
                            const float* __restrict__ origin, const float* __restrict__ vsz,
                            const float* __restrict__ KR,
                            float* __restrict__ cnt, int n){
  int c0 = coords[n*4], c1 = coords[n*4+1], c2 = coords[n*4+2], c3 = coords[n*4+3];
  coords_out[n*4+0] = (float)c0;
  coords_out[n*4+1] = (float)c1;
  coords_out[n*4+2] = (float)c2;
  coords_out[n*4+3] = (float)c3;
  int sh = 2 - stage[0];
  int s1 = c1 >> sh, s2 = c2 >> sh, s3 = c3 >> sh;
  scn[n*3+0] = s1; scn[n*3+1] = s2; scn[n*3+2] = s3;
  grid[(s1*GS + s2)*GS + s3] = n;

  float vs = vsz[0];
  float wx = (float)c1*vs + origin[0];
  float wy = (float)c2*vs + origin[1];
  float wz = (float)c3*vs + origin[2];
  float den = 0.f;
  #pragma unroll 1
  for (int v = 0; v < VN; ++v){
    const float* P = KR + v*12;
    float ix = P[0]*wx + P[1]*wy + P[2]*wz + P[3];
    float iy = P[4]*wx + P[5]*wy + P[6]*wz + P[7];
    float iz = P[8]*wx + P[9]*wy + P[10]*wz + P[11];
    float gx = 2.f*(ix/iz)/159.f - 1.f;
    float gy = 2.f*(iy/iz)/119.f - 1.f;
    bool ok = (fabsf(gx) <= 1.f) && (fabsf(gy) <= 1.f) && (iz > 0.f);
    den += ok ? 1.f : 0.f;
  }
  cnt[n] = den;
}

// ---- merged: f1 conv (169) + f4 LDS conv (720) + f2 conv (675) + scatter (512) ----
__global__ __launch_bounds__(256) void k_heads(
    const ushort* nhwc1, const ushort* wf1, const float* b_f1, ushort* t1,
    const ushort* nhwc2, const ushort* wf2, const float* b_f2, ushort* fcat,
    const ushort* nhwc4, const ushort* wf4, const float* b_f4, ushort* t4,
    const int* coords, const int* stage, int* grid, int* scn, float* coords_out,
    const float* origin, const float* vsz, const float* KR, float* cnt){
  __shared__ ushort lds[18*18*36];
  int bid = blockIdx.x;
  int tid = threadIdx.x;
  if (bid < 169){ conv_dev<3,5,9,1>(nhwc1, wf1, b_f1, t1, 30, 40, 10800, 80, 80, 0, bid, tid); return; }
  bid -= 169;
  if (bid < 720){ conv_lds_dev<16,2>(nhwc4, wf4, b_f4, t4, 120, 160, 24, 24, nullptr, lds, bid, tid); return; }
  bid -= 720;
  if (bid < 675){ conv_dev<2,3,9,1>(nhwc2, wf2, b_f2, fcat, 60, 80, 43200, 40, 160, 80, bid, tid); return; }
  bid -= 675;
  { int n = bid*256 + tid;
    scatter_dev(coords, stage, grid, scn, coords_out, origin, vsz, KR, cnt, n); }
}

// ---- merged: resize+pool+padzero (5063 blocks) + slice-split nbr build (2048) ----
__global__ __launch_bounds__(256) void k_respool_nbr(
    const ushort* __restrict__ t1, const ushort* __restrict__ t4, ushort* __restrict__ fc,
    const int* __restrict__ scn, const int* __restrict__ grid,
    int* __restrict__ nbr, unsigned* __restrict__ gmask16){
  __shared__ unsigned m16[4];
  int bid = blockIdx.x;
  int tidx = threadIdx.x;
  if (bid < 5063){
    int tid = bid*256 + tidx;
    if (tid < 864000){
      int c4 = tid % 20;
      int x  = (tid / 20) % 80;
      int y  = (tid / 1600) % 60;
      int v  = tid / 96000;
      int c = c4*4;
      int ky = y >> 1; int y0, y1; float wy0, wy1;
      if ((y & 1) == 0){ y0 = ky-1; y1 = ky; wy0 = 0.25f; wy1 = 0.75f; if (y0 < 0){ y0 = 0; wy0 = 0.f; wy1 = 1.f; } }
      else             { y0 = ky; y1 = ky+1; wy0 = 0.75f; wy1 = 0.25f; if (y1 > 29){ y1 = 29; wy1 = 0.f; wy0 = 1.f; } }
      int kx = x >> 1; int x0, x1; float wx0, wx1;
      if ((x & 1) == 0){ x0 = kx-1; x1 = kx; wx0 = 0.25f; wx1 = 0.75f; if (x0 < 0){ x0 = 0; wx0 = 0.f; wx1 = 1.f; } }
      else             { x0 = kx; x1 = kx+1; wx0 = 0.75f; wx1 = 0.25f; if (x1 > 39){ x1 = 39; wx1 = 0.f; wx0 = 1.f; } }
      float4 a00 = ld4b(t1 + ((size_t)(v*30 + y0)*40 + x0)*80 + c);
      float4 a01 = ld4b(t1 + ((size_t)(v*30 + y0)*40 + x1)*80 + c);
      float4 a10 = ld4b(t1 + ((size_t)(v*30 + y1)*40 + x0)*80 + c);
      float4 a11 = ld4b(t1 + ((size_t)(v*30 + y1)*40 + x1)*80 + c);
      float w00 = wy0*wx0, w01 = wy0*wx1, w10 = wy1*wx0, w11 = wy1*wx1;
      float4 r;
      r.x = w00*a00.x + w01*a01.x + w10*a10.x + w11*a11.x;
      r.y = w00*a00.y + w01*a01.y + w10*a10.y + w11*a11.y;
      r.z = w00*a00.z + w01*a01.z + w10*a10.z + w11*a11.z;
      r.w = w00*a00.w + w01*a01.w + w10*a10.w + w11*a11.w;
      st4b(fc + ((size_t)(v*60 + y)*80 + x)*160 + c, r);
      return;
    }
    int t = tid - 864000;
    if (t >= 432000) return;
    int c4 = t % 10;
    int x  = (t / 10) % 80;
    int y  = (t / 800) % 60;
    int v  = t / 48000;
    if (c4 < 6){
      int c = c4*4;
      const ushort* b0 = t4 + ((size_t)(v*120 + 2*y)*160 + 2*x)*24 + c;
      float4 a = ld4b(b0), b = ld4b(b0 + 24), cc = ld4b(b0 + 160*24), d = ld4b(b0 + 160*24 + 24);
      float4 r;
      r.x = 0.25f*(a.x + b.x + cc.x + d.x);
      r.y = 0.25f*(a.y + b.y + cc.y + d.y);
      r.z = 0.25f*(a.z + b.z + cc.z + d.z);
      r.w = 0.25f*(a.w + b.w + cc.w + d.w);
      st4b(fc + ((size_t)(v*60 + y)*80 + x)*160 + 120 + c, r);
    } else {
      float4 zz = {0.f,0.f,0.f,0.f};
      st4b(fc + ((size_t)(v*60 + y)*80 + x)*160 + 144 + (c4-6)*4, zz);
    }
    return;
  }
  bid -= 5063;
  if (tidx < 4) m16[tidx] = 0;
  __syncthreads();
  int vb = bid*64;
  int lane = tidx & 63;
  int wv = tidx >> 6;
  int n = vb + lane;
  int sx = scn[n*3+0], sy = scn[n*3+1], sz = scn[n*3+2];
  int k0 = wv*7;
  int k1 = min(27, k0 + 7);
  unsigned msk = 0;
  #pragma unroll 1
  for (int k = k0; k < k1; ++k){
    int dx = k/9 - 1, dy = (k/3)%3 - 1, dz = k%3 - 1;
    int nx = sx+dx, ny = sy+dy, nz = sz+dz;
    int idx = -1;
    if (((unsigned)nx < 96u) && ((unsigned)ny < 96u) && ((unsigned)nz < 96u))
      idx = grid[(nx*GS + ny)*GS + nz];
    unsigned long long b = __ballot(idx >= 0);
    unsigned sub = (unsigned)((b >> ((lane >> 4)*16)) & 0xFFFFull);
    // skip stores for 16-groups with no neighbor at this tap: never read
    if (sub){
      nbr[(size_t)k*NVOX + n] = idx;
      msk |= (1u << k);
    }
  }
  if ((lane & 15) == 0 && msk) atomicOr(&m16[lane >> 4], msk);
  __syncthreads();
  if (tidx < 4) gmask16[(vb >> 4) + tidx] = m16[tidx];
}

// ---- sampling: projection recomputed in-kernel (no table round-trip),
// masked mean/var + bn0. fp32 bilinear weights (closer to reference). ----
__global__ __launch_bounds__(256) void k_sample(
    const ushort* __restrict__ fuse, const int* __restrict__ coords,
    const float* __restrict__ origin, const float* __restrict__ vsz,
    const float* __restrict__ KR,
    const float* __restrict__ bn0g,
    const float* __restrict__ bn0b, ushort* __restrict__ F0){
  int tid = blockIdx.x*256 + threadIdx.x;
  int vox = tid >> 3;
  int c4 = tid & 7;
  int c = c4*4;
  int c1 = coords[vox*4+1], c2 = coords[vox*4+2], c3 = coords[vox*4+3];
  float vs = vsz[0];
  float wxx = (float)c1*vs + origin[0];
  float wyy = (float)c2*vs + origin[1];
  float wzz = (float)c3*vs + origin[2];
  float s0=0.f,s1=0.f,s2=0.f,s3=0.f;
  float q0=0.f,q1=0.f,q2=0.f,q3=0.f;
  float den = 0.f;
  #pragma unroll
  for (int v = 0; v < VN; ++v){
    const float* P = KR + v*12;
    float ix = P[0]*wxx + P[1]*wyy + P[2]*wzz + P[3];
    float iy = P[4]*wxx + P[5]*wyy + P[6]*wzz + P[7];
    float iz = P[8]*wxx + P[9]*wyy + P[10]*wzz + P[11];
    float gx = 2.f*(ix/iz)/159.f - 1.f;   // exact div: match reference rounding
    float gy = 2.f*(iy/iz)/119.f - 1.f;
    bool ok = (fabsf(gx) <= 1.f) && (fabsf(gy) <= 1.f) && (iz > 0.f);
    float px = ok ? (gx + 1.f)*0.5f*79.f : 0.f;
    float py = ok ? (gy + 1.f)*0.5f*59.f : 0.f;
    float x0f = floorf(px), y0f = floorf(py);
    float fx = px - x0f, fy = py - y0f;
    int idx = (int)y0f*80 + (int)x0f;
    float mf = ok ? 1.f : 0.f;
    den += mf;
    float w00 = (1.f-fx)*(1.f-fy)*mf, w01 = fx*(1.f-fy)*mf;
    float w10 = (1.f-fx)*fy*mf,       w11 = fx*fy*mf;
    const ushort* bp = fuse + (size_t)v*153600 + (size_t)idx*32 + c;
    float4 a00 = ld4b(bp);
    float4 a01 = ld4b(bp + 32);
    float4 a10 = ld4b(bp + 2560);
    float4 a11 = ld4b(bp + 2592);
    float g0 = w00*a00.x + w01*a01.x + w10*a10.x + w11*a11.x;
    float g1 = w00*a00.y + w01*a01.y + w10*a10.y + w11*a11.y;
    float g2 = w00*a00.z + w01*a01.z + w10*a10.z + w11*a11.z;
    float g3 = w00*a00.w + w01*a01.w + w10*a10.w + w11*a11.w;
    s0 += g0; q0 += g0*g0;
    s1 += g1; q1 += g1*g1;
    s2 += g2; q2 += g2*g2;
    s3 += g3; q3 += g3*g3;
  }
  float iden = 1.f/den;
  float m0 = s0*iden, m1 = s1*iden, m2 = s2*iden, m3 = s3*iden;
  float4 g = ld4(bn0g + c);
  float4 b = ld4(bn0b + c);
  float4 r;
  r.x = g.x*fmaxf(q0*iden - m0*m0, 0.f)*INVS + b.x;
  r.y = g.y*fmaxf(q1*iden - m1*m1, 0.f)*INVS + b.y;
  r.z = g.z*fmaxf(q2*iden - m2*m2, 0.f)*INVS + b.z;
  r.w = g.w*fmaxf(q3*iden - m3*m3, 0.f)*INVS + b.w;
  st4b(F0 + (size_t)vox*32 + c, r);
}

// ---- subm sparse conv 32->32 via MFMA bf16 ----
// Operand-swapped: lane m = voxel for gathers AND output; acc[g][n][r] =
// channel n*16+q*4+r of voxel (vb+g*16+m). uint2 skip loads + stores;
// LN reduce = 2 shuffles (xor 16, 32). Batch-3 taps per iteration.
template<int MODE>
__global__ __launch_bounds__(256, 4) void k_subm_mfma(
    const ushort* __restrict__ fin, const ushort* __restrict__ w2,
    const int* __restrict__ nbr, const unsigned* __restrict__ gmask16,
    const float* __restrict__ lng, const float* __restrict__ lnb,
    ushort* __restrict__ fout){
  int lane = threadIdx.x & 63;
  int wave = threadIdx.x >> 6;
  int vb = blockIdx.x*128 + wave*32;
  int m = lane & 15;
  int q = lane >> 4;

  unsigned rem0 = gmask16[(vb >> 4) + 0];
  unsigned rem1 = gmask16[(vb >> 4) + 1];
  unsigned rem = rem0 | rem1;

  f32x4v acc[2][2];
  acc[0][0] = 0.f; acc[0][1] = 0.f; acc[1][0] = 0.f; acc[1][1] = 0.f;
  bf16x8 zc = (short)0;

  while (rem){
    int k0 = __ffs(rem) - 1; rem &= rem - 1;
    int k1 = -1, k2 = -1;
    if (rem){ k1 = __ffs(rem) - 1; rem &= rem - 1; }
    if (rem){ k2 = __ffs(rem) - 1; rem &= rem - 1; }
    int a0v = nbr[(size_t)k0*NVOX + vb + m];
    int b0v = nbr[(size_t)k0*NVOX + vb + 16 + m];
    int a1 = -1, b1 = -1, a2 = -1, b2 = -1;
    if (k1 >= 0){
      int av = nbr[(size_t)k1*NVOX + vb + m];
      int bv = nbr[(size_t)k1*NVOX + vb + 16 + m];
      a1 = ((rem0 >> k1) & 1) ? av : -1;
      b1 = ((rem1 >> k1) & 1) ? bv : -1;
    }
    if (k2 >= 0){
      int av = nbr[(size_t)k2*NVOX + vb + m];
      int bv = nbr[(size_t)k2*NVOX + vb + 16 + m];
      a2 = ((rem0 >> k2) & 1) ? av : -1;
      b2 = ((rem1 >> k2) & 1) ? bv : -1;
    }
    int a0 = ((rem0 >> k0) & 1) ? a0v : -1;
    int b0 = ((rem1 >> k0) & 1) ? b0v : -1;
    bf16x8 A0, B0, A1 = zc, B1 = zc, A2 = zc, B2 = zc, t;
    bf16x8 w10 = zc, w11 = zc, w20 = zc, w21 = zc;
    t = *(const bf16x8*)(fin + (size_t)(a0 < 0 ? 0 : a0)*32 + q*8); A0 = (a0 < 0) ? zc : t;
    t = *(const bf16x8*)(fin + (size_t)(b0 < 0 ? 0 : b0)*32 + q*8); B0 = (b0 < 0) ? zc : t;
    bf16x8 w00 = *(const bf16x8*)(w2 + (size_t)(k0*32 + m)*32 + q*8);
    bf16x8 w01 = *(const bf16x8*)(w2 + (size_t)(k0*32 + 16 + m)*32 + q*8);
    if (k1 >= 0){
      t = *(const bf16x8*)(fin + (size_t)(a1 < 0 ? 0 : a1)*32 + q*8); A1 = (a1 < 0) ? zc : t;
      t = *(const bf16x8*)(fin + (size_t)(b1 < 0 ? 0 : b1)*32 + q*8); B1 = (b1 < 0) ? zc : t;
      w10 = *(const bf16x8*)(w2 + (size_t)(k1*32 + m)*32 + q*8);
      w11 = *(const bf16x8*)(w2 + (size_t)(k1*32 + 16 + m)*32 + q*8);
    }
    if (k2 >= 0){
      t = *(const bf16x8*)(fin + (size_t)(a2 < 0 ? 0 : a2)*32 + q*8); A2 = (a2 < 0) ? zc : t;
      t = *(const bf16x8*)(fin + (size_t)(b2 < 0 ? 0 : b2)*32 + q*8); B2 = (b2 < 0) ? zc : t;
      w20 = *(const bf16x8*)(w2 + (size_t)(k2*32 + m)*32 + q*8);
      w21 = *(const bf16x8*)(w2 + (size_t)(k2*32 + 16 + m)*32 + q*8);
    }
    acc[0][0] = __builtin_amdgcn_mfma_f32_16x16x32_bf16(w00, A0, acc[0][0], 0, 0, 0);
    acc[0][1] = __builtin_amdgcn_mfma_f32_16x16x32_bf16(w01, A0, acc[0][1], 0, 0, 0);
    acc[1][0] = __builtin_amdgcn_mfma_f32_16x16x32_bf16(w00, B0, acc[1][0], 0, 0, 0);
    acc[1][1] = __builtin_amdgcn_mfma_f32_16x16x32_bf16(w01, B0, acc[1][1], 0, 0, 0);
    if (k1 >= 0){
      acc[0][0] = __builtin_amdgcn_mfma_f32_16x16x32_bf16(w10, A1, acc[0][0], 0, 0, 0);
      acc[0][1] = __builtin_amdgcn_mfma_f32_16x16x32_bf16(w11, A1, acc[0][1], 0, 0, 0);
      acc[1][0] = __builtin_amdgcn_mfma_f32_16x16x32_bf16(w10, B1, acc[1][0], 0, 0, 0);
      acc[1][1] = __builtin_amdgcn_mfma_f32_16x16x32_bf16(w11, B1, acc[1][1], 0, 0, 0);
    }
    if (k2 >= 0){
      acc[0][0] = __builtin_amdgcn_mfma_f32_16x16x32_bf16(w20, A2, acc[0][0], 0, 0, 0);
      acc[0][1] = __builtin_amdgcn_mfma_f32_16x16x32_bf16(w21, A2, acc[0][1], 0, 0, 0);
      acc[1][0] = __builtin_amdgcn_mfma_f32_16x16x32_bf16(w20, B2, acc[1][0], 0, 0, 0);
      acc[1][1] = __builtin_amdgcn_mfma_f32_16x16x32_bf16(w21, B2, acc[1][1], 0, 0, 0);
    }
  }

  float4 g0v{0,0,0,0}, g1v{0,0,0,0}, b0v{0,0,0,0}, b1v{0,0,0,0};
  if (MODE == 1){
    g0v = ld4(lng + q*4);  g1v = ld4(lng + 16 + q*4);
    b0v = ld4(lnb + q*4);  b1v = ld4(lnb + 16 + q*4);
  }
  #pragma unroll
  for (int t = 0; t < 2; ++t){
    int vox = vb + t*16 + m;
    float x0[4], x1[4];
    #pragma unroll
    for (int r = 0; r < 4; ++r){
      x0[r] = fmaxf(acc[t][0][r], 0.f);
      x1[r] = fmaxf(acc[t][1][r], 0.f);
    }
    if (MODE == 1){
      uint2 sk0 = *(const uint2*)(fin + (size_t)vox*32 + q*4);
      uint2 sk1 = *(const uint2*)(fin + (size_t)vox*32 + 16 + q*4);
      x0[0] += blo(sk0.x); x0[1] += bhi(sk0.x); x0[2] += blo(sk0.y); x0[3] += bhi(sk0.y);
      x1[0] += blo(sk1.x); x1[1] += bhi(sk1.x); x1[2] += blo(sk1.y); x1[3] += bhi(sk1.y);
      float s = (x0[0]+x0[1]+x0[2]+x0[3]) + (x1[0]+x1[1]+x1[2]+x1[3]);
      s += __shfl_xor(s, 16);
      s += __shfl_xor(s, 32);
      float mean = s * (1.f/32.f);
      float v2 = 0.f;
      #pragma unroll
      for (int r = 0; r < 4; ++r){
        x0[r] -= mean; x1[r] -= mean;
        v2 += x0[r]*x0[r] + x1[r]*x1[r];
      }
      v2 += __shfl_xor(v2, 16);
      v2 += __shfl_xor(v2, 32);
      float rs = 1.f / sqrtf(v2*(1.f/32.f) + 1e-5f);
      x0[0] = x0[0]*rs*g0v.x + b0v.x; x0[1] = x0[1]*rs*g0v.y + b0v.y;
      x0[2] = x0[2]*rs*g0v.z + b0v.z; x0[3] = x0[3]*rs*g0v.w + b0v.w;
      x1[0] = x1[0]*rs*g1v.x + b1v.x; x1[1] = x1[1]*rs*g1v.y + b1v.y;
      x1[2] = x1[2]*rs*g1v.z + b1v.z; x1[3] = x1[3]*rs*g1v.w + b1v.w;
    }
    st4b(fout + (size_t)vox*32 + q*4,      float4{x0[0],x0[1],x0[2],x0[3]});
    st4b(fout + (size_t)vox*32 + 16 + q*4, float4{x1[0],x1[1],x1[2],x1[3]});
  }
}

// ---- final subm 32->1 + bn. 4 threads/voxel (8 ch each), 2-tap batches,
// cross-lane reduce. ----
__global__ __launch_bounds__(256) void k_s4(
    const ushort* __restrict__ fin, const float* __restrict__ w4,
    const int* __restrict__ nbr, const unsigned* __restrict__ gmask16,
    const float* __restrict__ bn4g, const float* __restrict__ bn4b,
    float* __restrict__ occ){
  int tid = blockIdx.x*256 + threadIdx.x;
  int n = tid >> 2;
  int part = tid & 3;
  unsigned rem = gmask16[n >> 4];
  float acc = 0.f;
  while (rem){
    int k0 = __ffs(rem) - 1; rem &= rem - 1;
    int k1 = -1;
    if (rem){ k1 = __ffs(rem) - 1; rem &= rem - 1; }
    int i0 = nbr[(size_t)k0*NVOX + n];
    int i1 = (k1 >= 0) ? nbr[(size_t)k1*NVOX + n] : -1;
    uint4 d0 = *(const uint4*)(fin + (size_t)(i0 < 0 ? 0 : i0)*32 + part*8);
    uint4 d1 = {0,0,0,0};
    if (k1 >= 0) d1 = *(const uint4*)(fin + (size_t)(i1 < 0 ? 0 : i1)*32 + part*8);
    if (i0 >= 0){
      float4 wa = ld4(w4 + k0*32 + part*8);
      float4 wb = ld4(w4 + k0*32 + part*8 + 4);
      acc += blo(d0.x)*wa.x + bhi(d0.x)*wa.y + blo(d0.y)*wa.z + bhi(d0.y)*wa.w
           + blo(d0.z)*wb.x + bhi(d0.z)*wb.y + blo(d0.w)*wb.z + bhi(d0.w)*wb.w;
    }
    if (i1 >= 0){
      float4 wa = ld4(w4 + k1*32 + part*8);
      float4 wb = ld4(w4 + k1*32 + part*8 + 4);
      acc += blo(d1.x)*wa.x + bhi(d1.x)*wa.y + blo(d1.y)*wa.z + bhi(d1.y)*wa.w
           + blo(d1.z)*wb.x + bhi(d1.z)*wb.y + blo(d1.w)*wb.z + bhi(d1.w)*wb.w;
    }
  }
  acc += __shfl_xor(acc, 1, 4);
  acc += __shfl_xor(acc, 2, 4);
  if (part == 0) occ[n] = bn4g[0]*acc*INVS + bn4b[0];
}

extern "C" void kernel_launch(void* const* d_in, const int* in_sizes, int n_in,
                              void* d_out, int out_size, void* d_ws, size_t ws_size,
                              hipStream_t stream){
  const float* feats1 = (const float*)d_in[0];
  const float* feats2 = (const float*)d_in[1];
  const float* feats4 = (const float*)d_in[2];
  const int*   coords = (const int*)d_in[3];
  const float* origin = (const float*)d_in[4];
  const float* vsz    = (const float*)d_in[5];
  const float* KR     = (const float*)d_in[6];
  const float* w_f1 = (const float*)d_in[7];  const float* b_f1 = (const float*)d_in[8];
  const float* w_f2 = (const float*)d_in[9];  const float* b_f2 = (const float*)d_in[10];
  const float* w_f4 = (const float*)d_in[11]; const float* b_f4 = (const float*)d_in[12];
  const float* w_dn = (const float*)d_in[13]; const float* b_dn = (const float*)d_in[14];
  const float* w_p[4] = {(const float*)d_in[15], (const float*)d_in[17],
                         (const float*)d_in[19], (const float*)d_in[21]};
  const float* b_p[4] = {(const float*)d_in[16], (const float*)d_in[18],
                         (const float*)d_in[20], (const float*)d_in[22]};
  const float* bn0g = (const float*)d_in[23]; const float* bn0b = (const float*)d_in[24];
  const float* w_elan = (const float*)d_in[25];
  const float* w_s1 = (const float*)d_in[26]; const float* ln1g = (const float*)d_in[27]; const float* ln1b = (const float*)d_in[28];
  const float* w_s2 = (const float*)d_in[29]; const float* ln2g = (const float*)d_in[30]; const float* ln2b = (const float*)d_in[31];
  const float* w_s3 = (const float*)d_in[32]; const float* ln3g = (const float*)d_in[33]; const float* ln3b = (const float*)d_in[34];
  const float* w_s4 = (const float*)d_in[35]; const float* bn4g = (const float*)d_in[36]; const float* bn4b = (const float*)d_in[37];
  const int* stage  = (const int*)d_in[38];
  float* out = (float*)d_out;
  char* base = (char*)d_ws;

  size_t off = 0;
  auto alloc = [&](size_t bytes)->char*{ char* p = base + off; off += (bytes + 255) & ~(size_t)255; return p; };
  ushort* nhwc1 = (ushort*)alloc((size_t)9*30*40*96*2);
  ushort* nhwc2 = (ushort*)alloc((size_t)9*60*80*64*2);
  ushort* nhwc4 = (ushort*)alloc((size_t)9*120*160*32*2);
  ushort* t1    = (ushort*)alloc((size_t)9*30*40*80*2);
  ushort* t4    = (ushort*)alloc((size_t)9*120*160*24*2);
  ushort* fcat  = (ushort*)alloc((size_t)9*60*80*160*2);
  ushort* A     = (ushort*)alloc((size_t)9*60*80*32*2);
  ushort* B     = (ushort*)alloc((size_t)9*60*80*32*2);
  ushort* Fb0   = (ushort*)alloc((size_t)NVOX*32*2);
  ushort* Fb1   = (ushort*)alloc((size_t)NVOX*32*2);
  int*    nbr   = (int*)alloc((size_t)27*NVOX*4);
  int*    grid  = (int*)alloc((size_t)GS*GS*GS*4);
  int*    scn   = (int*)alloc((size_t)NVOX*3*4);
  unsigned* gmask16 = (unsigned*)alloc((size_t)(NVOX/16)*4);
  ushort* wf1   = (ushort*)alloc(9*3*80*32*2);
  ushort* wf2   = (ushort*)alloc(9*2*48*32*2);
  ushort* wf4   = (ushort*)alloc(9*1*32*32*2);
  ushort* wdn   = (ushort*)alloc(1*5*32*32*2);
  ushort* wp0   = (ushort*)alloc(9*1*32*32*2);
  ushort* wp1   = (ushort*)alloc(9*1*32*32*2);
  ushort* wp2   = (ushort*)alloc(9*1*32*32*2);
  ushort* wp3   = (ushort*)alloc(9*1*32*32*2);
  ushort* w2e   = (ushort*)alloc(27*1024*2);
  ushort* w2s1  = (ushort*)alloc(27*1024*2);
  ushort* w2s2  = (ushort*)alloc(27*1024*2);
  ushort* w2s3  = (ushort*)alloc(27*1024*2);

  auto nb = [](int total){ return (total + 255)/256; };

  // 1. mega prep
  k_prep<<<8012,256,0,stream>>>(
      w_f1, w_f2, w_f4, w_dn, w_p[0], w_p[1], w_p[2], w_p[3],
      w_elan, w_s1, w_s2, w_s3,
      wf1, wf2, wf4, wdn, wp0, wp1, wp2, wp3, w2e, w2s1, w2s2, w2s3, grid,
      feats1, feats2, feats4, nhwc1, nhwc2, nhwc4);

  // 2. head convs (f1 reg-path, f4 LDS-tiled, f2 reg-path) + scatter
  k_heads<<<169 + 720 + 675 + 512,256,0,stream>>>(
      nhwc1, wf1, b_f1, t1,
      nhwc2, wf2, b_f2, fcat,
      nhwc4, wf4, b_f4, t4,
      coords, stage, grid, scn, out + NVOX,
      origin, vsz, KR, out + 5*NVOX);

  // 3. respool + nbr build
  k_respool_nbr<<<5063 + 2048,256,0,stream>>>(t1, t4, fcat, scn, grid, nbr, gmask16);

  // 4-8. down conv (1x1 reg-path) + 4 LDS-tiled residual convs
  k_conv_mfma<5,2,1,1><<<675,256,0,stream>>>(fcat, wdn, b_dn, A, 60, 80, 43200, 32, 32, 0);
  k_conv_lds4<<<675,256,0,stream>>>(A, wp0, b_p[0], B, A);
  k_conv_lds4<<<675,256,0,stream>>>(B, wp1, b_p[1], A, B);
  k_conv_lds4<<<675,256,0,stream>>>(A, wp2, b_p[2], B, A);
  k_conv_lds4<<<675,256,0,stream>>>(B, wp3, b_p[3], A, B);

  // 9. sampling -> F0 (projection recomputed in-kernel)
  k_sample<<<NVOX/32,256,0,stream>>>(A, coords, origin, vsz, KR, bn0g, bn0b, Fb0);

  // 10-13. sparse conv stack (MT=2, batch-3 taps, swapped operands)
  k_subm_mfma<0><<<NVOX/128,256,0,stream>>>(Fb0, w2e,  nbr, gmask16, nullptr, nullptr, Fb1);
  k_subm_mfma<1><<<NVOX/128,256,0,stream>>>(Fb1, w2s1, nbr, gmask16, ln1g, ln1b, Fb0);
  k_subm_mfma<1><<<NVOX/128,256,0,stream>>>(Fb0, w2s2, nbr, gmask16, ln2g, ln2b, Fb1);
  k_subm_mfma<1><<<NVOX/128,256,0,stream>>>(Fb1, w2s3, nbr, gmask16, ln3g, ln3b, Fb0);

  // 14. final head (4 threads per voxel)
  k_s4<<<NVOX/64,256,0,stream>>>(Fb0, w_s4, nbr, gmask16, bn4g, bn4b, out);
}

// Round 5
// 332.655 us; speedup vs baseline: 1.0376x; 1.0376x over previous
//
#include <hip/hip_runtime.h>
#include <math.h>

#define VN 9
#define NVOX 131072
#define GS 96
static constexpr float INVS = 0.9999950000374997f; // 1/sqrt(1+1e-5)

typedef short bf16x8 __attribute__((ext_vector_type(8)));
typedef float f32x4v __attribute__((ext_vector_type(4)));

__device__ inline float4 ld4(const float* p){ return *reinterpret_cast<const float4*>(p); }

__device__ inline ushort f2b(float f){
  unsigned u = __float_as_uint(f);
  unsigned r = (u + 0x7fffu + ((u >> 16) & 1u)) >> 16;
  return (ushort)r;
}
__device__ inline float b2f(ushort s){ return __uint_as_float(((unsigned)s) << 16); }
__device__ inline float blo(unsigned u){ return __uint_as_float(u << 16); }
__device__ inline float bhi(unsigned u){ return __uint_as_float(u & 0xffff0000u); }

__device__ inline float4 ld4b(const ushort* p){
  uint2 u = *reinterpret_cast<const uint2*>(p);
  float4 r; r.x = blo(u.x); r.y = bhi(u.x); r.z = blo(u.y); r.w = bhi(u.y); return r;
}
__device__ inline void st4b(ushort* p, float4 v){
  uint2 u;
  u.x = (unsigned)f2b(v.x) | ((unsigned)f2b(v.y) << 16);
  u.y = (unsigned)f2b(v.z) | ((unsigned)f2b(v.w) << 16);
  *reinterpret_cast<uint2*>(p) = u;
}

// ---- weight prep helpers ----
__device__ inline void wprep2_dev(const float* __restrict__ w, ushort* __restrict__ o,
                                  int Cout, int Cin, int K, int CK, int CoutPad, int tid){
  int ci32 = tid & 31;
  int co = (tid >> 5) % CoutPad;
  int ck = (tid / (32*CoutPad)) % CK;
  int tap = tid / (32*CoutPad*CK);
  int ci = ck*32 + ci32;
  float v = 0.f;
  if (co < Cout && ci < Cin) v = w[(size_t)(co*Cin + ci)*K*K + tap];
  o[tid] = f2b(v);
}
__device__ inline void wprep_dev(const float* __restrict__ w, ushort* __restrict__ o, int tid){
  int k = tid >> 10;
  int r = tid & 1023;
  int co = r >> 5;
  int ci = r & 31;
  o[tid] = f2b(w[k*1024 + ci*32 + co]);
}

// ---- NCHW fp32 -> NHWC bf16 via LDS tile ----
__device__ inline void nhwc_tile_dev(const float* __restrict__ in, ushort* __restrict__ out,
                                     int C, int Cpad, int HW, int tile, int tilesPerV,
                                     float* lds, int tx){
  int v  = tile / tilesPerV;
  int p0 = (tile - v*tilesPerV) * 64;
  const float* ip = in + (size_t)v*C*HW + p0;
  int iters = Cpad >> 2;
  for (int i = 0; i < iters; ++i){
    int idx = i*256 + tx;
    int c = idx >> 6;
    int p = idx & 63;
    float val = 0.f;
    if (c < C && (p0 + p) < HW) val = ip[(size_t)c*HW + p];
    lds[c*65 + p] = val;
  }
  __syncthreads();
  int groups = Cpad >> 2;
  int tot = 64*groups;
  for (int basei = 0; basei < tot; basei += 256){
    int idx = basei + tx;
    if (idx < tot){
      int g  = idx % groups;
      int px = idx / groups;
      if ((p0 + px) < HW){
        float4 r;
        r.x = lds[(g*4+0)*65 + px];
        r.y = lds[(g*4+1)*65 + px];
        r.z = lds[(g*4+2)*65 + px];
        r.w = lds[(g*4+3)*65 + px];
        st4b(out + (size_t)(v*HW + p0 + px)*Cpad + g*4, r);
      }
    }
  }
}

// ---- mega prep kernel: weight preps + grid clear + NHWC transposes ----
__global__ __launch_bounds__(256) void k_prep(
    const float* wf1s, const float* wf2s, const float* wf4s, const float* wdns,
    const float* wp0s, const float* wp1s, const float* wp2s, const float* wp3s,
    const float* wes, const float* ws1s, const float* ws2s, const float* ws3s,
    ushort* wf1, ushort* wf2, ushort* wf4, ushort* wdn,
    ushort* wp0, ushort* wp1, ushort* wp2, ushort* wp3,
    ushort* w2e, ushort* w2s1, ushort* w2s2, ushort* w2s3,
    int* grid,
    const float* f1, const float* f2, const float* f4,
    ushort* o1, ushort* o2, ushort* o4){
  __shared__ float lds[96*65];
  int bid = blockIdx.x;
  int tx = threadIdx.x;
  if (bid < 270){ int t = bid*256+tx; if (t < 69120) wprep2_dev(wf1s, wf1, 80, 80, 3, 3, 80, t); return; }
  bid -= 270;
  if (bid < 108){ int t = bid*256+tx; if (t < 27648) wprep2_dev(wf2s, wf2, 40, 40, 3, 2, 48, t); return; }
  bid -= 108;
  if (bid < 36){ int t = bid*256+tx; if (t < 9216) wprep2_dev(wf4s, wf4, 24, 24, 3, 1, 32, t); return; }
  bid -= 36;
  if (bid < 20){ int t = bid*256+tx; if (t < 5120) wprep2_dev(wdns, wdn, 32, 144, 1, 5, 32, t); return; }
  bid -= 20;
  if (bid < 36){ int t = bid*256+tx; if (t < 9216) wprep2_dev(wp0s, wp0, 32, 32, 3, 1, 32, t); return; }
  bid -= 36;
  if (bid < 36){ int t = bid*256+tx; if (t < 9216) wprep2_dev(wp1s, wp1, 32, 32, 3, 1, 32, t); return; }
  bid -= 36;
  if (bid < 36){ int t = bid*256+tx; if (t < 9216) wprep2_dev(wp2s, wp2, 32, 32, 3, 1, 32, t); return; }
  bid -= 36;
  if (bid < 36){ int t = bid*256+tx; if (t < 9216) wprep2_dev(wp3s, wp3, 32, 32, 3, 1, 32, t); return; }
  bid -= 36;
  if (bid < 108){ int t = bid*256+tx; if (t < 27648) wprep_dev(wes, w2e, t); return; }
  bid -= 108;
  if (bid < 108){ int t = bid*256+tx; if (t < 27648) wprep_dev(ws1s, w2s1, t); return; }
  bid -= 108;
  if (bid < 108){ int t = bid*256+tx; if (t < 27648) wprep_dev(ws2s, w2s2, t); return; }
  bid -= 108;
  if (bid < 108){ int t = bid*256+tx; if (t < 27648) wprep_dev(ws3s, w2s3, t); return; }
  bid -= 108;
  if (bid < 3456){ int t = bid*256+tx; if (t < GS*GS*GS) grid[t] = -1; return; }
  bid -= 3456;
  if (bid < 171){ nhwc_tile_dev(f1, o1, 80, 96, 1200, bid, 19, lds, tx); return; }
  bid -= 171;
  if (bid < 675){ nhwc_tile_dev(f2, o2, 40, 64, 4800, bid, 75, lds, tx); return; }
  bid -= 675;
  if (bid < 2700){ nhwc_tile_dev(f4, o4, 24, 32, 19200, bid, 300, lds, tx); }
}

// ---- implicit-GEMM conv via MFMA, register path (for f1/f2/1x1) ----
// Operand-swapped: mfma(Bf, Af) -> D[row=co(q*4+r)][col=px(m)]; epilogue
// stores 4 consecutive channels per lane as one uint2.
template<int CK, int NT, int TAPS, int MT>
__device__ void conv_dev(
    const ushort* __restrict__ fin, const ushort* __restrict__ w2,
    const float* __restrict__ bias, ushort* __restrict__ outp,
    int H, int W, int total, int Cout, int outStride, int outOff,
    int bid, int tid){
  constexpr int CIN = CK*32;
  constexpr int COP = NT*16;
  int lane = tid & 63;
  int wave = tid >> 6;
  int vbase = bid*(MT*64) + wave*(MT*16);
  int m = lane & 15, q = lane >> 4;
  int HW = H*W;
  int p[MT], py[MT], px[MT]; bool pin[MT];
  #pragma unroll
  for (int t = 0; t < MT; ++t){
    int pp = vbase + t*16 + m;
    pin[t] = pp < total;
    if (pp > total-1) pp = total-1;
    p[t] = pp;
    int v = pp / HW; int rem = pp - v*HW;
    int y = rem / W;
    py[t] = y; px[t] = rem - y*W;
  }
  f32x4v acc[MT][NT];
  #pragma unroll
  for (int t = 0; t < MT; ++t)
    #pragma unroll
    for (int n = 0; n < NT; ++n) acc[t][n] = 0.f;
  bf16x8 z = (short)0;

  #pragma unroll 1
  for (int tap = 0; tap < TAPS; ++tap){
    int dy = (TAPS == 9) ? tap/3 - 1 : 0;
    int dx = (TAPS == 9) ? tap%3 - 1 : 0;
    int off = dy*W + dx;
    bool val[MT];
    #pragma unroll
    for (int t = 0; t < MT; ++t)
      val[t] = pin[t] && ((unsigned)(py[t]+dy) < (unsigned)H)
                      && ((unsigned)(px[t]+dx) < (unsigned)W);
    #pragma unroll
    for (int ck = 0; ck < CK; ++ck){
      bf16x8 Af[MT], Bf[NT];
      #pragma unroll
      for (int t = 0; t < MT; ++t){
        size_t idx = val[t] ? (size_t)(p[t]+off) : 0;
        bf16x8 a = *(const bf16x8*)(fin + idx*CIN + ck*32 + q*8);
        Af[t] = val[t] ? a : z;
      }
      #pragma unroll
      for (int n = 0; n < NT; ++n)
        Bf[n] = *(const bf16x8*)(w2 + ((size_t)((tap*CK+ck)*COP + n*16 + m))*32 + q*8);
      #pragma unroll
      for (int t = 0; t < MT; ++t)
        #pragma unroll
        for (int n = 0; n < NT; ++n)
          acc[t][n] = __builtin_amdgcn_mfma_f32_16x16x32_bf16(Bf[n], Af[t], acc[t][n], 0, 0, 0);
    }
  }

  #pragma unroll
  for (int n = 0; n < NT; ++n){
    int co4 = n*16 + q*4;
    bool cok = co4 < Cout;   // all Couts are multiples of 4
    float4 bs = cok ? ld4(bias + co4) : float4{0.f,0.f,0.f,0.f};
    #pragma unroll
    for (int t = 0; t < MT; ++t){
      int pp = vbase + t*16 + m;
      if (pp < total && cok){
        float4 v;
        v.x = fmaxf(acc[t][n][0] + bs.x, 0.f);
        v.y = fmaxf(acc[t][n][1] + bs.y, 0.f);
        v.z = fmaxf(acc[t][n][2] + bs.z, 0.f);
        v.w = fmaxf(acc[t][n][3] + bs.w, 0.f);
        st4b(outp + (size_t)pp*outStride + outOff + co4, v);
      }
    }
  }
}

template<int CK, int NT, int TAPS, int MT>
__global__ __launch_bounds__(256) void k_conv_mfma(
    const ushort* __restrict__ fin, const ushort* __restrict__ w2,
    const float* __restrict__ bias, ushort* __restrict__ outp,
    int H, int W, int total, int Cout, int outStride, int outOff){
  conv_dev<CK,NT,TAPS,MT>(fin, w2, bias, outp, H, W, total, Cout, outStride, outOff,
                          blockIdx.x, threadIdx.x);
}

// ---- LDS-tiled 3x3 conv, CIN=32. Tile TH x 16 px, halo patch (TH+2)x18x36 in LDS.
// Operand-swapped MFMA; uint2 stores/skip-loads.
template<int TH, int NT>
__device__ void conv_lds_dev(
    const ushort* __restrict__ fin, const ushort* __restrict__ w2,
    const float* __restrict__ bias, ushort* __restrict__ outp,
    int H, int W, int Cout, int outStride,
    const ushort* __restrict__ skipin, ushort* lds, int bid, int tid){
  constexpr int RPW = TH/4;
  constexpr int PS = 36;             // padded channel stride (18 banks -> 2-way free)
  int xtiles = W >> 4;
  int ytiles = (H + TH - 1) / TH;
  int v  = bid / (ytiles*xtiles);
  int rem = bid - v*(ytiles*xtiles);
  int ty = (rem / xtiles) * TH;
  int tx = (rem % xtiles) * 16;
  const ushort* ibase = fin + (size_t)v*H*W*32;
  // load halo patch (TH+2) x 18 x 32ch
  for (int i = tid; i < (TH+2)*18*4; i += 256){
    int chunk = i & 3;
    int pxi = i >> 2;
    int ly = pxi / 18, lx = pxi - ly*18;
    int gy = ty + ly - 1, gx = tx + lx - 1;
    uint4 d = {0,0,0,0};
    if ((unsigned)gy < (unsigned)H && (unsigned)gx < (unsigned)W)
      d = *(const uint4*)(ibase + ((size_t)gy*W + gx)*32 + chunk*8);
    *(uint4*)(lds + (size_t)(ly*18 + lx)*PS + chunk*8) = d;
  }
  __syncthreads();
  int lane = tid & 63;
  int wave = tid >> 6;
  int m = lane & 15, q = lane >> 4;
  f32x4v acc[RPW][NT];
  #pragma unroll
  for (int t = 0; t < RPW; ++t)
    #pragma unroll
    for (int n = 0; n < NT; ++n) acc[t][n] = 0.f;

  #pragma unroll 1
  for (int tap = 0; tap < 9; ++tap){
    int dy = tap/3 - 1, dx = tap%3 - 1;
    bf16x8 Af[RPW], Bf[NT];
    #pragma unroll
    for (int t = 0; t < RPW; ++t){
      int ly = wave*RPW + t + 1 + dy;
      int lx = m + 1 + dx;
      Af[t] = *(const bf16x8*)(lds + (size_t)(ly*18 + lx)*PS + q*8);
    }
    #pragma unroll
    for (int n = 0; n < NT; ++n)
      Bf[n] = *(const bf16x8*)(w2 + ((size_t)(tap*(NT*16) + n*16 + m))*32 + q*8);
    #pragma unroll
    for (int t = 0; t < RPW; ++t)
      #pragma unroll
      for (int n = 0; n < NT; ++n)
        acc[t][n] = __builtin_amdgcn_mfma_f32_16x16x32_bf16(Bf[n], Af[t], acc[t][n], 0, 0, 0);
  }

  // epilogue: lane m = px-in-tile, acc[t][n][r] = channel n*16+q*4+r
  #pragma unroll
  for (int n = 0; n < NT; ++n){
    int co4 = n*16 + q*4;
    bool cok = co4 < Cout;
    float4 bs = cok ? ld4(bias + co4) : float4{0.f,0.f,0.f,0.f};
    #pragma unroll
    for (int t = 0; t < RPW; ++t){
      int y = ty + wave*RPW + t;
      int x = tx + m;
      if (y < H && cok){
        size_t pp = (size_t)(v*H + y)*W + x;
        float4 val;
        val.x = fmaxf(acc[t][n][0] + bs.x, 0.f);
        val.y = fmaxf(acc[t][n][1] + bs.y, 0.f);
        val.z = fmaxf(acc[t][n][2] + bs.z, 0.f);
        val.w = fmaxf(acc[t][n][3] + bs.w, 0.f);
        if (skipin){
          float4 sk = ld4b(skipin + pp*32 + co4);
          val.x += sk.x; val.y += sk.y; val.z += sk.z; val.w += sk.w;
        }
        st4b(outp + pp*outStride + co4, val);
      }
    }
  }
}

// chain conv: TH=4 -> patch 6x18x36 = 7.8 KB, 675 blocks
__global__ __launch_bounds__(256) void k_conv_lds4(
    const ushort* __restrict__ fin, const ushort* __restrict__ w2,
    const float* __restrict__ bias, ushort* __restrict__ outp,
    const ushort* __restrict__ skipin){
  __shared__ ushort lds[6*18*36];
  conv_lds_dev<4,2>(fin, w2, bias, outp, 60, 80, 32, 32, skipin, lds, blockIdx.x, threadIdx.x);
}

// ---- scatter device: grid scatter + coords + sample table (fp32 weights) + count ----
// Projection computed ONCE per voxel here (latency-hidden under head convs);
// k_sample consumes the table -> no 8x redundant VALU recompute there.
__device__ void scatter_dev(const int* __restrict__ coords, const int* __restrict__ stage,
                            int* __restrict__ grid, int* __restrict__ scn,
                            float* __restrict__ coords_out,
                            const float* __restrict__ origin, const float* __restrict__ vsz,
                            const float* __restrict__ KR,
                            ushort* __restrict__ sidx, float4* __restrict__ swf,
                            float* __restrict__ cnt, int n){
  int c0 = coords[n*4], c1 = coords[n*4+1], c2 = coords[n*4+2], c3 = coords[n*4+3];
  coords_out[n*4+0] = (float)c0;
  coords_out[n*4+1] = (float)c1;
  coords_out[n*4+2] = (float)c2;
  coords_out[n*4+3] = (float)c3;
  int sh = 2 - stage[0];
  int s1 = c1 >> sh, s2 = c2 >> sh, s3 = c3 >> sh;
  scn[n*3+0] = s1; scn[n*3+1] = s2; scn[n*3+2] = s3;
  grid[(s1*GS + s2)*GS + s3] = n;

  float vs = vsz[0];
  float wx = (float)c1*vs + origin[0];
  float wy = (float)c2*vs + origin[1];
  float wz = (float)c3*vs + origin[2];
  float den = 0.f;
  #pragma unroll 1
  for (int v = 0; v < VN; ++v){
    const float* P = KR + v*12;
    float ix = P[0]*wx + P[1]*wy + P[2]*wz + P[3];
    float iy = P[4]*wx + P[5]*wy + P[6]*wz + P[7];
    float iz = P[8]*wx + P[9]*wy + P[10]*wz + P[11];
    float gx = 2.f*(ix/iz)/159.f - 1.f;   // exact div: match reference rounding
    float gy = 2.f*(iy/iz)/119.f - 1.f;
    bool ok = (fabsf(gx) <= 1.f) && (fabsf(gy) <= 1.f) && (iz > 0.f);
    float px = ok ? (gx + 1.f)*0.5f*79.f : 0.f;
    float py = ok ? (gy + 1.f)*0.5f*59.f : 0.f;
    float x0f = floorf(px), y0f = floorf(py);
    float fx = px - x0f, fy = py - y0f;
    int idx = (int)y0f*80 + (int)x0f;
    float mf = ok ? 1.f : 0.f;
    den += mf;
    float4 w;
    w.x = (1.f-fx)*(1.f-fy)*mf;
    w.y = fx*(1.f-fy)*mf;
    w.z = (1.f-fx)*fy*mf;
    w.w = fx*fy*mf;
    sidx[(size_t)v*NVOX + n] = (ushort)idx;
    swf[(size_t)v*NVOX + n] = w;
  }
  cnt[n] = den;
}

// ---- merged: f1 conv (169) + f4 LDS conv (720) + f2 conv (675) + scatter (512) ----
__global__ __launch_bounds__(256) void k_heads(
    const ushort* nhwc1, const ushort* wf1, const float* b_f1, ushort* t1,
    const ushort* nhwc2, const ushort* wf2, const float* b_f2, ushort* fcat,
    const ushort* nhwc4, const ushort* wf4, const float* b_f4, ushort* t4,
    const int* coords, const int* stage, int* grid, int* scn, float* coords_out,
    const float* origin, const float* vsz, const float* KR,
    ushort* sidx, float4* swf, float* cnt){
  __shared__ ushort lds[18*18*36];
  int bid = blockIdx.x;
  int tid = threadIdx.x;
  if (bid < 169){ conv_dev<3,5,9,1>(nhwc1, wf1, b_f1, t1, 30, 40, 10800, 80, 80, 0, bid, tid); return; }
  bid -= 169;
  if (bid < 720){ conv_lds_dev<16,2>(nhwc4, wf4, b_f4, t4, 120, 160, 24, 24, nullptr, lds, bid, tid); return; }
  bid -= 720;
  if (bid < 675){ conv_dev<2,3,9,1>(nhwc2, wf2, b_f2, fcat, 60, 80, 43200, 40, 160, 80, bid, tid); return; }
  bid -= 675;
  { int n = bid*256 + tid;
    scatter_dev(coords, stage, grid, scn, coords_out, origin, vsz, KR, sidx, swf, cnt, n); }
}

// ---- merged: resize+pool+padzero (5063 blocks) + slice-split nbr build (2048) ----
__global__ __launch_bounds__(256) void k_respool_nbr(
    const ushort* __restrict__ t1, const ushort* __restrict__ t4, ushort* __restrict__ fc,
    const int* __restrict__ scn, const int* __restrict__ grid,
    int* __restrict__ nbr, unsigned* __restrict__ gmask16){
  __shared__ unsigned m16[4];
  int bid = blockIdx.x;
  int tidx = threadIdx.x;
  if (bid < 5063){
    int tid = bid*256 + tidx;
    if (tid < 864000){
      int c4 = tid % 20;
      int x  = (tid / 20) % 80;
      int y  = (tid / 1600) % 60;
      int v  = tid / 96000;
      int c = c4*4;
      int ky = y >> 1; int y0, y1; float wy0, wy1;
      if ((y & 1) == 0){ y0 = ky-1; y1 = ky; wy0 = 0.25f; wy1 = 0.75f; if (y0 < 0){ y0 = 0; wy0 = 0.f; wy1 = 1.f; } }
      else             { y0 = ky; y1 = ky+1; wy0 = 0.75f; wy1 = 0.25f; if (y1 > 29){ y1 = 29; wy1 = 0.f; wy0 = 1.f; } }
      int kx = x >> 1; int x0, x1; float wx0, wx1;
      if ((x & 1) == 0){ x0 = kx-1; x1 = kx; wx0 = 0.25f; wx1 = 0.75f; if (x0 < 0){ x0 = 0; wx0 = 0.f; wx1 = 1.f; } }
      else             { x0 = kx; x1 = kx+1; wx0 = 0.75f; wx1 = 0.25f; if (x1 > 39){ x1 = 39; wx1 = 0.f; wx0 = 1.f; } }
      float4 a00 = ld4b(t1 + ((size_t)(v*30 + y0)*40 + x0)*80 + c);
      float4 a01 = ld4b(t1 + ((size_t)(v*30 + y0)*40 + x1)*80 + c);
      float4 a10 = ld4b(t1 + ((size_t)(v*30 + y1)*40 + x0)*80 + c);
      float4 a11 = ld4b(t1 + ((size_t)(v*30 + y1)*40 + x1)*80 + c);
      float w00 = wy0*wx0, w01 = wy0*wx1, w10 = wy1*wx0, w11 = wy1*wx1;
      float4 r;
      r.x = w00*a00.x + w01*a01.x + w10*a10.x + w11*a11.x;
      r.y = w00*a00.y + w01*a01.y + w10*a10.y + w11*a11.y;
      r.z = w00*a00.z + w01*a01.z + w10*a10.z + w11*a11.z;
      r.w = w00*a00.w + w01*a01.w + w10*a10.w + w11*a11.w;
      st4b(fc + ((size_t)(v*60 + y)*80 + x)*160 + c, r);
      return;
    }
    int t = tid - 864000;
    if (t >= 432000) return;
    int c4 = t % 10;
    int x  = (t / 10) % 80;
    int y  = (t / 800) % 60;
    int v  = t / 48000;
    if (c4 < 6){
      int c = c4*4;
      const ushort* b0 = t4 + ((size_t)(v*120 + 2*y)*160 + 2*x)*24 + c;
      float4 a = ld4b(b0), b = ld4b(b0 + 24), cc = ld4b(b0 + 160*24), d = ld4b(b0 + 160*24 + 24);
      float4 r;
      r.x = 0.25f*(a.x + b.x + cc.x + d.x);
      r.y = 0.25f*(a.y + b.y + cc.y + d.y);
      r.z = 0.25f*(a.z + b.z + cc.z + d.z);
      r.w = 0.25f*(a.w + b.w + cc.w + d.w);
      st4b(fc + ((size_t)(v*60 + y)*80 + x)*160 + 120 + c, r);
    } else {
      float4 zz = {0.f,0.f,0.f,0.f};
      st4b(fc + ((size_t)(v*60 + y)*80 + x)*160 + 144 + (c4-6)*4, zz);
    }
    return;
  }
  bid -= 5063;
  if (tidx < 4) m16[tidx] = 0;
  __syncthreads();
  int vb = bid*64;
  int lane = tidx & 63;
  int wv = tidx >> 6;
  int n = vb + lane;
  int sx = scn[n*3+0], sy = scn[n*3+1], sz = scn[n*3+2];
  int k0 = wv*7;
  int k1 = min(27, k0 + 7);
  unsigned msk = 0;
  #pragma unroll 1
  for (int k = k0; k < k1; ++k){
    int dx = k/9 - 1, dy = (k/3)%3 - 1, dz = k%3 - 1;
    int nx = sx+dx, ny = sy+dy, nz = sz+dz;
    int idx = -1;
    if (((unsigned)nx < 96u) && ((unsigned)ny < 96u) && ((unsigned)nz < 96u))
      idx = grid[(nx*GS + ny)*GS + nz];
    unsigned long long b = __ballot(idx >= 0);
    unsigned sub = (unsigned)((b >> ((lane >> 4)*16)) & 0xFFFFull);
    // skip stores for 16-groups with no neighbor at this tap: never read
    if (sub){
      nbr[(size_t)k*NVOX + n] = idx;
      msk |= (1u << k);
    }
  }
  if ((lane & 15) == 0 && msk) atomicOr(&m16[lane >> 4], msk);
  __syncthreads();
  if (tidx < 4) gmask16[(vb >> 4) + tidx] = m16[tidx];
}

// ---- sampling from fp32-weight table + masked mean/var + bn0 ----
__global__ __launch_bounds__(256) void k_sample(
    const ushort* __restrict__ fuse, const ushort* __restrict__ sidx,
    const float4* __restrict__ swf,
    const float* __restrict__ cnt, const float* __restrict__ bn0g,
    const float* __restrict__ bn0b, ushort* __restrict__ F0){
  int tid = blockIdx.x*256 + threadIdx.x;
  int vox = tid >> 3;
  int c4 = tid & 7;
  int c = c4*4;
  float s0=0.f,s1=0.f,s2=0.f,s3=0.f;
  float q0=0.f,q1=0.f,q2=0.f,q3=0.f;
  #pragma unroll
  for (int v = 0; v < VN; ++v){
    int idx = sidx[(size_t)v*NVOX + vox];
    float4 w = swf[(size_t)v*NVOX + vox];
    const ushort* bp = fuse + (size_t)v*153600 + (size_t)idx*32 + c;
    float4 a00 = ld4b(bp);
    float4 a01 = ld4b(bp + 32);
    float4 a10 = ld4b(bp + 2560);
    float4 a11 = ld4b(bp + 2592);
    float g0 = w.x*a00.x + w.y*a01.x + w.z*a10.x + w.w*a11.x;
    float g1 = w.x*a00.y + w.y*a01.y + w.z*a10.y + w.w*a11.y;
    float g2 = w.x*a00.z + w.y*a01.z + w.z*a10.z + w.w*a11.z;
    float g3 = w.x*a00.w + w.y*a01.w + w.z*a10.w + w.w*a11.w;
    s0 += g0; q0 += g0*g0;
    s1 += g1; q1 += g1*g1;
    s2 += g2; q2 += g2*g2;
    s3 += g3; q3 += g3*g3;
  }
  float iden = 1.f/cnt[vox];
  float m0 = s0*iden, m1 = s1*iden, m2 = s2*iden, m3 = s3*iden;
  float4 g = ld4(bn0g + c);
  float4 b = ld4(bn0b + c);
  float4 r;
  r.x = g.x*fmaxf(q0*iden - m0*m0, 0.f)*INVS + b.x;
  r.y = g.y*fmaxf(q1*iden - m1*m1, 0.f)*INVS + b.y;
  r.z = g.z*fmaxf(q2*iden - m2*m2, 0.f)*INVS + b.z;
  r.w = g.w*fmaxf(q3*iden - m3*m3, 0.f)*INVS + b.w;
  st4b(F0 + (size_t)vox*32 + c, r);
}

// ---- subm sparse conv 32->32 via MFMA bf16 ----
// Operand-swapped: lane m = voxel for gathers AND output; acc[g][n][r] =
// channel n*16+q*4+r of voxel (vb+g*16+m). uint2 skip loads + stores;
// LN reduce = 2 shuffles (xor 16, 32). Batch-3 taps per iteration.
template<int MODE>
__global__ __launch_bounds__(256, 4) void k_subm_mfma(
    const ushort* __restrict__ fin, const ushort* __restrict__ w2,
    const int* __restrict__ nbr, const unsigned* __restrict__ gmask16,
    const float* __restrict__ lng, const float* __restrict__ lnb,
    ushort* __restrict__ fout){
  int lane = threadIdx.x & 63;
  int wave = threadIdx.x >> 6;
  int vb = blockIdx.x*128 + wave*32;
  int m = lane & 15;
  int q = lane >> 4;

  unsigned rem0 = gmask16[(vb >> 4) + 0];
  unsigned rem1 = gmask16[(vb >> 4) + 1];
  unsigned rem = rem0 | rem1;

  f32x4v acc[2][2];
  acc[0][0] = 0.f; acc[0][1] = 0.f; acc[1][0] = 0.f; acc[1][1] = 0.f;
  bf16x8 zc = (short)0;

  while (rem){
    int k0 = __ffs(rem) - 1; rem &= rem - 1;
    int k1 = -1, k2 = -1;
    if (rem){ k1 = __ffs(rem) - 1; rem &= rem - 1; }
    if (rem){ k2 = __ffs(rem) - 1; rem &= rem - 1; }
    int a0v = nbr[(size_t)k0*NVOX + vb + m];
    int b0v = nbr[(size_t)k0*NVOX + vb + 16 + m];
    int a1 = -1, b1 = -1, a2 = -1, b2 = -1;
    if (k1 >= 0){
      int av = nbr[(size_t)k1*NVOX + vb + m];
      int bv = nbr[(size_t)k1*NVOX + vb + 16 + m];
      a1 = ((rem0 >> k1) & 1) ? av : -1;
      b1 = ((rem1 >> k1) & 1) ? bv : -1;
    }
    if (k2 >= 0){
      int av = nbr[(size_t)k2*NVOX + vb + m];
      int bv = nbr[(size_t)k2*NVOX + vb + 16 + m];
      a2 = ((rem0 >> k2) & 1) ? av : -1;
      b2 = ((rem1 >> k2) & 1) ? bv : -1;
    }
    int a0 = ((rem0 >> k0) & 1) ? a0v : -1;
    int b0 = ((rem1 >> k0) & 1) ? b0v : -1;
    bf16x8 A0, B0, A1 = zc, B1 = zc, A2 = zc, B2 = zc, t;
    bf16x8 w10 = zc, w11 = zc, w20 = zc, w21 = zc;
    t = *(const bf16x8*)(fin + (size_t)(a0 < 0 ? 0 : a0)*32 + q*8); A0 = (a0 < 0) ? zc : t;
    t = *(const bf16x8*)(fin + (size_t)(b0 < 0 ? 0 : b0)*32 + q*8); B0 = (b0 < 0) ? zc : t;
    bf16x8 w00 = *(const bf16x8*)(w2 + (size_t)(k0*32 + m)*32 + q*8);
    bf16x8 w01 = *(const bf16x8*)(w2 + (size_t)(k0*32 + 16 + m)*32 + q*8);
    if (k1 >= 0){
      t = *(const bf16x8*)(fin + (size_t)(a1 < 0 ? 0 : a1)*32 + q*8); A1 = (a1 < 0) ? zc : t;
      t = *(const bf16x8*)(fin + (size_t)(b1 < 0 ? 0 : b1)*32 + q*8); B1 = (b1 < 0) ? zc : t;
      w10 = *(const bf16x8*)(w2 + (size_t)(k1*32 + m)*32 + q*8);
      w11 = *(const bf16x8*)(w2 + (size_t)(k1*32 + 16 + m)*32 + q*8);
    }
    if (k2 >= 0){
      t = *(const bf16x8*)(fin + (size_t)(a2 < 0 ? 0 : a2)*32 + q*8); A2 = (a2 < 0) ? zc : t;
      t = *(const bf16x8*)(fin + (size_t)(b2 < 0 ? 0 : b2)*32 + q*8); B2 = (b2 < 0) ? zc : t;
      w20 = *(const bf16x8*)(w2 + (size_t)(k2*32 + m)*32 + q*8);
      w21 = *(const bf16x8*)(w2 + (size_t)(k2*32 + 16 + m)*32 + q*8);
    }
    acc[0][0] = __builtin_amdgcn_mfma_f32_16x16x32_bf16(w00, A0, acc[0][0], 0, 0, 0);
    acc[0][1] = __builtin_amdgcn_mfma_f32_16x16x32_bf16(w01, A0, acc[0][1], 0, 0, 0);
    acc[1][0] = __builtin_amdgcn_mfma_f32_16x16x32_bf16(w00, B0, acc[1][0], 0, 0, 0);
    acc[1][1] = __builtin_amdgcn_mfma_f32_16x16x32_bf16(w01, B0, acc[1][1], 0, 0, 0);
    if (k1 >= 0){
      acc[0][0] = __builtin_amdgcn_mfma_f32_16x16x32_bf16(w10, A1, acc[0][0], 0, 0, 0);
      acc[0][1] = __builtin_amdgcn_mfma_f32_16x16x32_bf16(w11, A1, acc[0][1], 0, 0, 0);
      acc[1][0] = __builtin_amdgcn_mfma_f32_16x16x32_bf16(w10, B1, acc[1][0], 0, 0, 0);
      acc[1][1] = __builtin_amdgcn_mfma_f32_16x16x32_bf16(w11, B1, acc[1][1], 0, 0, 0);
    }
    if (k2 >= 0){
      acc[0][0] = __builtin_amdgcn_mfma_f32_16x16x32_bf16(w20, A2, acc[0][0], 0, 0, 0);
      acc[0][1] = __builtin_amdgcn_mfma_f32_16x16x32_bf16(w21, A2, acc[0][1], 0, 0, 0);
      acc[1][0] = __builtin_amdgcn_mfma_f32_16x16x32_bf16(w20, B2, acc[1][0], 0, 0, 0);
      acc[1][1] = __builtin_amdgcn_mfma_f32_16x16x32_bf16(w21, B2, acc[1][1], 0, 0, 0);
    }
  }

  float4 g0v{0,0,0,0}, g1v{0,0,0,0}, b0v{0,0,0,0}, b1v{0,0,0,0};
  if (MODE == 1){
    g0v = ld4(lng + q*4);  g1v = ld4(lng + 16 + q*4);
    b0v = ld4(lnb + q*4);  b1v = ld4(lnb + 16 + q*4);
  }
  #pragma unroll
  for (int t = 0; t < 2; ++t){
    int vox = vb + t*16 + m;
    float x0[4], x1[4];
    #pragma unroll
    for (int r = 0; r < 4; ++r){
      x0[r] = fmaxf(acc[t][0][r], 0.f);
      x1[r] = fmaxf(acc[t][1][r], 0.f);
    }
    if (MODE == 1){
      uint2 sk0 = *(const uint2*)(fin + (size_t)vox*32 + q*4);
      uint2 sk1 = *(const uint2*)(fin + (size_t)vox*32 + 16 + q*4);
      x0[0] += blo(sk0.x); x0[1] += bhi(sk0.x); x0[2] += blo(sk0.y); x0[3] += bhi(sk0.y);
      x1[0] += blo(sk1.x); x1[1] += bhi(sk1.x); x1[2] += blo(sk1.y); x1[3] += bhi(sk1.y);
      float s = (x0[0]+x0[1]+x0[2]+x0[3]) + (x1[0]+x1[1]+x1[2]+x1[3]);
      s += __shfl_xor(s, 16);
      s += __shfl_xor(s, 32);
      float mean = s * (1.f/32.f);
      float v2 = 0.f;
      #pragma unroll
      for (int r = 0; r < 4; ++r){
        x0[r] -= mean; x1[r] -= mean;
        v2 += x0[r]*x0[r] + x1[r]*x1[r];
      }
      v2 += __shfl_xor(v2, 16);
      v2 += __shfl_xor(v2, 32);
      float rs = 1.f / sqrtf(v2*(1.f/32.f) + 1e-5f);
      x0[0] = x0[0]*rs*g0v.x + b0v.x; x0[1] = x0[1]*rs*g0v.y + b0v.y;
      x0[2] = x0[2]*rs*g0v.z + b0v.z; x0[3] = x0[3]*rs*g0v.w + b0v.w;
      x1[0] = x1[0]*rs*g1v.x + b1v.x; x1[1] = x1[1]*rs*g1v.y + b1v.y;
      x1[2] = x1[2]*rs*g1v.z + b1v.z; x1[3] = x1[3]*rs*g1v.w + b1v.w;
    }
    st4b(fout + (size_t)vox*32 + q*4,      float4{x0[0],x0[1],x0[2],x0[3]});
    st4b(fout + (size_t)vox*32 + 16 + q*4, float4{x1[0],x1[1],x1[2],x1[3]});
  }
}

// ---- final subm 32->1 + bn. 4 threads/voxel (8 ch each), 2-tap batches,
// cross-lane reduce. ----
__global__ __launch_bounds__(256) void k_s4(
    const ushort* __restrict__ fin, const float* __restrict__ w4,
    const int* __restrict__ nbr, const unsigned* __restrict__ gmask16,
    const float* __restrict__ bn4g, const float* __restrict__ bn4b,
    float* __restrict__ occ){
  int tid = blockIdx.x*256 + threadIdx.x;
  int n = tid >> 2;
  int part = tid & 3;
  unsigned rem = gmask16[n >> 4];
  float acc = 0.f;
  while (rem){
    int k0 = __ffs(rem) - 1; rem &= rem - 1;
    int k1 = -1;
    if (rem){ k1 = __ffs(rem) - 1; rem &= rem - 1; }
    int i0 = nbr[(size_t)k0*NVOX + n];
    int i1 = (k1 >= 0) ? nbr[(size_t)k1*NVOX + n] : -1;
    uint4 d0 = *(const uint4*)(fin + (size_t)(i0 < 0 ? 0 : i0)*32 + part*8);
    uint4 d1 = {0,0,0,0};
    if (k1 >= 0) d1 = *(const uint4*)(fin + (size_t)(i1 < 0 ? 0 : i1)*32 + part*8);
    if (i0 >= 0){
      float4 wa = ld4(w4 + k0*32 + part*8);
      float4 wb = ld4(w4 + k0*32 + part*8 + 4);
      acc += blo(d0.x)*wa.x + bhi(d0.x)*wa.y + blo(d0.y)*wa.z + bhi(d0.y)*wa.w
           + blo(d0.z)*wb.x + bhi(d0.z)*wb.y + blo(d0.w)*wb.z + bhi(d0.w)*wb.w;
    }
    if (i1 >= 0){
      float4 wa = ld4(w4 + k1*32 + part*8);
      float4 wb = ld4(w4 + k1*32 + part*8 + 4);
      acc += blo(d1.x)*wa.x + bhi(d1.x)*wa.y + blo(d1.y)*wa.z + bhi(d1.y)*wa.w
           + blo(d1.z)*wb.x + bhi(d1.z)*wb.y + blo(d1.w)*wb.z + bhi(d1.w)*wb.w;
    }
  }
  acc += __shfl_xor(acc, 1, 4);
  acc += __shfl_xor(acc, 2, 4);
  if (part == 0) occ[n] = bn4g[0]*acc*INVS + bn4b[0];
}

extern "C" void kernel_launch(void* const* d_in, const int* in_sizes, int n_in,
                              void* d_out, int out_size, void* d_ws, size_t ws_size,
                              hipStream_t stream){
  const float* feats1 = (const float*)d_in[0];
  const float* feats2 = (const float*)d_in[1];
  const float* feats4 = (const float*)d_in[2];
  const int*   coords = (const int*)d_in[3];
  const float* origin = (const float*)d_in[4];
  const float* vsz    = (const float*)d_in[5];
  const float* KR     = (const float*)d_in[6];
  const float* w_f1 = (const float*)d_in[7];  const float* b_f1 = (const float*)d_in[8];
  const float* w_f2 = (const float*)d_in[9];  const float* b_f2 = (const float*)d_in[10];
  const float* w_f4 = (const float*)d_in[11]; const float* b_f4 = (const float*)d_in[12];
  const float* w_dn = (const float*)d_in[13]; const float* b_dn = (const float*)d_in[14];
  const float* w_p[4] = {(const float*)d_in[15], (const float*)d_in[17],
                         (const float*)d_in[19], (const float*)d_in[21]};
  const float* b_p[4] = {(const float*)d_in[16], (const float*)d_in[18],
                         (const float*)d_in[20], (const float*)d_in[22]};
  const float* bn0g = (const float*)d_in[23]; const float* bn0b = (const float*)d_in[24];
  const float* w_elan = (const float*)d_in[25];
  const float* w_s1 = (const float*)d_in[26]; const float* ln1g = (const float*)d_in[27]; const float* ln1b = (const float*)d_in[28];
  const float* w_s2 = (const float*)d_in[29]; const float* ln2g = (const float*)d_in[30]; const float* ln2b = (const float*)d_in[31];
  const float* w_s3 = (const float*)d_in[32]; const float* ln3g = (const float*)d_in[33]; const float* ln3b = (const float*)d_in[34];
  const float* w_s4 = (const float*)d_in[35]; const float* bn4g = (const float*)d_in[36]; const float* bn4b = (const float*)d_in[37];
  const int* stage  = (const int*)d_in[38];
  float* out = (float*)d_out;
  char* base = (char*)d_ws;

  size_t off = 0;
  auto alloc = [&](size_t bytes)->char*{ char* p = base + off; off += (bytes + 255) & ~(size_t)255; return p; };
  ushort* nhwc1 = (ushort*)alloc((size_t)9*30*40*96*2);
  ushort* nhwc2 = (ushort*)alloc((size_t)9*60*80*64*2);
  ushort* nhwc4 = (ushort*)alloc((size_t)9*120*160*32*2);
  ushort* t1    = (ushort*)alloc((size_t)9*30*40*80*2);
  ushort* t4    = (ushort*)alloc((size_t)9*120*160*24*2);
  ushort* fcat  = (ushort*)alloc((size_t)9*60*80*160*2);
  ushort* A     = (ushort*)alloc((size_t)9*60*80*32*2);
  ushort* B     = (ushort*)alloc((size_t)9*60*80*32*2);
  ushort* Fb0   = (ushort*)alloc((size_t)NVOX*32*2);
  ushort* Fb1   = (ushort*)alloc((size_t)NVOX*32*2);
  int*    nbr   = (int*)alloc((size_t)27*NVOX*4);
  int*    grid  = (int*)alloc((size_t)GS*GS*GS*4);
  int*    scn   = (int*)alloc((size_t)NVOX*3*4);
  unsigned* gmask16 = (unsigned*)alloc((size_t)(NVOX/16)*4);
  ushort* wf1   = (ushort*)alloc(9*3*80*32*2);
  ushort* wf2   = (ushort*)alloc(9*2*48*32*2);
  ushort* wf4   = (ushort*)alloc(9*1*32*32*2);
  ushort* wdn   = (ushort*)alloc(1*5*32*32*2);
  ushort* wp0   = (ushort*)alloc(9*1*32*32*2);
  ushort* wp1   = (ushort*)alloc(9*1*32*32*2);
  ushort* wp2   = (ushort*)alloc(9*1*32*32*2);
  ushort* wp3   = (ushort*)alloc(9*1*32*32*2);
  ushort* w2e   = (ushort*)alloc(27*1024*2);
  ushort* w2s1  = (ushort*)alloc(27*1024*2);
  ushort* w2s2  = (ushort*)alloc(27*1024*2);
  ushort* w2s3  = (ushort*)alloc(27*1024*2);
  ushort* sidx  = (ushort*)alloc((size_t)VN*NVOX*2);     // 2.36 MB
  float4* swf   = (float4*)alloc((size_t)VN*NVOX*16);    // 18.9 MB, fp32 weights

  auto nb = [](int total){ return (total + 255)/256; };

  // 1. mega prep
  k_prep<<<8012,256,0,stream>>>(
      w_f1, w_f2, w_f4, w_dn, w_p[0], w_p[1], w_p[2], w_p[3],
      w_elan, w_s1, w_s2, w_s3,
      wf1, wf2, wf4, wdn, wp0, wp1, wp2, wp3, w2e, w2s1, w2s2, w2s3, grid,
      feats1, feats2, feats4, nhwc1, nhwc2, nhwc4);

  // 2. head convs (f1 reg-path, f4 LDS-tiled, f2 reg-path) + scatter (projection once/voxel)
  k_heads<<<169 + 720 + 675 + 512,256,0,stream>>>(
      nhwc1, wf1, b_f1, t1,
      nhwc2, wf2, b_f2, fcat,
      nhwc4, wf4, b_f4, t4,
      coords, stage, grid, scn, out + NVOX,
      origin, vsz, KR, sidx, swf, out + 5*NVOX);

  // 3. respool + nbr build
  k_respool_nbr<<<5063 + 2048,256,0,stream>>>(t1, t4, fcat, scn, grid, nbr, gmask16);

  // 4-8. down conv (1x1 reg-path) + 4 LDS-tiled residual convs
  k_conv_mfma<5,2,1,1><<<675,256,0,stream>>>(fcat, wdn, b_dn, A, 60, 80, 43200, 32, 32, 0);
  k_conv_lds4<<<675,256,0,stream>>>(A, wp0, b_p[0], B, A);
  k_conv_lds4<<<675,256,0,stream>>>(B, wp1, b_p[1], A, B);
  k_conv_lds4<<<675,256,0,stream>>>(A, wp2, b_p[2], B, A);
  k_conv_lds4<<<675,256,0,stream>>>(B, wp3, b_p[3], A, B);

  // 9. sampling -> F0 (table-driven, fp32 weights)
  k_sample<<<NVOX/32,256,0,stream>>>(A, sidx, swf, out + 5*NVOX, bn0g, bn0b, Fb0);

  // 10-13. sparse conv stack (MT=2, batch-3 taps, swapped operands)
  k_subm_mfma<0><<<NVOX/128,256,0,stream>>>(Fb0, w2e,  nbr, gmask16, nullptr, nullptr, Fb1);
  k_subm_mfma<1><<<NVOX/128,256,0,stream>>>(Fb1, w2s1, nbr, gmask16, ln1g, ln1b, Fb0);
  k_subm_mfma<1><<<NVOX/128,256,0,stream>>>(Fb0, w2s2, nbr, gmask16, ln2g, ln2b, Fb1);
  k_subm_mfma<1><<<NVOX/128,256,0,stream>>>(Fb1, w2s3, nbr, gmask16, ln3g, ln3b, Fb0);

  // 14. final head (4 threads per voxel)
  k_s4<<<NVOX/64,256,0,stream>>>(Fb0, w_s4, nbr, gmask16, bn4g, bn4b, out);
}

// Round 7
// 330.684 us; speedup vs baseline: 1.0438x; 1.0060x over previous
//
#include <hip/hip_runtime.h>
#include <math.h>

#define VN 9
#define NVOX 131072
#define GS 96
static constexpr float INVS = 0.9999950000374997f; // 1/sqrt(1+1e-5)

typedef short bf16x8 __attribute__((ext_vector_type(8)));
typedef float f32x4v __attribute__((ext_vector_type(4)));

__device__ inline float4 ld4(const float* p){ return *reinterpret_cast<const float4*>(p); }

__device__ inline ushort f2b(float f){
  unsigned u = __float_as_uint(f);
  unsigned r = (u + 0x7fffu + ((u >> 16) & 1u)) >> 16;
  return (ushort)r;
}
__device__ inline float b2f(ushort s){ return __uint_as_float(((unsigned)s) << 16); }
__device__ inline float blo(unsigned u){ return __uint_as_float(u << 16); }
__device__ inline float bhi(unsigned u){ return __uint_as_float(u & 0xffff0000u); }

__device__ inline float4 ld4b(const ushort* p){
  uint2 u = *reinterpret_cast<const uint2*>(p);
  float4 r; r.x = blo(u.x); r.y = bhi(u.x); r.z = blo(u.y); r.w = bhi(u.y); return r;
}
__device__ inline void st4b(ushort* p, float4 v){
  uint2 u;
  u.x = (unsigned)f2b(v.x) | ((unsigned)f2b(v.y) << 16);
  u.y = (unsigned)f2b(v.z) | ((unsigned)f2b(v.w) << 16);
  *reinterpret_cast<uint2*>(p) = u;
}

// ---- weight prep helpers ----
__device__ inline void wprep2_dev(const float* __restrict__ w, ushort* __restrict__ o,
                                  int Cout, int Cin, int K, int CK, int CoutPad, int tid){
  int ci32 = tid & 31;
  int co = (tid >> 5) % CoutPad;
  int ck = (tid / (32*CoutPad)) % CK;
  int tap = tid / (32*CoutPad*CK);
  int ci = ck*32 + ci32;
  float v = 0.f;
  if (co < Cout && ci < Cin) v = w[(size_t)(co*Cin + ci)*K*K + tap];
  o[tid] = f2b(v);
}
__device__ inline void wprep_dev(const float* __restrict__ w, ushort* __restrict__ o, int tid){
  int k = tid >> 10;
  int r = tid & 1023;
  int co = r >> 5;
  int ci = r & 31;
  o[tid] = f2b(w[k*1024 + ci*32 + co]);
}

// ---- NCHW fp32 -> NHWC bf16 via LDS tile ----
__device__ inline void nhwc_tile_dev(const float* __restrict__ in, ushort* __restrict__ out,
                                     int C, int Cpad, int HW, int tile, int tilesPerV,
                                     float* lds, int tx){
  int v  = tile / tilesPerV;
  int p0 = (tile - v*tilesPerV) * 64;
  const float* ip = in + (size_t)v*C*HW + p0;
  int iters = Cpad >> 2;
  for (int i = 0; i < iters; ++i){
    int idx = i*256 + tx;
    int c = idx >> 6;
    int p = idx & 63;
    float val = 0.f;
    if (c < C && (p0 + p) < HW) val = ip[(size_t)c*HW + p];
    lds[c*65 + p] = val;
  }
  __syncthreads();
  int groups = Cpad >> 2;
  int tot = 64*groups;
  for (int basei = 0; basei < tot; basei += 256){
    int idx = basei + tx;
    if (idx < tot){
      int g  = idx % groups;
      int px = idx / groups;
      if ((p0 + px) < HW){
        float4 r;
        r.x = lds[(g*4+0)*65 + px];
        r.y = lds[(g*4+1)*65 + px];
        r.z = lds[(g*4+2)*65 + px];
        r.w = lds[(g*4+3)*65 + px];
        st4b(out + (size_t)(v*HW + p0 + px)*Cpad + g*4, r);
      }
    }
  }
}

// ---- mega prep kernel: weight preps + grid clear + NHWC transposes ----
__global__ __launch_bounds__(256) void k_prep(
    const float* wf1s, const float* wf2s, const float* wf4s, const float* wdns,
    const float* wp0s, const float* wp1s, const float* wp2s, const float* wp3s,
    const float* wes, const float* ws1s, const float* ws2s, const float* ws3s,
    ushort* wf1, ushort* wf2, ushort* wf4, ushort* wdn,
    ushort* wp0, ushort* wp1, ushort* wp2, ushort* wp3,
    ushort* w2e, ushort* w2s1, ushort* w2s2, ushort* w2s3,
    int* grid,
    const float* f1, const float* f2, const float* f4,
    ushort* o1, ushort* o2, ushort* o4){
  __shared__ float lds[96*65];
  int bid = blockIdx.x;
  int tx = threadIdx.x;
  if (bid < 270){ int t = bid*256+tx; if (t < 69120) wprep2_dev(wf1s, wf1, 80, 80, 3, 3, 80, t); return; }
  bid -= 270;
  if (bid < 108){ int t = bid*256+tx; if (t < 27648) wprep2_dev(wf2s, wf2, 40, 40, 3, 2, 48, t); return; }
  bid -= 108;
  if (bid < 36){ int t = bid*256+tx; if (t < 9216) wprep2_dev(wf4s, wf4, 24, 24, 3, 1, 32, t); return; }
  bid -= 36;
  if (bid < 20){ int t = bid*256+tx; if (t < 5120) wprep2_dev(wdns, wdn, 32, 144, 1, 5, 32, t); return; }
  bid -= 20;
  if (bid < 36){ int t = bid*256+tx; if (t < 9216) wprep2_dev(wp0s, wp0, 32, 32, 3, 1, 32, t); return; }
  bid -= 36;
  if (bid < 36){ int t = bid*256+tx; if (t < 9216) wprep2_dev(wp1s, wp1, 32, 32, 3, 1, 32, t); return; }
  bid -= 36;
  if (bid < 36){ int t = bid*256+tx; if (t < 9216) wprep2_dev(wp2s, wp2, 32, 32, 3, 1, 32, t); return; }
  bid -= 36;
  if (bid < 36){ int t = bid*256+tx; if (t < 9216) wprep2_dev(wp3s, wp3, 32, 32, 3, 1, 32, t); return; }
  bid -= 36;
  if (bid < 108){ int t = bid*256+tx; if (t < 27648) wprep_dev(wes, w2e, t); return; }
  bid -= 108;
  if (bid < 108){ int t = bid*256+tx; if (t < 27648) wprep_dev(ws1s, w2s1, t); return; }
  bid -= 108;
  if (bid < 108){ int t = bid*256+tx; if (t < 27648) wprep_dev(ws2s, w2s2, t); return; }
  bid -= 108;
  if (bid < 108){ int t = bid*256+tx; if (t < 27648) wprep_dev(ws3s, w2s3, t); return; }
  bid -= 108;
  if (bid < 3456){ int t = bid*256+tx; if (t < GS*GS*GS) grid[t] = -1; return; }
  bid -= 3456;
  if (bid < 171){ nhwc_tile_dev(f1, o1, 80, 96, 1200, bid, 19, lds, tx); return; }
  bid -= 171;
  if (bid < 675){ nhwc_tile_dev(f2, o2, 40, 64, 4800, bid, 75, lds, tx); return; }
  bid -= 675;
  if (bid < 2700){ nhwc_tile_dev(f4, o4, 24, 32, 19200, bid, 300, lds, tx); }
}

// ---- implicit-GEMM conv via MFMA, register path (for f1/f2) ----
// Operand-swapped: mfma(Bf, Af) -> D[row=co(q*4+r)][col=px(m)]; epilogue
// stores 4 consecutive channels per lane as one uint2.
template<int CK, int NT, int TAPS, int MT>
__device__ void conv_dev(
    const ushort* __restrict__ fin, const ushort* __restrict__ w2,
    const float* __restrict__ bias, ushort* __restrict__ outp,
    int H, int W, int total, int Cout, int outStride, int outOff,
    int bid, int tid){
  constexpr int CIN = CK*32;
  constexpr int COP = NT*16;
  int lane = tid & 63;
  int wave = tid >> 6;
  int vbase = bid*(MT*64) + wave*(MT*16);
  int m = lane & 15, q = lane >> 4;
  int HW = H*W;
  int p[MT], py[MT], px[MT]; bool pin[MT];
  #pragma unroll
  for (int t = 0; t < MT; ++t){
    int pp = vbase + t*16 + m;
    pin[t] = pp < total;
    if (pp > total-1) pp = total-1;
    p[t] = pp;
    int v = pp / HW; int rem = pp - v*HW;
    int y = rem / W;
    py[t] = y; px[t] = rem - y*W;
  }
  f32x4v acc[MT][NT];
  #pragma unroll
  for (int t = 0; t < MT; ++t)
    #pragma unroll
    for (int n = 0; n < NT; ++n) acc[t][n] = 0.f;
  bf16x8 z = (short)0;

  #pragma unroll 1
  for (int tap = 0; tap < TAPS; ++tap){
    int dy = (TAPS == 9) ? tap/3 - 1 : 0;
    int dx = (TAPS == 9) ? tap%3 - 1 : 0;
    int off = dy*W + dx;
    bool val[MT];
    #pragma unroll
    for (int t = 0; t < MT; ++t)
      val[t] = pin[t] && ((unsigned)(py[t]+dy) < (unsigned)H)
                      && ((unsigned)(px[t]+dx) < (unsigned)W);
    #pragma unroll
    for (int ck = 0; ck < CK; ++ck){
      bf16x8 Af[MT], Bf[NT];
      #pragma unroll
      for (int t = 0; t < MT; ++t){
        size_t idx = val[t] ? (size_t)(p[t]+off) : 0;
        bf16x8 a = *(const bf16x8*)(fin + idx*CIN + ck*32 + q*8);
        Af[t] = val[t] ? a : z;
      }
      #pragma unroll
      for (int n = 0; n < NT; ++n)
        Bf[n] = *(const bf16x8*)(w2 + ((size_t)((tap*CK+ck)*COP + n*16 + m))*32 + q*8);
      #pragma unroll
      for (int t = 0; t < MT; ++t)
        #pragma unroll
        for (int n = 0; n < NT; ++n)
          acc[t][n] = __builtin_amdgcn_mfma_f32_16x16x32_bf16(Bf[n], Af[t], acc[t][n], 0, 0, 0);
    }
  }

  #pragma unroll
  for (int n = 0; n < NT; ++n){
    int co4 = n*16 + q*4;
    bool cok = co4 < Cout;   // all Couts are multiples of 4
    float4 bs = cok ? ld4(bias + co4) : float4{0.f,0.f,0.f,0.f};
    #pragma unroll
    for (int t = 0; t < MT; ++t){
      int pp = vbase + t*16 + m;
      if (pp < total && cok){
        float4 v;
        v.x = fmaxf(acc[t][n][0] + bs.x, 0.f);
        v.y = fmaxf(acc[t][n][1] + bs.y, 0.f);
        v.z = fmaxf(acc[t][n][2] + bs.z, 0.f);
        v.w = fmaxf(acc[t][n][3] + bs.w, 0.f);
        st4b(outp + (size_t)pp*outStride + outOff + co4, v);
      }
    }
  }
}

// ---- LDS-tiled 3x3 conv, CIN=32. Tile TH x 16 px, halo patch (TH+2)x18x36 in LDS.
// Operand-swapped MFMA; uint2 stores/skip-loads.
template<int TH, int NT>
__device__ void conv_lds_dev(
    const ushort* __restrict__ fin, const ushort* __restrict__ w2,
    const float* __restrict__ bias, ushort* __restrict__ outp,
    int H, int W, int Cout, int outStride,
    const ushort* __restrict__ skipin, ushort* lds, int bid, int tid){
  constexpr int RPW = TH/4;
  constexpr int PS = 36;             // padded channel stride (18 banks -> 2-way free)
  int xtiles = W >> 4;
  int ytiles = (H + TH - 1) / TH;
  int v  = bid / (ytiles*xtiles);
  int rem = bid - v*(ytiles*xtiles);
  int ty = (rem / xtiles) * TH;
  int tx = (rem % xtiles) * 16;
  const ushort* ibase = fin + (size_t)v*H*W*32;
  // load halo patch (TH+2) x 18 x 32ch
  for (int i = tid; i < (TH+2)*18*4; i += 256){
    int chunk = i & 3;
    int pxi = i >> 2;
    int ly = pxi / 18, lx = pxi - ly*18;
    int gy = ty + ly - 1, gx = tx + lx - 1;
    uint4 d = {0,0,0,0};
    if ((unsigned)gy < (unsigned)H && (unsigned)gx < (unsigned)W)
      d = *(const uint4*)(ibase + ((size_t)gy*W + gx)*32 + chunk*8);
    *(uint4*)(lds + (size_t)(ly*18 + lx)*PS + chunk*8) = d;
  }
  __syncthreads();
  int lane = tid & 63;
  int wave = tid >> 6;
  int m = lane & 15, q = lane >> 4;
  f32x4v acc[RPW][NT];
  #pragma unroll
  for (int t = 0; t < RPW; ++t)
    #pragma unroll
    for (int n = 0; n < NT; ++n) acc[t][n] = 0.f;

  #pragma unroll 1
  for (int tap = 0; tap < 9; ++tap){
    int dy = tap/3 - 1, dx = tap%3 - 1;
    bf16x8 Af[RPW], Bf[NT];
    #pragma unroll
    for (int t = 0; t < RPW; ++t){
      int ly = wave*RPW + t + 1 + dy;
      int lx = m + 1 + dx;
      Af[t] = *(const bf16x8*)(lds + (size_t)(ly*18 + lx)*PS + q*8);
    }
    #pragma unroll
    for (int n = 0; n < NT; ++n)
      Bf[n] = *(const bf16x8*)(w2 + ((size_t)(tap*(NT*16) + n*16 + m))*32 + q*8);
    #pragma unroll
    for (int t = 0; t < RPW; ++t)
      #pragma unroll
      for (int n = 0; n < NT; ++n)
        acc[t][n] = __builtin_amdgcn_mfma_f32_16x16x32_bf16(Bf[n], Af[t], acc[t][n], 0, 0, 0);
  }

  // epilogue: lane m = px-in-tile, acc[t][n][r] = channel n*16+q*4+r
  #pragma unroll
  for (int n = 0; n < NT; ++n){
    int co4 = n*16 + q*4;
    bool cok = co4 < Cout;
    float4 bs = cok ? ld4(bias + co4) : float4{0.f,0.f,0.f,0.f};
    #pragma unroll
    for (int t = 0; t < RPW; ++t){
      int y = ty + wave*RPW + t;
      int x = tx + m;
      if (y < H && cok){
        size_t pp = (size_t)(v*H + y)*W + x;
        float4 val;
        val.x = fmaxf(acc[t][n][0] + bs.x, 0.f);
        val.y = fmaxf(acc[t][n][1] + bs.y, 0.f);
        val.z = fmaxf(acc[t][n][2] + bs.z, 0.f);
        val.w = fmaxf(acc[t][n][3] + bs.w, 0.f);
        if (skipin){
          float4 sk = ld4b(skipin + pp*32 + co4);
          val.x += sk.x; val.y += sk.y; val.z += sk.z; val.w += sk.w;
        }
        st4b(outp + pp*outStride + co4, val);
      }
    }
  }
}

// chain conv: TH=4 -> patch 6x18x36 = 7.8 KB, 675 blocks
__global__ __launch_bounds__(256) void k_conv_lds4(
    const ushort* __restrict__ fin, const ushort* __restrict__ w2,
    const float* __restrict__ bias, ushort* __restrict__ outp,
    const ushort* __restrict__ skipin){
  __shared__ ushort lds[6*18*36];
  conv_lds_dev<4,2>(fin, w2, bias, outp, 60, 80, 32, 32, skipin, lds, blockIdx.x, threadIdx.x);
}

// ---- FUSED: down 1x1 (160->32) over 6x18 halo into LDS, then p0 3x3 from LDS.
// A intermediate never touches global. Halo recompute: +69% on the cheap 1x1.
// Per-px accumulation order identical to the standalone kernels -> bitwise same.
__global__ __launch_bounds__(256) void k_down_p0(
    const ushort* __restrict__ fcat, const ushort* __restrict__ wdn,
    const float* __restrict__ b_dn, const ushort* __restrict__ wp0,
    const float* __restrict__ b_p0, ushort* __restrict__ outB){
  __shared__ ushort ldsA[6*18*36];
  int bid = blockIdx.x;
  int tid = threadIdx.x;
  int v  = bid / 75;
  int rem = bid - v*75;
  int ty = (rem / 5) * 4;
  int tx = (rem % 5) * 16;
  int lane = tid & 63;
  int wave = tid >> 6;
  int m = lane & 15, q = lane >> 4;
  bf16x8 z = (short)0;

  // stage 1: down conv over 108 halo px (6x18), results -> ldsA (bf16)
  #pragma unroll
  for (int t = 0; t < 2; ++t){
    int hp = (wave*2 + t)*16 + m;      // 0..127; valid < 108
    int hpc = hp < 108 ? hp : 107;
    int ly = hpc / 18, lx = hpc - ly*18;
    int gy = ty + ly - 1, gx = tx + lx - 1;
    bool ok = (hp < 108) && ((unsigned)gy < 60u) && ((unsigned)gx < 80u);
    size_t pbase = ((size_t)(v*60 + (ok ? gy : 0))*80 + (ok ? gx : 0))*160;
    f32x4v acc0 = 0.f, acc1 = 0.f;
    #pragma unroll
    for (int ck = 0; ck < 5; ++ck){
      bf16x8 a = *(const bf16x8*)(fcat + pbase + ck*32 + q*8);
      if (!ok) a = z;
      bf16x8 w0 = *(const bf16x8*)(wdn + ((size_t)(ck*32 + m))*32 + q*8);
      bf16x8 w1 = *(const bf16x8*)(wdn + ((size_t)(ck*32 + 16 + m))*32 + q*8);
      acc0 = __builtin_amdgcn_mfma_f32_16x16x32_bf16(w0, a, acc0, 0, 0, 0);
      acc1 = __builtin_amdgcn_mfma_f32_16x16x32_bf16(w1, a, acc1, 0, 0, 0);
    }
    if (hp < 108){
      float4 bs0 = ld4(b_dn + q*4);
      float4 bs1 = ld4(b_dn + 16 + q*4);
      float4 v0, v1;
      v0.x = ok ? fmaxf(acc0[0] + bs0.x, 0.f) : 0.f;
      v0.y = ok ? fmaxf(acc0[1] + bs0.y, 0.f) : 0.f;
      v0.z = ok ? fmaxf(acc0[2] + bs0.z, 0.f) : 0.f;
      v0.w = ok ? fmaxf(acc0[3] + bs0.w, 0.f) : 0.f;
      v1.x = ok ? fmaxf(acc1[0] + bs1.x, 0.f) : 0.f;
      v1.y = ok ? fmaxf(acc1[1] + bs1.y, 0.f) : 0.f;
      v1.z = ok ? fmaxf(acc1[2] + bs1.z, 0.f) : 0.f;
      v1.w = ok ? fmaxf(acc1[3] + bs1.w, 0.f) : 0.f;
      st4b(ldsA + (size_t)(ly*18 + lx)*36 + q*4,      v0);
      st4b(ldsA + (size_t)(ly*18 + lx)*36 + 16 + q*4, v1);
    }
  }
  __syncthreads();

  // stage 2: p0 3x3 from ldsA, skip from ldsA center, out -> global B
  f32x4v pacc0 = 0.f, pacc1 = 0.f;
  #pragma unroll 1
  for (int tap = 0; tap < 9; ++tap){
    int dy = tap/3 - 1, dx = tap%3 - 1;
    bf16x8 Af = *(const bf16x8*)(ldsA + (size_t)((wave+1+dy)*18 + (m+1+dx))*36 + q*8);
    bf16x8 B0 = *(const bf16x8*)(wp0 + ((size_t)(tap*32 + m))*32 + q*8);
    bf16x8 B1 = *(const bf16x8*)(wp0 + ((size_t)(tap*32 + 16 + m))*32 + q*8);
    pacc0 = __builtin_amdgcn_mfma_f32_16x16x32_bf16(B0, Af, pacc0, 0, 0, 0);
    pacc1 = __builtin_amdgcn_mfma_f32_16x16x32_bf16(B1, Af, pacc1, 0, 0, 0);
  }
  int y = ty + wave, x = tx + m;
  size_t pp = (size_t)(v*60 + y)*80 + x;
  #pragma unroll
  for (int n = 0; n < 2; ++n){
    int co4 = n*16 + q*4;
    float4 bs = ld4(b_p0 + co4);
    f32x4v& pa = n ? pacc1 : pacc0;
    float4 sk = ld4b(ldsA + (size_t)((wave+1)*18 + (m+1))*36 + co4);
    float4 val;
    val.x = fmaxf(pa[0] + bs.x, 0.f) + sk.x;
    val.y = fmaxf(pa[1] + bs.y, 0.f) + sk.y;
    val.z = fmaxf(pa[2] + bs.z, 0.f) + sk.z;
    val.w = fmaxf(pa[3] + bs.w, 0.f) + sk.w;
    st4b(outB + pp*32 + co4, val);
  }
}

// ---- FUSED: p2 3x3 over 6x18 interior (input staged 8x20) into LDS, then p3
// 3x3 from LDS. OOB p2 outputs forced to 0 (zero-pad semantics preserved).
__global__ __launch_bounds__(256) void k_p2_p3(
    const ushort* __restrict__ finA, const ushort* __restrict__ wp2,
    const float* __restrict__ b_p2, const ushort* __restrict__ wp3,
    const float* __restrict__ b_p3, ushort* __restrict__ outB){
  __shared__ ushort ldsIn[8*20*36];
  __shared__ ushort ldsMid[6*18*36];
  int bid = blockIdx.x;
  int tid = threadIdx.x;
  int v  = bid / 75;
  int rem = bid - v*75;
  int ty = (rem / 5) * 4;
  int tx = (rem % 5) * 16;
  // stage A 8x20 halo
  for (int i = tid; i < 8*20*4; i += 256){
    int chunk = i & 3;
    int pxi = i >> 2;
    int ly = pxi / 20, lx = pxi - ly*20;
    int gy = ty + ly - 2, gx = tx + lx - 2;
    uint4 d = {0,0,0,0};
    if ((unsigned)gy < 60u && (unsigned)gx < 80u)
      d = *(const uint4*)(finA + ((size_t)(v*60 + gy)*80 + gx)*32 + chunk*8);
    *(uint4*)(ldsIn + (size_t)(ly*20 + lx)*36 + chunk*8) = d;
  }
  __syncthreads();
  int lane = tid & 63;
  int wave = tid >> 6;
  int m = lane & 15, q = lane >> 4;

  // p2 over 108 px (6x18) -> ldsMid
  #pragma unroll
  for (int t = 0; t < 2; ++t){
    int hp = (wave*2 + t)*16 + m;
    int hpc = hp < 108 ? hp : 107;
    int ly = hpc / 18, lx = hpc - ly*18;
    int gy = ty + ly - 1, gx = tx + lx - 1;
    bool ok = (hp < 108) && ((unsigned)gy < 60u) && ((unsigned)gx < 80u);
    f32x4v acc0 = 0.f, acc1 = 0.f;
    #pragma unroll 1
    for (int tap = 0; tap < 9; ++tap){
      int dy = tap/3 - 1, dx = tap%3 - 1;
      bf16x8 a = *(const bf16x8*)(ldsIn + (size_t)((ly+dy+1)*20 + (lx+dx+1))*36 + q*8);
      bf16x8 w0 = *(const bf16x8*)(wp2 + ((size_t)(tap*32 + m))*32 + q*8);
      bf16x8 w1 = *(const bf16x8*)(wp2 + ((size_t)(tap*32 + 16 + m))*32 + q*8);
      acc0 = __builtin_amdgcn_mfma_f32_16x16x32_bf16(w0, a, acc0, 0, 0, 0);
      acc1 = __builtin_amdgcn_mfma_f32_16x16x32_bf16(w1, a, acc1, 0, 0, 0);
    }
    if (hp < 108){
      float4 bs0 = ld4(b_p2 + q*4);
      float4 bs1 = ld4(b_p2 + 16 + q*4);
      float4 sk0 = ld4b(ldsIn + (size_t)((ly+1)*20 + (lx+1))*36 + q*4);
      float4 sk1 = ld4b(ldsIn + (size_t)((ly+1)*20 + (lx+1))*36 + 16 + q*4);
      float4 v0, v1;
      v0.x = ok ? fmaxf(acc0[0] + bs0.x, 0.f) + sk0.x : 0.f;
      v0.y = ok ? fmaxf(acc0[1] + bs0.y, 0.f) + sk0.y : 0.f;
      v0.z = ok ? fmaxf(acc0[2] + bs0.z, 0.f) + sk0.z : 0.f;
      v0.w = ok ? fmaxf(acc0[3] + bs0.w, 0.f) + sk0.w : 0.f;
      v1.x = ok ? fmaxf(acc1[0] + bs1.x, 0.f) + sk1.x : 0.f;
      v1.y = ok ? fmaxf(acc1[1] + bs1.y, 0.f) + sk1.y : 0.f;
      v1.z = ok ? fmaxf(acc1[2] + bs1.z, 0.f) + sk1.z : 0.f;
      v1.w = ok ? fmaxf(acc1[3] + bs1.w, 0.f) + sk1.w : 0.f;
      st4b(ldsMid + (size_t)(ly*18 + lx)*36 + q*4,      v0);
      st4b(ldsMid + (size_t)(ly*18 + lx)*36 + 16 + q*4, v1);
    }
  }
  __syncthreads();

  // p3 from ldsMid, skip from ldsMid center, out -> global
  f32x4v pacc0 = 0.f, pacc1 = 0.f;
  #pragma unroll 1
  for (int tap = 0; tap < 9; ++tap){
    int dy = tap/3 - 1, dx = tap%3 - 1;
    bf16x8 a = *(const bf16x8*)(ldsMid + (size_t)((wave+1+dy)*18 + (m+1+dx))*36 + q*8);
    bf16x8 w0 = *(const bf16x8*)(wp3 + ((size_t)(tap*32 + m))*32 + q*8);
    bf16x8 w1 = *(const bf16x8*)(wp3 + ((size_t)(tap*32 + 16 + m))*32 + q*8);
    pacc0 = __builtin_amdgcn_mfma_f32_16x16x32_bf16(w0, a, pacc0, 0, 0, 0);
    pacc1 = __builtin_amdgcn_mfma_f32_16x16x32_bf16(w1, a, pacc1, 0, 0, 0);
  }
  int y = ty + wave, x = tx + m;
  size_t pp = (size_t)(v*60 + y)*80 + x;
  #pragma unroll
  for (int n = 0; n < 2; ++n){
    int co4 = n*16 + q*4;
    float4 bs = ld4(b_p3 + co4);
    f32x4v& pa = n ? pacc1 : pacc0;
    float4 sk = ld4b(ldsMid + (size_t)((wave+1)*18 + (m+1))*36 + co4);
    float4 val;
    val.x = fmaxf(pa[0] + bs.x, 0.f) + sk.x;
    val.y = fmaxf(pa[1] + bs.y, 0.f) + sk.y;
    val.z = fmaxf(pa[2] + bs.z, 0.f) + sk.z;
    val.w = fmaxf(pa[3] + bs.w, 0.f) + sk.w;
    st4b(outB + pp*32 + co4, val);
  }
}

// ---- scatter device: grid scatter + coords + sample table (fp32 weights) + count ----
__device__ void scatter_dev(const int* __restrict__ coords, const int* __restrict__ stage,
                            int* __restrict__ grid, int* __restrict__ scn,
                            float* __restrict__ coords_out,
                            const float* __restrict__ origin, const float* __restrict__ vsz,
                            const float* __restrict__ KR,
                            ushort* __restrict__ sidx, float4* __restrict__ swf,
                            float* __restrict__ cnt, int n){
  int c0 = coords[n*4], c1 = coords[n*4+1], c2 = coords[n*4+2], c3 = coords[n*4+3];
  coords_out[n*4+0] = (float)c0;
  coords_out[n*4+1] = (float)c1;
  coords_out[n*4+2] = (float)c2;
  coords_out[n*4+3] = (float)c3;
  int sh = 2 - stage[0];
  int s1 = c1 >> sh, s2 = c2 >> sh, s3 = c3 >> sh;
  scn[n*3+0] = s1; scn[n*3+1] = s2; scn[n*3+2] = s3;
  grid[(s1*GS + s2)*GS + s3] = n;

  float vs = vsz[0];
  float wx = (float)c1*vs + origin[0];
  float wy = (float)c2*vs + origin[1];
  float wz = (float)c3*vs + origin[2];
  float den = 0.f;
  #pragma unroll 1
  for (int v = 0; v < VN; ++v){
    const float* P = KR + v*12;
    float ix = P[0]*wx + P[1]*wy + P[2]*wz + P[3];
    float iy = P[4]*wx + P[5]*wy + P[6]*wz + P[7];
    float iz = P[8]*wx + P[9]*wy + P[10]*wz + P[11];
    float gx = 2.f*(ix/iz)/159.f - 1.f;   // exact div: match reference rounding
    float gy = 2.f*(iy/iz)/119.f - 1.f;
    bool ok = (fabsf(gx) <= 1.f) && (fabsf(gy) <= 1.f) && (iz > 0.f);
    float px = ok ? (gx + 1.f)*0.5f*79.f : 0.f;
    float py = ok ? (gy + 1.f)*0.5f*59.f : 0.f;
    float x0f = floorf(px), y0f = floorf(py);
    float fx = px - x0f, fy = py - y0f;
    int idx = (int)y0f*80 + (int)x0f;
    float mf = ok ? 1.f : 0.f;
    den += mf;
    float4 w;
    w.x = (1.f-fx)*(1.f-fy)*mf;
    w.y = fx*(1.f-fy)*mf;
    w.z = (1.f-fx)*fy*mf;
    w.w = fx*fy*mf;
    sidx[(size_t)v*NVOX + n] = (ushort)idx;
    swf[(size_t)v*NVOX + n] = w;
  }
  cnt[n] = den;
}

// ---- merged: f1 conv (169) + f4 LDS conv (720) + f2 conv (675) + scatter (512) ----
__global__ __launch_bounds__(256) void k_heads(
    const ushort* nhwc1, const ushort* wf1, const float* b_f1, ushort* t1,
    const ushort* nhwc2, const ushort* wf2, const float* b_f2, ushort* fcat,
    const ushort* nhwc4, const ushort* wf4, const float* b_f4, ushort* t4,
    const int* coords, const int* stage, int* grid, int* scn, float* coords_out,
    const float* origin, const float* vsz, const float* KR,
    ushort* sidx, float4* swf, float* cnt){
  __shared__ ushort lds[18*18*36];
  int bid = blockIdx.x;
  int tid = threadIdx.x;
  if (bid < 169){ conv_dev<3,5,9,1>(nhwc1, wf1, b_f1, t1, 30, 40, 10800, 80, 80, 0, bid, tid); return; }
  bid -= 169;
  if (bid < 720){ conv_lds_dev<16,2>(nhwc4, wf4, b_f4, t4, 120, 160, 24, 24, nullptr, lds, bid, tid); return; }
  bid -= 720;
  if (bid < 675){ conv_dev<2,3,9,1>(nhwc2, wf2, b_f2, fcat, 60, 80, 43200, 40, 160, 80, bid, tid); return; }
  bid -= 675;
  { int n = bid*256 + tid;
    scatter_dev(coords, stage, grid, scn, coords_out, origin, vsz, KR, sidx, swf, cnt, n); }
}

// ---- merged: resize+pool+padzero (5063 blocks) + slice-split nbr build (2048) ----
__global__ __launch_bounds__(256) void k_respool_nbr(
    const ushort* __restrict__ t1, const ushort* __restrict__ t4, ushort* __restrict__ fc,
    const int* __restrict__ scn, const int* __restrict__ grid,
    int* __restrict__ nbr, unsigned* __restrict__ gmask16){
  __shared__ unsigned m16[4];
  int bid = blockIdx.x;
  int tidx = threadIdx.x;
  if (bid < 5063){
    int tid = bid*256 + tidx;
    if (tid < 864000){
      int c4 = tid % 20;
      int x  = (tid / 20) % 80;
      int y  = (tid / 1600) % 60;
      int v  = tid / 96000;
      int c = c4*4;
      int ky = y >> 1; int y0, y1; float wy0, wy1;
      if ((y & 1) == 0){ y0 = ky-1; y1 = ky; wy0 = 0.25f; wy1 = 0.75f; if (y0 < 0){ y0 = 0; wy0 = 0.f; wy1 = 1.f; } }
      else             { y0 = ky; y1 = ky+1; wy0 = 0.75f; wy1 = 0.25f; if (y1 > 29){ y1 = 29; wy1 = 0.f; wy0 = 1.f; } }
      int kx = x >> 1; int x0, x1; float wx0, wx1;
      if ((x & 1) == 0){ x0 = kx-1; x1 = kx; wx0 = 0.25f; wx1 = 0.75f; if (x0 < 0){ x0 = 0; wx0 = 0.f; wx1 = 1.f; } }
      else             { x0 = kx; x1 = kx+1; wx0 = 0.75f; wx1 = 0.25f; if (x1 > 39){ x1 = 39; wx1 = 0.f; wx0 = 1.f; } }
      float4 a00 = ld4b(t1 + ((size_t)(v*30 + y0)*40 + x0)*80 + c);
      float4 a01 = ld4b(t1 + ((size_t)(v*30 + y0)*40 + x1)*80 + c);
      float4 a10 = ld4b(t1 + ((size_t)(v*30 + y1)*40 + x0)*80 + c);
      float4 a11 = ld4b(t1 + ((size_t)(v*30 + y1)*40 + x1)*80 + c);
      float w00 = wy0*wx0, w01 = wy0*wx1, w10 = wy1*wx0, w11 = wy1*wx1;
      float4 r;
      r.x = w00*a00.x + w01*a01.x + w10*a10.x + w11*a11.x;
      r.y = w00*a00.y + w01*a01.y + w10*a10.y + w11*a11.y;
      r.z = w00*a00.z + w01*a01.z + w10*a10.z + w11*a11.z;
      r.w = w00*a00.w + w01*a01.w + w10*a10.w + w11*a11.w;
      st4b(fc + ((size_t)(v*60 + y)*80 + x)*160 + c, r);
      return;
    }
    int t = tid - 864000;
    if (t >= 432000) return;
    int c4 = t % 10;
    int x  = (t / 10) % 80;
    int y  = (t / 800) % 60;
    int v  = t / 48000;
    if (c4 < 6){
      int c = c4*4;
      const ushort* b0 = t4 + ((size_t)(v*120 + 2*y)*160 + 2*x)*24 + c;
      float4 a = ld4b(b0), b = ld4b(b0 + 24), cc = ld4b(b0 + 160*24), d = ld4b(b0 + 160*24 + 24);
      float4 r;
      r.x = 0.25f*(a.x + b.x + cc.x + d.x);
      r.y = 0.25f*(a.y + b.y + cc.y + d.y);
      r.z = 0.25f*(a.z + b.z + cc.z + d.z);
      r.w = 0.25f*(a.w + b.w + cc.w + d.w);
      st4b(fc + ((size_t)(v*60 + y)*80 + x)*160 + 120 + c, r);
    } else {
      float4 zz = {0.f,0.f,0.f,0.f};
      st4b(fc + ((size_t)(v*60 + y)*80 + x)*160 + 144 + (c4-6)*4, zz);
    }
    return;
  }
  bid -= 5063;
  if (tidx < 4) m16[tidx] = 0;
  __syncthreads();
  int vb = bid*64;
  int lane = tidx & 63;
  int wv = tidx >> 6;
  int n = vb + lane;
  int sx = scn[n*3+0], sy = scn[n*3+1], sz = scn[n*3+2];
  int k0 = wv*7;
  int k1 = min(27, k0 + 7);
  unsigned msk = 0;
  #pragma unroll 1
  for (int k = k0; k < k1; ++k){
    int dx = k/9 - 1, dy = (k/3)%3 - 1, dz = k%3 - 1;
    int nx = sx+dx, ny = sy+dy, nz = sz+dz;
    int idx = -1;
    if (((unsigned)nx < 96u) && ((unsigned)ny < 96u) && ((unsigned)nz < 96u))
      idx = grid[(nx*GS + ny)*GS + nz];
    unsigned long long b = __ballot(idx >= 0);
    unsigned sub = (unsigned)((b >> ((lane >> 4)*16)) & 0xFFFFull);
    // skip stores for 16-groups with no neighbor at this tap: never read
    if (sub){
      nbr[(size_t)k*NVOX + n] = idx;
      msk |= (1u << k);
    }
  }
  if ((lane & 15) == 0 && msk) atomicOr(&m16[lane >> 4], msk);
  __syncthreads();
  if (tidx < 4) gmask16[(vb >> 4) + tidx] = m16[tidx];
}

// ---- sampling from fp32-weight table + masked mean/var + bn0 ----
__global__ __launch_bounds__(256) void k_sample(
    const ushort* __restrict__ fuse, const ushort* __restrict__ sidx,
    const float4* __restrict__ swf,
    const float* __restrict__ cnt, const float* __restrict__ bn0g,
    const float* __restrict__ bn0b, ushort* __restrict__ F0){
  int tid = blockIdx.x*256 + threadIdx.x;
  int vox = tid >> 3;
  int c4 = tid & 7;
  int c = c4*4;
  float s0=0.f,s1=0.f,s2=0.f,s3=0.f;
  float q0=0.f,q1=0.f,q2=0.f,q3=0.f;
  #pragma unroll
  for (int v = 0; v < VN; ++v){
    int idx = sidx[(size_t)v*NVOX + vox];
    float4 w = swf[(size_t)v*NVOX + vox];
    const ushort* bp = fuse + (size_t)v*153600 + (size_t)idx*32 + c;
    float4 a00 = ld4b(bp);
    float4 a01 = ld4b(bp + 32);
    float4 a10 = ld4b(bp + 2560);
    float4 a11 = ld4b(bp + 2592);
    float g0 = w.x*a00.x + w.y*a01.x + w.z*a10.x + w.w*a11.x;
    float g1 = w.x*a00.y + w.y*a01.y + w.z*a10.y + w.w*a11.y;
    float g2 = w.x*a00.z + w.y*a01.z + w.z*a10.z + w.w*a11.z;
    float g3 = w.x*a00.w + w.y*a01.w + w.z*a10.w + w.w*a11.w;
    s0 += g0; q0 += g0*g0;
    s1 += g1; q1 += g1*g1;
    s2 += g2; q2 += g2*g2;
    s3 += g3; q3 += g3*g3;
  }
  float iden = 1.f/cnt[vox];
  float m0 = s0*iden, m1 = s1*iden, m2 = s2*iden, m3 = s3*iden;
  float4 g = ld4(bn0g + c);
  float4 b = ld4(bn0b + c);
  float4 r;
  r.x = g.x*fmaxf(q0*iden - m0*m0, 0.f)*INVS + b.x;
  r.y = g.y*fmaxf(q1*iden - m1*m1, 0.f)*INVS + b.y;
  r.z = g.z*fmaxf(q2*iden - m2*m2, 0.f)*INVS + b.z;
  r.w = g.w*fmaxf(q3*iden - m3*m3, 0.f)*INVS + b.w;
  st4b(F0 + (size_t)vox*32 + c, r);
}

// ---- subm sparse conv 32->32 via MFMA bf16 ----
// Operand-swapped; MT=2; batch-3 taps; LN reduce = 2 shuffles.
template<int MODE>
__global__ __launch_bounds__(256, 4) void k_subm_mfma(
    const ushort* __restrict__ fin, const ushort* __restrict__ w2,
    const int* __restrict__ nbr, const unsigned* __restrict__ gmask16,
    const float* __restrict__ lng, const float* __restrict__ lnb,
    ushort* __restrict__ fout){
  int lane = threadIdx.x & 63;
  int wave = threadIdx.x >> 6;
  int vb = blockIdx.x*128 + wave*32;
  int m = lane & 15;
  int q = lane >> 4;

  unsigned rem0 = gmask16[(vb >> 4) + 0];
  unsigned rem1 = gmask16[(vb >> 4) + 1];
  unsigned rem = rem0 | rem1;

  f32x4v acc[2][2];
  acc[0][0] = 0.f; acc[0][1] = 0.f; acc[1][0] = 0.f; acc[1][1] = 0.f;
  bf16x8 zc = (short)0;

  while (rem){
    int k0 = __ffs(rem) - 1; rem &= rem - 1;
    int k1 = -1, k2 = -1;
    if (rem){ k1 = __ffs(rem) - 1; rem &= rem - 1; }
    if (rem){ k2 = __ffs(rem) - 1; rem &= rem - 1; }
    int a0v = nbr[(size_t)k0*NVOX + vb + m];
    int b0v = nbr[(size_t)k0*NVOX + vb + 16 + m];
    int a1 = -1, b1 = -1, a2 = -1, b2 = -1;
    if (k1 >= 0){
      int av = nbr[(size_t)k1*NVOX + vb + m];
      int bv = nbr[(size_t)k1*NVOX + vb + 16 + m];
      a1 = ((rem0 >> k1) & 1) ? av : -1;
      b1 = ((rem1 >> k1) & 1) ? bv : -1;
    }
    if (k2 >= 0){
      int av = nbr[(size_t)k2*NVOX + vb + m];
      int bv = nbr[(size_t)k2*NVOX + vb + 16 + m];
      a2 = ((rem0 >> k2) & 1) ? av : -1;
      b2 = ((rem1 >> k2) & 1) ? bv : -1;
    }
    int a0 = ((rem0 >> k0) & 1) ? a0v : -1;
    int b0 = ((rem1 >> k0) & 1) ? b0v : -1;
    bf16x8 A0, B0, A1 = zc, B1 = zc, A2 = zc, B2 = zc, t;
    bf16x8 w10 = zc, w11 = zc, w20 = zc, w21 = zc;
    t = *(const bf16x8*)(fin + (size_t)(a0 < 0 ? 0 : a0)*32 + q*8); A0 = (a0 < 0) ? zc : t;
    t = *(const bf16x8*)(fin + (size_t)(b0 < 0 ? 0 : b0)*32 + q*8); B0 = (b0 < 0) ? zc : t;
    bf16x8 w00 = *(const bf16x8*)(w2 + (size_t)(k0*32 + m)*32 + q*8);
    bf16x8 w01 = *(const bf16x8*)(w2 + (size_t)(k0*32 + 16 + m)*32 + q*8);
    if (k1 >= 0){
      t = *(const bf16x8*)(fin + (size_t)(a1 < 0 ? 0 : a1)*32 + q*8); A1 = (a1 < 0) ? zc : t;
      t = *(const bf16x8*)(fin + (size_t)(b1 < 0 ? 0 : b1)*32 + q*8); B1 = (b1 < 0) ? zc : t;
      w10 = *(const bf16x8*)(w2 + (size_t)(k1*32 + m)*32 + q*8);
      w11 = *(const bf16x8*)(w2 + (size_t)(k1*32 + 16 + m)*32 + q*8);
    }
    if (k2 >= 0){
      t = *(const bf16x8*)(fin + (size_t)(a2 < 0 ? 0 : a2)*32 + q*8); A2 = (a2 < 0) ? zc : t;
      t = *(const bf16x8*)(fin + (size_t)(b2 < 0 ? 0 : b2)*32 + q*8); B2 = (b2 < 0) ? zc : t;
      w20 = *(const bf16x8*)(w2 + (size_t)(k2*32 + m)*32 + q*8);
      w21 = *(const bf16x8*)(w2 + (size_t)(k2*32 + 16 + m)*32 + q*8);
    }
    acc[0][0] = __builtin_amdgcn_mfma_f32_16x16x32_bf16(w00, A0, acc[0][0], 0, 0, 0);
    acc[0][1] = __builtin_amdgcn_mfma_f32_16x16x32_bf16(w01, A0, acc[0][1], 0, 0, 0);
    acc[1][0] = __builtin_amdgcn_mfma_f32_16x16x32_bf16(w00, B0, acc[1][0], 0, 0, 0);
    acc[1][1] = __builtin_amdgcn_mfma_f32_16x16x32_bf16(w01, B0, acc[1][1], 0, 0, 0);
    if (k1 >= 0){
      acc[0][0] = __builtin_amdgcn_mfma_f32_16x16x32_bf16(w10, A1, acc[0][0], 0, 0, 0);
      acc[0][1] = __builtin_amdgcn_mfma_f32_16x16x32_bf16(w11, A1, acc[0][1], 0, 0, 0);
      acc[1][0] = __builtin_amdgcn_mfma_f32_16x16x32_bf16(w10, B1, acc[1][0], 0, 0, 0);
      acc[1][1] = __builtin_amdgcn_mfma_f32_16x16x32_bf16(w11, B1, acc[1][1], 0, 0, 0);
    }
    if (k2 >= 0){
      acc[0][0] = __builtin_amdgcn_mfma_f32_16x16x32_bf16(w20, A2, acc[0][0], 0, 0, 0);
      acc[0][1] = __builtin_amdgcn_mfma_f32_16x16x32_bf16(w21, A2, acc[0][1], 0, 0, 0);
      acc[1][0] = __builtin_amdgcn_mfma_f32_16x16x32_bf16(w20, B2, acc[1][0], 0, 0, 0);
      acc[1][1] = __builtin_amdgcn_mfma_f32_16x16x32_bf16(w21, B2, acc[1][1], 0, 0, 0);
    }
  }

  float4 g0v{0,0,0,0}, g1v{0,0,0,0}, b0v{0,0,0,0}, b1v{0,0,0,0};
  if (MODE == 1){
    g0v = ld4(lng + q*4);  g1v = ld4(lng + 16 + q*4);
    b0v = ld4(lnb + q*4);  b1v = ld4(lnb + 16 + q*4);
  }
  #pragma unroll
  for (int t = 0; t < 2; ++t){
    int vox = vb + t*16 + m;
    float x0[4], x1[4];
    #pragma unroll
    for (int r = 0; r < 4; ++r){
      x0[r] = fmaxf(acc[t][0][r], 0.f);
      x1[r] = fmaxf(acc[t][1][r], 0.f);
    }
    if (MODE == 1){
      uint2 sk0 = *(const uint2*)(fin + (size_t)vox*32 + q*4);
      uint2 sk1 = *(const uint2*)(fin + (size_t)vox*32 + 16 + q*4);
      x0[0] += blo(sk0.x); x0[1] += bhi(sk0.x); x0[2] += blo(sk0.y); x0[3] += bhi(sk0.y);
      x1[0] += blo(sk1.x); x1[1] += bhi(sk1.x); x1[2] += blo(sk1.y); x1[3] += bhi(sk1.y);
      float s = (x0[0]+x0[1]+x0[2]+x0[3]) + (x1[0]+x1[1]+x1[2]+x1[3]);
      s += __shfl_xor(s, 16);
      s += __shfl_xor(s, 32);
      float mean = s * (1.f/32.f);
      float v2 = 0.f;
      #pragma unroll
      for (int r = 0; r < 4; ++r){
        x0[r] -= mean; x1[r] -= mean;
        v2 += x0[r]*x0[r] + x1[r]*x1[r];
      }
      v2 += __shfl_xor(v2, 16);
      v2 += __shfl_xor(v2, 32);
      float rs = 1.f / sqrtf(v2*(1.f/32.f) + 1e-5f);
      x0[0] = x0[0]*rs*g0v.x + b0v.x; x0[1] = x0[1]*rs*g0v.y + b0v.y;
      x0[2] = x0[2]*rs*g0v.z + b0v.z; x0[3] = x0[3]*rs*g0v.w + b0v.w;
      x1[0] = x1[0]*rs*g1v.x + b1v.x; x1[1] = x1[1]*rs*g1v.y + b1v.y;
      x1[2] = x1[2]*rs*g1v.z + b1v.z; x1[3] = x1[3]*rs*g1v.w + b1v.w;
    }
    st4b(fout + (size_t)vox*32 + q*4,      float4{x0[0],x0[1],x0[2],x0[3]});
    st4b(fout + (size_t)vox*32 + 16 + q*4, float4{x1[0],x1[1],x1[2],x1[3]});
  }
}

// ---- final subm 32->1 + bn. 4 threads/voxel (8 ch each), 2-tap batches,
// cross-lane reduce. ----
__global__ __launch_bounds__(256) void k_s4(
    const ushort* __restrict__ fin, const float* __restrict__ w4,
    const int* __restrict__ nbr, const unsigned* __restrict__ gmask16,
    const float* __restrict__ bn4g, const float* __restrict__ bn4b,
    float* __restrict__ occ){
  int tid = blockIdx.x*256 + threadIdx.x;
  int n = tid >> 2;
  int part = tid & 3;
  unsigned rem = gmask16[n >> 4];
  float acc = 0.f;
  while (rem){
    int k0 = __ffs(rem) - 1; rem &= rem - 1;
    int k1 = -1;
    if (rem){ k1 = __ffs(rem) - 1; rem &= rem - 1; }
    int i0 = nbr[(size_t)k0*NVOX + n];
    int i1 = (k1 >= 0) ? nbr[(size_t)k1*NVOX + n] : -1;
    uint4 d0 = *(const uint4*)(fin + (size_t)(i0 < 0 ? 0 : i0)*32 + part*8);
    uint4 d1 = {0,0,0,0};
    if (k1 >= 0) d1 = *(const uint4*)(fin + (size_t)(i1 < 0 ? 0 : i1)*32 + part*8);
    if (i0 >= 0){
      float4 wa = ld4(w4 + k0*32 + part*8);
      float4 wb = ld4(w4 + k0*32 + part*8 + 4);
      acc += blo(d0.x)*wa.x + bhi(d0.x)*wa.y + blo(d0.y)*wa.z + bhi(d0.y)*wa.w
           + blo(d0.z)*wb.x + bhi(d0.z)*wb.y + blo(d0.w)*wb.z + bhi(d0.w)*wb.w;
    }
    if (i1 >= 0){
      float4 wa = ld4(w4 + k1*32 + part*8);
      float4 wb = ld4(w4 + k1*32 + part*8 + 4);
      acc += blo(d1.x)*wa.x + bhi(d1.x)*wa.y + blo(d1.y)*wa.z + bhi(d1.y)*wa.w
           + blo(d1.z)*wb.x + bhi(d1.z)*wb.y + blo(d1.w)*wb.z + bhi(d1.w)*wb.w;
    }
  }
  acc += __shfl_xor(acc, 1, 4);
  acc += __shfl_xor(acc, 2, 4);
  if (part == 0) occ[n] = bn4g[0]*acc*INVS + bn4b[0];
}

extern "C" void kernel_launch(void* const* d_in, const int* in_sizes, int n_in,
                              void* d_out, int out_size, void* d_ws, size_t ws_size,
                              hipStream_t stream){
  const float* feats1 = (const float*)d_in[0];
  const float* feats2 = (const float*)d_in[1];
  const float* feats4 = (const float*)d_in[2];
  const int*   coords = (const int*)d_in[3];
  const float* origin = (const float*)d_in[4];
  const float* vsz    = (const float*)d_in[5];
  const float* KR     = (const float*)d_in[6];
  const float* w_f1 = (const float*)d_in[7];  const float* b_f1 = (const float*)d_in[8];
  const float* w_f2 = (const float*)d_in[9];  const float* b_f2 = (const float*)d_in[10];
  const float* w_f4 = (const float*)d_in[11]; const float* b_f4 = (const float*)d_in[12];
  const float* w_dn = (const float*)d_in[13]; const float* b_dn = (const float*)d_in[14];
  const float* w_p[4] = {(const float*)d_in[15], (const float*)d_in[17],
                         (const float*)d_in[19], (const float*)d_in[21]};
  const float* b_p[4] = {(const float*)d_in[16], (const float*)d_in[18],
                         (const float*)d_in[20], (const float*)d_in[22]};
  const float* bn0g = (const float*)d_in[23]; const float* bn0b = (const float*)d_in[24];
  const float* w_elan = (const float*)d_in[25];
  const float* w_s1 = (const float*)d_in[26]; const float* ln1g = (const float*)d_in[27]; const float* ln1b = (const float*)d_in[28];
  const float* w_s2 = (const float*)d_in[29]; const float* ln2g = (const float*)d_in[30]; const float* ln2b = (const float*)d_in[31];
  const float* w_s3 = (const float*)d_in[32]; const float* ln3g = (const float*)d_in[33]; const float* ln3b = (const float*)d_in[34];
  const float* w_s4 = (const float*)d_in[35]; const float* bn4g = (const float*)d_in[36]; const float* bn4b = (const float*)d_in[37];
  const int* stage  = (const int*)d_in[38];
  float* out = (float*)d_out;
  char* base = (char*)d_ws;

  size_t off = 0;
  auto alloc = [&](size_t bytes)->char*{ char* p = base + off; off += (bytes + 255) & ~(size_t)255; return p; };
  ushort* nhwc1 = (ushort*)alloc((size_t)9*30*40*96*2);
  ushort* nhwc2 = (ushort*)alloc((size_t)9*60*80*64*2);
  ushort* nhwc4 = (ushort*)alloc((size_t)9*120*160*32*2);
  ushort* t1    = (ushort*)alloc((size_t)9*30*40*80*2);
  ushort* t4    = (ushort*)alloc((size_t)9*120*160*24*2);
  ushort* fcat  = (ushort*)alloc((size_t)9*60*80*160*2);
  ushort* A     = (ushort*)alloc((size_t)9*60*80*32*2);
  ushort* B     = (ushort*)alloc((size_t)9*60*80*32*2);
  ushort* Fb0   = (ushort*)alloc((size_t)NVOX*32*2);
  ushort* Fb1   = (ushort*)alloc((size_t)NVOX*32*2);
  int*    nbr   = (int*)alloc((size_t)27*NVOX*4);
  int*    grid  = (int*)alloc((size_t)GS*GS*GS*4);
  int*    scn   = (int*)alloc((size_t)NVOX*3*4);
  unsigned* gmask16 = (unsigned*)alloc((size_t)(NVOX/16)*4);
  ushort* wf1   = (ushort*)alloc(9*3*80*32*2);
  ushort* wf2   = (ushort*)alloc(9*2*48*32*2);
  ushort* wf4   = (ushort*)alloc(9*1*32*32*2);
  ushort* wdn   = (ushort*)alloc(1*5*32*32*2);
  ushort* wp0   = (ushort*)alloc(9*1*32*32*2);
  ushort* wp1   = (ushort*)alloc(9*1*32*32*2);
  ushort* wp2   = (ushort*)alloc(9*1*32*32*2);
  ushort* wp3   = (ushort*)alloc(9*1*32*32*2);
  ushort* w2e   = (ushort*)alloc(27*1024*2);
  ushort* w2s1  = (ushort*)alloc(27*1024*2);
  ushort* w2s2  = (ushort*)alloc(27*1024*2);
  ushort* w2s3  = (ushort*)alloc(27*1024*2);
  ushort* sidx  = (ushort*)alloc((size_t)VN*NVOX*2);     // 2.36 MB
  float4* swf   = (float4*)alloc((size_t)VN*NVOX*16);    // 18.9 MB, fp32 weights

  auto nb = [](int total){ return (total + 255)/256; };

  // 1. mega prep
  k_prep<<<8012,256,0,stream>>>(
      w_f1, w_f2, w_f4, w_dn, w_p[0], w_p[1], w_p[2], w_p[3],
      w_elan, w_s1, w_s2, w_s3,
      wf1, wf2, wf4, wdn, wp0, wp1, wp2, wp3, w2e, w2s1, w2s2, w2s3, grid,
      feats1, feats2, feats4, nhwc1, nhwc2, nhwc4);

  // 2. head convs + scatter (projection once/voxel)
  k_heads<<<169 + 720 + 675 + 512,256,0,stream>>>(
      nhwc1, wf1, b_f1, t1,
      nhwc2, wf2, b_f2, fcat,
      nhwc4, wf4, b_f4, t4,
      coords, stage, grid, scn, out + NVOX,
      origin, vsz, KR, sidx, swf, out + 5*NVOX);

  // 3. respool + nbr build
  k_respool_nbr<<<5063 + 2048,256,0,stream>>>(t1, t4, fcat, scn, grid, nbr, gmask16);

  // 4-6. fused down+p0, p1, fused p2+p3  (chain 5 kernels -> 3)
  k_down_p0<<<675,256,0,stream>>>(fcat, wdn, b_dn, wp0, b_p[0], B);
  k_conv_lds4<<<675,256,0,stream>>>(B, wp1, b_p[1], A, B);
  k_p2_p3<<<675,256,0,stream>>>(A, wp2, b_p[2], wp3, b_p[3], B);

  // 7. sampling -> F0 (table-driven, fp32 weights); fuse result now in B
  k_sample<<<NVOX/32,256,0,stream>>>(B, sidx, swf, out + 5*NVOX, bn0g, bn0b, Fb0);

  // 8-11. sparse conv stack
  k_subm_mfma<0><<<NVOX/128,256,0,stream>>>(Fb0, w2e,  nbr, gmask16, nullptr, nullptr, Fb1);
  k_subm_mfma<1><<<NVOX/128,256,0,stream>>>(Fb1, w2s1, nbr, gmask16, ln1g, ln1b, Fb0);
  k_subm_mfma<1><<<NVOX/128,256,0,stream>>>(Fb0, w2s2, nbr, gmask16, ln2g, ln2b, Fb1);
  k_subm_mfma<1><<<NVOX/128,256,0,stream>>>(Fb1, w2s3, nbr, gmask16, ln3g, ln3b, Fb0);

  // 12. final head
  k_s4<<<NVOX/64,256,0,stream>>>(Fb0, w_s4, nbr, gmask16, bn4g, bn4b, out);
}

// Round 9
// 330.076 us; speedup vs baseline: 1.0457x; 1.0018x over previous
//
#include <hip/hip_runtime.h>
#include <math.h>

#define VN 9
#define NVOX 131072
#define GS 96
static constexpr float INVS = 0.9999950000374997f; // 1/sqrt(1+1e-5)

typedef short bf16x8 __attribute__((ext_vector_type(8)));
typedef float f32x4v __attribute__((ext_vector_type(4)));

__device__ inline float4 ld4(const float* p){ return *reinterpret_cast<const float4*>(p); }

__device__ inline ushort f2b(float f){
  unsigned u = __float_as_uint(f);
  unsigned r = (u + 0x7fffu + ((u >> 16) & 1u)) >> 16;
  return (ushort)r;
}
__device__ inline float b2f(ushort s){ return __uint_as_float(((unsigned)s) << 16); }
__device__ inline float blo(unsigned u){ return __uint_as_float(u << 16); }
__device__ inline float bhi(unsigned u){ return __uint_as_float(u & 0xffff0000u); }

__device__ inline float4 ld4b(const ushort* p){
  uint2 u = *reinterpret_cast<const uint2*>(p);
  float4 r; r.x = blo(u.x); r.y = bhi(u.x); r.z = blo(u.y); r.w = bhi(u.y); return r;
}
__device__ inline void st4b(ushort* p, float4 v){
  uint2 u;
  u.x = (unsigned)f2b(v.x) | ((unsigned)f2b(v.y) << 16);
  u.y = (unsigned)f2b(v.z) | ((unsigned)f2b(v.w) << 16);
  *reinterpret_cast<uint2*>(p) = u;
}

// ---- weight prep helpers ----
__device__ inline void wprep2_dev(const float* __restrict__ w, ushort* __restrict__ o,
                                  int Cout, int Cin, int K, int CK, int CoutPad, int tid){
  int ci32 = tid & 31;
  int co = (tid >> 5) % CoutPad;
  int ck = (tid / (32*CoutPad)) % CK;
  int tap = tid / (32*CoutPad*CK);
  int ci = ck*32 + ci32;
  float v = 0.f;
  if (co < Cout && ci < Cin) v = w[(size_t)(co*Cin + ci)*K*K + tap];
  o[tid] = f2b(v);
}
__device__ inline void wprep_dev(const float* __restrict__ w, ushort* __restrict__ o, int tid){
  int k = tid >> 10;
  int r = tid & 1023;
  int co = r >> 5;
  int ci = r & 31;
  o[tid] = f2b(w[k*1024 + ci*32 + co]);
}

// ---- NCHW fp32 -> NHWC bf16 via LDS tile ----
__device__ inline void nhwc_tile_dev(const float* __restrict__ in, ushort* __restrict__ out,
                                     int C, int Cpad, int HW, int tile, int tilesPerV,
                                     float* lds, int tx){
  int v  = tile / tilesPerV;
  int p0 = (tile - v*tilesPerV) * 64;
  const float* ip = in + (size_t)v*C*HW + p0;
  int iters = Cpad >> 2;
  for (int i = 0; i < iters; ++i){
    int idx = i*256 + tx;
    int c = idx >> 6;
    int p = idx & 63;
    float val = 0.f;
    if (c < C && (p0 + p) < HW) val = ip[(size_t)c*HW + p];
    lds[c*65 + p] = val;
  }
  __syncthreads();
  int groups = Cpad >> 2;
  int tot = 64*groups;
  for (int basei = 0; basei < tot; basei += 256){
    int idx = basei + tx;
    if (idx < tot){
      int g  = idx % groups;
      int px = idx / groups;
      if ((p0 + px) < HW){
        float4 r;
        r.x = lds[(g*4+0)*65 + px];
        r.y = lds[(g*4+1)*65 + px];
        r.z = lds[(g*4+2)*65 + px];
        r.w = lds[(g*4+3)*65 + px];
        st4b(out + (size_t)(v*HW + p0 + px)*Cpad + g*4, r);
      }
    }
  }
}

// ---- mega prep kernel: weight preps + grid clear + NHWC transposes ----
__global__ __launch_bounds__(256) void k_prep(
    const float* wf1s, const float* wf2s, const float* wf4s, const float* wdns,
    const float* wp0s, const float* wp1s, const float* wp2s, const float* wp3s,
    const float* wes, const float* ws1s, const float* ws2s, const float* ws3s,
    ushort* wf1, ushort* wf2, ushort* wf4, ushort* wdn,
    ushort* wp0, ushort* wp1, ushort* wp2, ushort* wp3,
    ushort* w2e, ushort* w2s1, ushort* w2s2, ushort* w2s3,
    int* grid,
    const float* f1, const float* f2, const float* f4,
    ushort* o1, ushort* o2, ushort* o4){
  __shared__ float lds[96*65];
  int bid = blockIdx.x;
  int tx = threadIdx.x;
  if (bid < 270){ int t = bid*256+tx; if (t < 69120) wprep2_dev(wf1s, wf1, 80, 80, 3, 3, 80, t); return; }
  bid -= 270;
  if (bid < 108){ int t = bid*256+tx; if (t < 27648) wprep2_dev(wf2s, wf2, 40, 40, 3, 2, 48, t); return; }
  bid -= 108;
  if (bid < 36){ int t = bid*256+tx; if (t < 9216) wprep2_dev(wf4s, wf4, 24, 24, 3, 1, 32, t); return; }
  bid -= 36;
  if (bid < 20){ int t = bid*256+tx; if (t < 5120) wprep2_dev(wdns, wdn, 32, 144, 1, 5, 32, t); return; }
  bid -= 20;
  if (bid < 36){ int t = bid*256+tx; if (t < 9216) wprep2_dev(wp0s, wp0, 32, 32, 3, 1, 32, t); return; }
  bid -= 36;
  if (bid < 36){ int t = bid*256+tx; if (t < 9216) wprep2_dev(wp1s, wp1, 32, 32, 3, 1, 32, t); return; }
  bid -= 36;
  if (bid < 36){ int t = bid*256+tx; if (t < 9216) wprep2_dev(wp2s, wp2, 32, 32, 3, 1, 32, t); return; }
  bid -= 36;
  if (bid < 36){ int t = bid*256+tx; if (t < 9216) wprep2_dev(wp3s, wp3, 32, 32, 3, 1, 32, t); return; }
  bid -= 36;
  if (bid < 108){ int t = bid*256+tx; if (t < 27648) wprep_dev(wes, w2e, t); return; }
  bid -= 108;
  if (bid < 108){ int t = bid*256+tx; if (t < 27648) wprep_dev(ws1s, w2s1, t); return; }
  bid -= 108;
  if (bid < 108){ int t = bid*256+tx; if (t < 27648) wprep_dev(ws2s, w2s2, t); return; }
  bid -= 108;
  if (bid < 108){ int t = bid*256+tx; if (t < 27648) wprep_dev(ws3s, w2s3, t); return; }
  bid -= 108;
  if (bid < 3456){ int t = bid*256+tx; if (t < GS*GS*GS) grid[t] = -1; return; }
  bid -= 3456;
  if (bid < 171){ nhwc_tile_dev(f1, o1, 80, 96, 1200, bid, 19, lds, tx); return; }
  bid -= 171;
  if (bid < 675){ nhwc_tile_dev(f2, o2, 40, 64, 4800, bid, 75, lds, tx); return; }
  bid -= 675;
  if (bid < 2700){ nhwc_tile_dev(f4, o4, 24, 32, 19200, bid, 300, lds, tx); }
}

// ---- implicit-GEMM conv via MFMA, register path (for f1/f2) ----
template<int CK, int NT, int TAPS, int MT>
__device__ void conv_dev(
    const ushort* __restrict__ fin, const ushort* __restrict__ w2,
    const float* __restrict__ bias, ushort* __restrict__ outp,
    int H, int W, int total, int Cout, int outStride, int outOff,
    int bid, int tid){
  constexpr int CIN = CK*32;
  constexpr int COP = NT*16;
  int lane = tid & 63;
  int wave = tid >> 6;
  int vbase = bid*(MT*64) + wave*(MT*16);
  int m = lane & 15, q = lane >> 4;
  int HW = H*W;
  int p[MT], py[MT], px[MT]; bool pin[MT];
  #pragma unroll
  for (int t = 0; t < MT; ++t){
    int pp = vbase + t*16 + m;
    pin[t] = pp < total;
    if (pp > total-1) pp = total-1;
    p[t] = pp;
    int v = pp / HW; int rem = pp - v*HW;
    int y = rem / W;
    py[t] = y; px[t] = rem - y*W;
  }
  f32x4v acc[MT][NT];
  #pragma unroll
  for (int t = 0; t < MT; ++t)
    #pragma unroll
    for (int n = 0; n < NT; ++n) acc[t][n] = 0.f;
  bf16x8 z = (short)0;

  #pragma unroll 1
  for (int tap = 0; tap < TAPS; ++tap){
    int dy = (TAPS == 9) ? tap/3 - 1 : 0;
    int dx = (TAPS == 9) ? tap%3 - 1 : 0;
    int off = dy*W + dx;
    bool val[MT];
    #pragma unroll
    for (int t = 0; t < MT; ++t)
      val[t] = pin[t] && ((unsigned)(py[t]+dy) < (unsigned)H)
                      && ((unsigned)(px[t]+dx) < (unsigned)W);
    #pragma unroll
    for (int ck = 0; ck < CK; ++ck){
      bf16x8 Af[MT], Bf[NT];
      #pragma unroll
      for (int t = 0; t < MT; ++t){
        size_t idx = val[t] ? (size_t)(p[t]+off) : 0;
        bf16x8 a = *(const bf16x8*)(fin + idx*CIN + ck*32 + q*8);
        Af[t] = val[t] ? a : z;
      }
      #pragma unroll
      for (int n = 0; n < NT; ++n)
        Bf[n] = *(const bf16x8*)(w2 + ((size_t)((tap*CK+ck)*COP + n*16 + m))*32 + q*8);
      #pragma unroll
      for (int t = 0; t < MT; ++t)
        #pragma unroll
        for (int n = 0; n < NT; ++n)
          acc[t][n] = __builtin_amdgcn_mfma_f32_16x16x32_bf16(Bf[n], Af[t], acc[t][n], 0, 0, 0);
    }
  }

  #pragma unroll
  for (int n = 0; n < NT; ++n){
    int co4 = n*16 + q*4;
    bool cok = co4 < Cout;   // all Couts are multiples of 4
    float4 bs = cok ? ld4(bias + co4) : float4{0.f,0.f,0.f,0.f};
    #pragma unroll
    for (int t = 0; t < MT; ++t){
      int pp = vbase + t*16 + m;
      if (pp < total && cok){
        float4 v;
        v.x = fmaxf(acc[t][n][0] + bs.x, 0.f);
        v.y = fmaxf(acc[t][n][1] + bs.y, 0.f);
        v.z = fmaxf(acc[t][n][2] + bs.z, 0.f);
        v.w = fmaxf(acc[t][n][3] + bs.w, 0.f);
        st4b(outp + (size_t)pp*outStride + outOff + co4, v);
      }
    }
  }
}

// ---- LDS-tiled 3x3 conv, CIN=32 ----
template<int TH, int NT>
__device__ void conv_lds_dev(
    const ushort* __restrict__ fin, const ushort* __restrict__ w2,
    const float* __restrict__ bias, ushort* __restrict__ outp,
    int H, int W, int Cout, int outStride,
    const ushort* __restrict__ skipin, ushort* lds, int bid, int tid){
  constexpr int RPW = TH/4;
  constexpr int PS = 36;             // padded channel stride (18 banks -> 2-way free)
  int xtiles = W >> 4;
  int ytiles = (H + TH - 1) / TH;
  int v  = bid / (ytiles*xtiles);
  int rem = bid - v*(ytiles*xtiles);
  int ty = (rem / xtiles) * TH;
  int tx = (rem % xtiles) * 16;
  const ushort* ibase = fin + (size_t)v*H*W*32;
  for (int i = tid; i < (TH+2)*18*4; i += 256){
    int chunk = i & 3;
    int pxi = i >> 2;
    int ly = pxi / 18, lx = pxi - ly*18;
    int gy = ty + ly - 1, gx = tx + lx - 1;
    uint4 d = {0,0,0,0};
    if ((unsigned)gy < (unsigned)H && (unsigned)gx < (unsigned)W)
      d = *(const uint4*)(ibase + ((size_t)gy*W + gx)*32 + chunk*8);
    *(uint4*)(lds + (size_t)(ly*18 + lx)*PS + chunk*8) = d;
  }
  __syncthreads();
  int lane = tid & 63;
  int wave = tid >> 6;
  int m = lane & 15, q = lane >> 4;
  f32x4v acc[RPW][NT];
  #pragma unroll
  for (int t = 0; t < RPW; ++t)
    #pragma unroll
    for (int n = 0; n < NT; ++n) acc[t][n] = 0.f;

  #pragma unroll 1
  for (int tap = 0; tap < 9; ++tap){
    int dy = tap/3 - 1, dx = tap%3 - 1;
    bf16x8 Af[RPW], Bf[NT];
    #pragma unroll
    for (int t = 0; t < RPW; ++t){
      int ly = wave*RPW + t + 1 + dy;
      int lx = m + 1 + dx;
      Af[t] = *(const bf16x8*)(lds + (size_t)(ly*18 + lx)*PS + q*8);
    }
    #pragma unroll
    for (int n = 0; n < NT; ++n)
      Bf[n] = *(const bf16x8*)(w2 + ((size_t)(tap*(NT*16) + n*16 + m))*32 + q*8);
    #pragma unroll
    for (int t = 0; t < RPW; ++t)
      #pragma unroll
      for (int n = 0; n < NT; ++n)
        acc[t][n] = __builtin_amdgcn_mfma_f32_16x16x32_bf16(Bf[n], Af[t], acc[t][n], 0, 0, 0);
  }

  #pragma unroll
  for (int n = 0; n < NT; ++n){
    int co4 = n*16 + q*4;
    bool cok = co4 < Cout;
    float4 bs = cok ? ld4(bias + co4) : float4{0.f,0.f,0.f,0.f};
    #pragma unroll
    for (int t = 0; t < RPW; ++t){
      int y = ty + wave*RPW + t;
      int x = tx + m;
      if (y < H && cok){
        size_t pp = (size_t)(v*H + y)*W + x;
        float4 val;
        val.x = fmaxf(acc[t][n][0] + bs.x, 0.f);
        val.y = fmaxf(acc[t][n][1] + bs.y, 0.f);
        val.z = fmaxf(acc[t][n][2] + bs.z, 0.f);
        val.w = fmaxf(acc[t][n][3] + bs.w, 0.f);
        if (skipin){
          float4 sk = ld4b(skipin + pp*32 + co4);
          val.x += sk.x; val.y += sk.y; val.z += sk.z; val.w += sk.w;
        }
        st4b(outp + pp*outStride + co4, val);
      }
    }
  }
}

// chain conv: TH=4 -> patch 6x18x36 = 7.8 KB, 675 blocks
__global__ __launch_bounds__(256) void k_conv_lds4(
    const ushort* __restrict__ fin, const ushort* __restrict__ w2,
    const float* __restrict__ bias, ushort* __restrict__ outp,
    const ushort* __restrict__ skipin){
  __shared__ ushort lds[6*18*36];
  conv_lds_dev<4,2>(fin, w2, bias, outp, 60, 80, 32, 32, skipin, lds, blockIdx.x, threadIdx.x);
}

// ---- FUSED: down 1x1 (160->32) over 6x18 halo into LDS, then p0 3x3 from LDS.
__global__ __launch_bounds__(256) void k_down_p0(
    const ushort* __restrict__ fcat, const ushort* __restrict__ wdn,
    const float* __restrict__ b_dn, const ushort* __restrict__ wp0,
    const float* __restrict__ b_p0, ushort* __restrict__ outB){
  __shared__ ushort ldsA[6*18*36];
  int bid = blockIdx.x;
  int tid = threadIdx.x;
  int v  = bid / 75;
  int rem = bid - v*75;
  int ty = (rem / 5) * 4;
  int tx = (rem % 5) * 16;
  int lane = tid & 63;
  int wave = tid >> 6;
  int m = lane & 15, q = lane >> 4;
  bf16x8 z = (short)0;

  #pragma unroll
  for (int t = 0; t < 2; ++t){
    int hp = (wave*2 + t)*16 + m;      // 0..127; valid < 108
    int hpc = hp < 108 ? hp : 107;
    int ly = hpc / 18, lx = hpc - ly*18;
    int gy = ty + ly - 1, gx = tx + lx - 1;
    bool ok = (hp < 108) && ((unsigned)gy < 60u) && ((unsigned)gx < 80u);
    size_t pbase = ((size_t)(v*60 + (ok ? gy : 0))*80 + (ok ? gx : 0))*160;
    f32x4v acc0 = 0.f, acc1 = 0.f;
    #pragma unroll
    for (int ck = 0; ck < 5; ++ck){
      bf16x8 a = *(const bf16x8*)(fcat + pbase + ck*32 + q*8);
      if (!ok) a = z;
      bf16x8 w0 = *(const bf16x8*)(wdn + ((size_t)(ck*32 + m))*32 + q*8);
      bf16x8 w1 = *(const bf16x8*)(wdn + ((size_t)(ck*32 + 16 + m))*32 + q*8);
      acc0 = __builtin_amdgcn_mfma_f32_16x16x32_bf16(w0, a, acc0, 0, 0, 0);
      acc1 = __builtin_amdgcn_mfma_f32_16x16x32_bf16(w1, a, acc1, 0, 0, 0);
    }
    if (hp < 108){
      float4 bs0 = ld4(b_dn + q*4);
      float4 bs1 = ld4(b_dn + 16 + q*4);
      float4 v0, v1;
      v0.x = ok ? fmaxf(acc0[0] + bs0.x, 0.f) : 0.f;
      v0.y = ok ? fmaxf(acc0[1] + bs0.y, 0.f) : 0.f;
      v0.z = ok ? fmaxf(acc0[2] + bs0.z, 0.f) : 0.f;
      v0.w = ok ? fmaxf(acc0[3] + bs0.w, 0.f) : 0.f;
      v1.x = ok ? fmaxf(acc1[0] + bs1.x, 0.f) : 0.f;
      v1.y = ok ? fmaxf(acc1[1] + bs1.y, 0.f) : 0.f;
      v1.z = ok ? fmaxf(acc1[2] + bs1.z, 0.f) : 0.f;
      v1.w = ok ? fmaxf(acc1[3] + bs1.w, 0.f) : 0.f;
      st4b(ldsA + (size_t)(ly*18 + lx)*36 + q*4,      v0);
      st4b(ldsA + (size_t)(ly*18 + lx)*36 + 16 + q*4, v1);
    }
  }
  __syncthreads();

  f32x4v pacc0 = 0.f, pacc1 = 0.f;
  #pragma unroll 1
  for (int tap = 0; tap < 9; ++tap){
    int dy = tap/3 - 1, dx = tap%3 - 1;
    bf16x8 Af = *(const bf16x8*)(ldsA + (size_t)((wave+1+dy)*18 + (m+1+dx))*36 + q*8);
    bf16x8 B0 = *(const bf16x8*)(wp0 + ((size_t)(tap*32 + m))*32 + q*8);
    bf16x8 B1 = *(const bf16x8*)(wp0 + ((size_t)(tap*32 + 16 + m))*32 + q*8);
    pacc0 = __builtin_amdgcn_mfma_f32_16x16x32_bf16(B0, Af, pacc0, 0, 0, 0);
    pacc1 = __builtin_amdgcn_mfma_f32_16x16x32_bf16(B1, Af, pacc1, 0, 0, 0);
  }
  int y = ty + wave, x = tx + m;
  size_t pp = (size_t)(v*60 + y)*80 + x;
  #pragma unroll
  for (int n = 0; n < 2; ++n){
    int co4 = n*16 + q*4;
    float4 bs = ld4(b_p0 + co4);
    f32x4v& pa = n ? pacc1 : pacc0;
    float4 sk = ld4b(ldsA + (size_t)((wave+1)*18 + (m+1))*36 + co4);
    float4 val;
    val.x = fmaxf(pa[0] + bs.x, 0.f) + sk.x;
    val.y = fmaxf(pa[1] + bs.y, 0.f) + sk.y;
    val.z = fmaxf(pa[2] + bs.z, 0.f) + sk.z;
    val.w = fmaxf(pa[3] + bs.w, 0.f) + sk.w;
    st4b(outB + pp*32 + co4, val);
  }
}

// ---- FUSED: p2 3x3 over 6x18 interior (input staged 8x20) into LDS, then p3.
__global__ __launch_bounds__(256) void k_p2_p3(
    const ushort* __restrict__ finA, const ushort* __restrict__ wp2,
    const float* __restrict__ b_p2, const ushort* __restrict__ wp3,
    const float* __restrict__ b_p3, ushort* __restrict__ outB){
  __shared__ ushort ldsIn[8*20*36];
  __shared__ ushort ldsMid[6*18*36];
  int bid = blockIdx.x;
  int tid = threadIdx.x;
  int v  = bid / 75;
  int rem = bid - v*75;
  int ty = (rem / 5) * 4;
  int tx = (rem % 5) * 16;
  for (int i = tid; i < 8*20*4; i += 256){
    int chunk = i & 3;
    int pxi = i >> 2;
    int ly = pxi / 20, lx = pxi - ly*20;
    int gy = ty + ly - 2, gx = tx + lx - 2;
    uint4 d = {0,0,0,0};
    if ((unsigned)gy < 60u && (unsigned)gx < 80u)
      d = *(const uint4*)(finA + ((size_t)(v*60 + gy)*80 + gx)*32 + chunk*8);
    *(uint4*)(ldsIn + (size_t)(ly*20 + lx)*36 + chunk*8) = d;
  }
  __syncthreads();
  int lane = tid & 63;
  int wave = tid >> 6;
  int m = lane & 15, q = lane >> 4;

  #pragma unroll
  for (int t = 0; t < 2; ++t){
    int hp = (wave*2 + t)*16 + m;
    int hpc = hp < 108 ? hp : 107;
    int ly = hpc / 18, lx = hpc - ly*18;
    int gy = ty + ly - 1, gx = tx + lx - 1;
    bool ok = (hp < 108) && ((unsigned)gy < 60u) && ((unsigned)gx < 80u);
    f32x4v acc0 = 0.f, acc1 = 0.f;
    #pragma unroll 1
    for (int tap = 0; tap < 9; ++tap){
      int dy = tap/3 - 1, dx = tap%3 - 1;
      bf16x8 a = *(const bf16x8*)(ldsIn + (size_t)((ly+dy+1)*20 + (lx+dx+1))*36 + q*8);
      bf16x8 w0 = *(const bf16x8*)(wp2 + ((size_t)(tap*32 + m))*32 + q*8);
      bf16x8 w1 = *(const bf16x8*)(wp2 + ((size_t)(tap*32 + 16 + m))*32 + q*8);
      acc0 = __builtin_amdgcn_mfma_f32_16x16x32_bf16(w0, a, acc0, 0, 0, 0);
      acc1 = __builtin_amdgcn_mfma_f32_16x16x32_bf16(w1, a, acc1, 0, 0, 0);
    }
    if (hp < 108){
      float4 bs0 = ld4(b_p2 + q*4);
      float4 bs1 = ld4(b_p2 + 16 + q*4);
      float4 sk0 = ld4b(ldsIn + (size_t)((ly+1)*20 + (lx+1))*36 + q*4);
      float4 sk1 = ld4b(ldsIn + (size_t)((ly+1)*20 + (lx+1))*36 + 16 + q*4);
      float4 v0, v1;
      v0.x = ok ? fmaxf(acc0[0] + bs0.x, 0.f) + sk0.x : 0.f;
      v0.y = ok ? fmaxf(acc0[1] + bs0.y, 0.f) + sk0.y : 0.f;
      v0.z = ok ? fmaxf(acc0[2] + bs0.z, 0.f) + sk0.z : 0.f;
      v0.w = ok ? fmaxf(acc0[3] + bs0.w, 0.f) + sk0.w : 0.f;
      v1.x = ok ? fmaxf(acc1[0] + bs1.x, 0.f) + sk1.x : 0.f;
      v1.y = ok ? fmaxf(acc1[1] + bs1.y, 0.f) + sk1.y : 0.f;
      v1.z = ok ? fmaxf(acc1[2] + bs1.z, 0.f) + sk1.z : 0.f;
      v1.w = ok ? fmaxf(acc1[3] + bs1.w, 0.f) + sk1.w : 0.f;
      st4b(ldsMid + (size_t)(ly*18 + lx)*36 + q*4,      v0);
      st4b(ldsMid + (size_t)(ly*18 + lx)*36 + 16 + q*4, v1);
    }
  }
  __syncthreads();

  f32x4v pacc0 = 0.f, pacc1 = 0.f;
  #pragma unroll 1
  for (int tap = 0; tap < 9; ++tap){
    int dy = tap/3 - 1, dx = tap%3 - 1;
    bf16x8 a = *(const bf16x8*)(ldsMid + (size_t)((wave+1+dy)*18 + (m+1+dx))*36 + q*8);
    bf16x8 w0 = *(const bf16x8*)(wp3 + ((size_t)(tap*32 + m))*32 + q*8);
    bf16x8 w1 = *(const bf16x8*)(wp3 + ((size_t)(tap*32 + 16 + m))*32 + q*8);
    pacc0 = __builtin_amdgcn_mfma_f32_16x16x32_bf16(w0, a, pacc0, 0, 0, 0);
    pacc1 = __builtin_amdgcn_mfma_f32_16x16x32_bf16(w1, a, pacc1, 0, 0, 0);
  }
  int y = ty + wave, x = tx + m;
  size_t pp = (size_t)(v*60 + y)*80 + x;
  #pragma unroll
  for (int n = 0; n < 2; ++n){
    int co4 = n*16 + q*4;
    float4 bs = ld4(b_p3 + co4);
    f32x4v& pa = n ? pacc1 : pacc0;
    float4 sk = ld4b(ldsMid + (size_t)((wave+1)*18 + (m+1))*36 + co4);
    float4 val;
    val.x = fmaxf(pa[0] + bs.x, 0.f) + sk.x;
    val.y = fmaxf(pa[1] + bs.y, 0.f) + sk.y;
    val.z = fmaxf(pa[2] + bs.z, 0.f) + sk.z;
    val.w = fmaxf(pa[3] + bs.w, 0.f) + sk.w;
    st4b(outB + pp*32 + co4, val);
  }
}

// ---- scatter device: grid scatter + coords + sample table (fp32 weights) + count ----
__device__ void scatter_dev(const int* __restrict__ coords, const int* __restrict__ stage,
                            int* __restrict__ grid, int* __restrict__ scn,
                            float* __restrict__ coords_out,
                            const float* __restrict__ origin, const float* __restrict__ vsz,
                            const float* __restrict__ KR,
                            ushort* __restrict__ sidx, float4* __restrict__ swf,
                            float* __restrict__ cnt, int n){
  int c0 = coords[n*4], c1 = coords[n*4+1], c2 = coords[n*4+2], c3 = coords[n*4+3];
  coords_out[n*4+0] = (float)c0;
  coords_out[n*4+1] = (float)c1;
  coords_out[n*4+2] = (float)c2;
  coords_out[n*4+3] = (float)c3;
  int sh = 2 - stage[0];
  int s1 = c1 >> sh, s2 = c2 >> sh, s3 = c3 >> sh;
  scn[n*3+0] = s1; scn[n*3+1] = s2; scn[n*3+2] = s3;
  grid[(s1*GS + s2)*GS + s3] = n;

  float vs = vsz[0];
  float wx = (float)c1*vs + origin[0];
  float wy = (float)c2*vs + origin[1];
  float wz = (float)c3*vs + origin[2];
  float den = 0.f;
  #pragma unroll 1
  for (int v = 0; v < VN; ++v){
    const float* P = KR + v*12;
    float ix = P[0]*wx + P[1]*wy + P[2]*wz + P[3];
    float iy = P[4]*wx + P[5]*wy + P[6]*wz + P[7];
    float iz = P[8]*wx + P[9]*wy + P[10]*wz + P[11];
    float gx = 2.f*(ix/iz)/159.f - 1.f;   // exact div: match reference rounding
    float gy = 2.f*(iy/iz)/119.f - 1.f;
    bool ok = (fabsf(gx) <= 1.f) && (fabsf(gy) <= 1.f) && (iz > 0.f);
    float px = ok ? (gx + 1.f)*0.5f*79.f : 0.f;
    float py = ok ? (gy + 1.f)*0.5f*59.f : 0.f;
    float x0f = floorf(px), y0f = floorf(py);
    float fx = px - x0f, fy = py - y0f;
    int idx = (int)y0f*80 + (int)x0f;
    float mf = ok ? 1.f : 0.f;
    den += mf;
    float4 w;
    w.x = (1.f-fx)*(1.f-fy)*mf;
    w.y = fx*(1.f-fy)*mf;
    w.z = (1.f-fx)*fy*mf;
    w.w = fx*fy*mf;
    sidx[(size_t)v*NVOX + n] = (ushort)idx;
    swf[(size_t)v*NVOX + n] = w;
  }
  cnt[n] = den;
}

// ---- merged: f1 conv (169) + f4 LDS conv (720) + f2 conv (675) + scatter (512) ----
__global__ __launch_bounds__(256) void k_heads(
    const ushort* nhwc1, const ushort* wf1, const float* b_f1, ushort* t1,
    const ushort* nhwc2, const ushort* wf2, const float* b_f2, ushort* fcat,
    const ushort* nhwc4, const ushort* wf4, const float* b_f4, ushort* t4,
    const int* coords, const int* stage, int* grid, int* scn, float* coords_out,
    const float* origin, const float* vsz, const float* KR,
    ushort* sidx, float4* swf, float* cnt){
  __shared__ ushort lds[18*18*36];
  int bid = blockIdx.x;
  int tid = threadIdx.x;
  if (bid < 169){ conv_dev<3,5,9,1>(nhwc1, wf1, b_f1, t1, 30, 40, 10800, 80, 80, 0, bid, tid); return; }
  bid -= 169;
  if (bid < 720){ conv_lds_dev<16,2>(nhwc4, wf4, b_f4, t4, 120, 160, 24, 24, nullptr, lds, bid, tid); return; }
  bid -= 720;
  if (bid < 675){ conv_dev<2,3,9,1>(nhwc2, wf2, b_f2, fcat, 60, 80, 43200, 40, 160, 80, bid, tid); return; }
  bid -= 675;
  { int n = bid*256 + tid;
    scatter_dev(coords, stage, grid, scn, coords_out, origin, vsz, KR, sidx, swf, cnt, n); }
}

// ---- merged: resize+pool+padzero (5063 blocks) + slice-split nbr build (2048) ----
__global__ __launch_bounds__(256) void k_respool_nbr(
    const ushort* __restrict__ t1, const ushort* __restrict__ t4, ushort* __restrict__ fc,
    const int* __restrict__ scn, const int* __restrict__ grid,
    int* __restrict__ nbr, unsigned* __restrict__ gmask16){
  __shared__ unsigned m16[4];
  int bid = blockIdx.x;
  int tidx = threadIdx.x;
  if (bid < 5063){
    int tid = bid*256 + tidx;
    if (tid < 864000){
      int c4 = tid % 20;
      int x  = (tid / 20) % 80;
      int y  = (tid / 1600) % 60;
      int v  = tid / 96000;
      int c = c4*4;
      int ky = y >> 1; int y0, y1; float wy0, wy1;
      if ((y & 1) == 0){ y0 = ky-1; y1 = ky; wy0 = 0.25f; wy1 = 0.75f; if (y0 < 0){ y0 = 0; wy0 = 0.f; wy1 = 1.f; } }
      else             { y0 = ky; y1 = ky+1; wy0 = 0.75f; wy1 = 0.25f; if (y1 > 29){ y1 = 29; wy1 = 0.f; wy0 = 1.f; } }
      int kx = x >> 1; int x0, x1; float wx0, wx1;
      if ((x & 1) == 0){ x0 = kx-1; x1 = kx; wx0 = 0.25f; wx1 = 0.75f; if (x0 < 0){ x0 = 0; wx0 = 0.f; wx1 = 1.f; } }
      else             { x0 = kx; x1 = kx+1; wx0 = 0.75f; wx1 = 0.25f; if (x1 > 39){ x1 = 39; wx1 = 0.f; wx0 = 1.f; } }
      float4 a00 = ld4b(t1 + ((size_t)(v*30 + y0)*40 + x0)*80 + c);
      float4 a01 = ld4b(t1 + ((size_t)(v*30 + y0)*40 + x1)*80 + c);
      float4 a10 = ld4b(t1 + ((size_t)(v*30 + y1)*40 + x0)*80 + c);
      float4 a11 = ld4b(t1 + ((size_t)(v*30 + y1)*40 + x1)*80 + c);
      float w00 = wy0*wx0, w01 = wy0*wx1, w10 = wy1*wx0, w11 = wy1*wx1;
      float4 r;
      r.x = w00*a00.x + w01*a01.x + w10*a10.x + w11*a11.x;
      r.y = w00*a00.y + w01*a01.y + w10*a10.y + w11*a11.y;
      r.z = w00*a00.z + w01*a01.z + w10*a10.z + w11*a11.z;
      r.w = w00*a00.w + w01*a01.w + w10*a10.w + w11*a11.w;
      st4b(fc + ((size_t)(v*60 + y)*80 + x)*160 + c, r);
      return;
    }
    int t = tid - 864000;
    if (t >= 432000) return;
    int c4 = t % 10;
    int x  = (t / 10) % 80;
    int y  = (t / 800) % 60;
    int v  = t / 48000;
    if (c4 < 6){
      int c = c4*4;
      const ushort* b0 = t4 + ((size_t)(v*120 + 2*y)*160 + 2*x)*24 + c;
      float4 a = ld4b(b0), b = ld4b(b0 + 24), cc = ld4b(b0 + 160*24), d = ld4b(b0 + 160*24 + 24);
      float4 r;
      r.x = 0.25f*(a.x + b.x + cc.x + d.x);
      r.y = 0.25f*(a.y + b.y + cc.y + d.y);
      r.z = 0.25f*(a.z + b.z + cc.z + d.z);
      r.w = 0.25f*(a.w + b.w + cc.w + d.w);
      st4b(fc + ((size_t)(v*60 + y)*80 + x)*160 + 120 + c, r);
    } else {
      float4 zz = {0.f,0.f,0.f,0.f};
      st4b(fc + ((size_t)(v*60 + y)*80 + x)*160 + 144 + (c4-6)*4, zz);
    }
    return;
  }
  bid -= 5063;
  if (tidx < 4) m16[tidx] = 0;
  __syncthreads();
  int vb = bid*64;
  int lane = tidx & 63;
  int wv = tidx >> 6;
  int n = vb + lane;
  int sx = scn[n*3+0], sy = scn[n*3+1], sz = scn[n*3+2];
  int k0 = wv*7;
  int k1 = min(27, k0 + 7);
  unsigned msk = 0;
  #pragma unroll 1
  for (int k = k0; k < k1; ++k){
    int dx = k/9 - 1, dy = (k/3)%3 - 1, dz = k%3 - 1;
    int nx = sx+dx, ny = sy+dy, nz = sz+dz;
    int idx = -1;
    if (((unsigned)nx < 96u) && ((unsigned)ny < 96u) && ((unsigned)nz < 96u))
      idx = grid[(nx*GS + ny)*GS + nz];
    unsigned long long b = __ballot(idx >= 0);
    unsigned sub = (unsigned)((b >> ((lane >> 4)*16)) & 0xFFFFull);
    if (sub){
      nbr[(size_t)k*NVOX + n] = idx;
      msk |= (1u << k);
    }
  }
  if ((lane & 15) == 0 && msk) atomicOr(&m16[lane >> 4], msk);
  __syncthreads();
  if (tidx < 4) gmask16[(vb >> 4) + tidx] = m16[tidx];
}

// ---- sampling from fp32-weight table + masked mean/var + bn0 ----
__global__ __launch_bounds__(256) void k_sample(
    const ushort* __restrict__ fuse, const ushort* __restrict__ sidx,
    const float4* __restrict__ swf,
    const float* __restrict__ cnt, const float* __restrict__ bn0g,
    const float* __restrict__ bn0b, ushort* __restrict__ F0){
  int tid = blockIdx.x*256 + threadIdx.x;
  int vox = tid >> 3;
  int c4 = tid & 7;
  int c = c4*4;
  float s0=0.f,s1=0.f,s2=0.f,s3=0.f;
  float q0=0.f,q1=0.f,q2=0.f,q3=0.f;
  #pragma unroll
  for (int v = 0; v < VN; ++v){
    int idx = sidx[(size_t)v*NVOX + vox];
    float4 w = swf[(size_t)v*NVOX + vox];
    const ushort* bp = fuse + (size_t)v*153600 + (size_t)idx*32 + c;
    float4 a00 = ld4b(bp);
    float4 a01 = ld4b(bp + 32);
    float4 a10 = ld4b(bp + 2560);
    float4 a11 = ld4b(bp + 2592);
    float g0 = w.x*a00.x + w.y*a01.x + w.z*a10.x + w.w*a11.x;
    float g1 = w.x*a00.y + w.y*a01.y + w.z*a10.y + w.w*a11.y;
    float g2 = w.x*a00.z + w.y*a01.z + w.z*a10.z + w.w*a11.z;
    float g3 = w.x*a00.w + w.y*a01.w + w.z*a10.w + w.w*a11.w;
    s0 += g0; q0 += g0*g0;
    s1 += g1; q1 += g1*g1;
    s2 += g2; q2 += g2*g2;
    s3 += g3; q3 += g3*g3;
  }
  float iden = 1.f/cnt[vox];
  float m0 = s0*iden, m1 = s1*iden, m2 = s2*iden, m3 = s3*iden;
  float4 g = ld4(bn0g + c);
  float4 b = ld4(bn0b + c);
  float4 r;
  r.x = g.x*fmaxf(q0*iden - m0*m0, 0.f)*INVS + b.x;
  r.y = g.y*fmaxf(q1*iden - m1*m1, 0.f)*INVS + b.y;
  r.z = g.z*fmaxf(q2*iden - m2*m2, 0.f)*INVS + b.z;
  r.w = g.w*fmaxf(q3*iden - m3*m3, 0.f)*INVS + b.w;
  st4b(F0 + (size_t)vox*32 + c, r);
}

// ---- subm sparse conv 32->32 via MFMA bf16 ----
// Operand-swapped; MT=2; batch-3 taps; cross-batch pipelined: the NEXT
// batch's 6 nbr loads are issued before the CURRENT batch's gathers/MFMAs,
// hiding one L2 latency hop per batch. Math order identical to R7.
template<int MODE>
__global__ __launch_bounds__(256, 4) void k_subm_mfma(
    const ushort* __restrict__ fin, const ushort* __restrict__ w2,
    const int* __restrict__ nbr, const unsigned* __restrict__ gmask16,
    const float* __restrict__ lng, const float* __restrict__ lnb,
    ushort* __restrict__ fout){
  int lane = threadIdx.x & 63;
  int wave = threadIdx.x >> 6;
  int vb = blockIdx.x*128 + wave*32;
  int m = lane & 15;
  int q = lane >> 4;

  unsigned rem0 = gmask16[(vb >> 4) + 0];
  unsigned rem1 = gmask16[(vb >> 4) + 1];
  unsigned rem = rem0 | rem1;

  f32x4v acc[2][2];
  acc[0][0] = 0.f; acc[0][1] = 0.f; acc[1][0] = 0.f; acc[1][1] = 0.f;
  bf16x8 zc = (short)0;

  // prologue: pop batch 0, issue its nbr loads
  int nk0 = -1, nk1 = -1, nk2 = -1;
  int na0 = -1, nb0 = -1, na1 = -1, nb1 = -1, na2 = -1, nb2 = -1;
  if (rem){
    nk0 = __ffs(rem) - 1; rem &= rem - 1;
    if (rem){ nk1 = __ffs(rem) - 1; rem &= rem - 1; }
    if (rem){ nk2 = __ffs(rem) - 1; rem &= rem - 1; }
    int av0 = nbr[(size_t)nk0*NVOX + vb + m];
    int bv0 = nbr[(size_t)nk0*NVOX + vb + 16 + m];
    na0 = ((rem0 >> nk0) & 1) ? av0 : -1;
    nb0 = ((rem1 >> nk0) & 1) ? bv0 : -1;
    if (nk1 >= 0){
      int av = nbr[(size_t)nk1*NVOX + vb + m];
      int bv = nbr[(size_t)nk1*NVOX + vb + 16 + m];
      na1 = ((rem0 >> nk1) & 1) ? av : -1;
      nb1 = ((rem1 >> nk1) & 1) ? bv : -1;
    }
    if (nk2 >= 0){
      int av = nbr[(size_t)nk2*NVOX + vb + m];
      int bv = nbr[(size_t)nk2*NVOX + vb + 16 + m];
      na2 = ((rem0 >> nk2) & 1) ? av : -1;
      nb2 = ((rem1 >> nk2) & 1) ? bv : -1;
    }
  }
  while (nk0 >= 0){
    int k0 = nk0, k1 = nk1, k2 = nk2;
    int a0 = na0, b0 = nb0, a1 = na1, b1 = nb1, a2 = na2, b2 = nb2;
    // prefetch NEXT batch's nbr indices (overlap with current gathers/MFMAs)
    nk0 = nk1 = nk2 = -1;
    na0 = nb0 = na1 = nb1 = na2 = nb2 = -1;
    if (rem){
      nk0 = __ffs(rem) - 1; rem &= rem - 1;
      if (rem){ nk1 = __ffs(rem) - 1; rem &= rem - 1; }
      if (rem){ nk2 = __ffs(rem) - 1; rem &= rem - 1; }
      int av0 = nbr[(size_t)nk0*NVOX + vb + m];
      int bv0 = nbr[(size_t)nk0*NVOX + vb + 16 + m];
      na0 = ((rem0 >> nk0) & 1) ? av0 : -1;
      nb0 = ((rem1 >> nk0) & 1) ? bv0 : -1;
      if (nk1 >= 0){
        int av = nbr[(size_t)nk1*NVOX + vb + m];
        int bv = nbr[(size_t)nk1*NVOX + vb + 16 + m];
        na1 = ((rem0 >> nk1) & 1) ? av : -1;
        nb1 = ((rem1 >> nk1) & 1) ? bv : -1;
      }
      if (nk2 >= 0){
        int av = nbr[(size_t)nk2*NVOX + vb + m];
        int bv = nbr[(size_t)nk2*NVOX + vb + 16 + m];
        na2 = ((rem0 >> nk2) & 1) ? av : -1;
        nb2 = ((rem1 >> nk2) & 1) ? bv : -1;
      }
    }
    // gathers + weight loads for current batch
    bf16x8 A0, B0, A1 = zc, B1 = zc, A2 = zc, B2 = zc, t;
    bf16x8 w10 = zc, w11 = zc, w20 = zc, w21 = zc;
    t = *(const bf16x8*)(fin + (size_t)(a0 < 0 ? 0 : a0)*32 + q*8); A0 = (a0 < 0) ? zc : t;
    t = *(const bf16x8*)(fin + (size_t)(b0 < 0 ? 0 : b0)*32 + q*8); B0 = (b0 < 0) ? zc : t;
    bf16x8 w00 = *(const bf16x8*)(w2 + (size_t)(k0*32 + m)*32 + q*8);
    bf16x8 w01 = *(const bf16x8*)(w2 + (size_t)(k0*32 + 16 + m)*32 + q*8);
    if (k1 >= 0){
      t = *(const bf16x8*)(fin + (size_t)(a1 < 0 ? 0 : a1)*32 + q*8); A1 = (a1 < 0) ? zc : t;
      t = *(const bf16x8*)(fin + (size_t)(b1 < 0 ? 0 : b1)*32 + q*8); B1 = (b1 < 0) ? zc : t;
      w10 = *(const bf16x8*)(w2 + (size_t)(k1*32 + m)*32 + q*8);
      w11 = *(const bf16x8*)(w2 + (size_t)(k1*32 + 16 + m)*32 + q*8);
    }
    if (k2 >= 0){
      t = *(const bf16x8*)(fin + (size_t)(a2 < 0 ? 0 : a2)*32 + q*8); A2 = (a2 < 0) ? zc : t;
      t = *(const bf16x8*)(fin + (size_t)(b2 < 0 ? 0 : b2)*32 + q*8); B2 = (b2 < 0) ? zc : t;
      w20 = *(const bf16x8*)(w2 + (size_t)(k2*32 + m)*32 + q*8);
      w21 = *(const bf16x8*)(w2 + (size_t)(k2*32 + 16 + m)*32 + q*8);
    }
    // MFMAs
    acc[0][0] = __builtin_amdgcn_mfma_f32_16x16x32_bf16(w00, A0, acc[0][0], 0, 0, 0);
    acc[0][1] = __builtin_amdgcn_mfma_f32_16x16x32_bf16(w01, A0, acc[0][1], 0, 0, 0);
    acc[1][0] = __builtin_amdgcn_mfma_f32_16x16x32_bf16(w00, B0, acc[1][0], 0, 0, 0);
    acc[1][1] = __builtin_amdgcn_mfma_f32_16x16x32_bf16(w01, B0, acc[1][1], 0, 0, 0);
    if (k1 >= 0){
      acc[0][0] = __builtin_amdgcn_mfma_f32_16x16x32_bf16(w10, A1, acc[0][0], 0, 0, 0);
      acc[0][1] = __builtin_amdgcn_mfma_f32_16x16x32_bf16(w11, A1, acc[0][1], 0, 0, 0);
      acc[1][0] = __builtin_amdgcn_mfma_f32_16x16x32_bf16(w10, B1, acc[1][0], 0, 0, 0);
      acc[1][1] = __builtin_amdgcn_mfma_f32_16x16x32_bf16(w11, B1, acc[1][1], 0, 0, 0);
    }
    if (k2 >= 0){
      acc[0][0] = __builtin_amdgcn_mfma_f32_16x16x32_bf16(w20, A2, acc[0][0], 0, 0, 0);
      acc[0][1] = __builtin_amdgcn_mfma_f32_16x16x32_bf16(w21, A2, acc[0][1], 0, 0, 0);
      acc[1][0] = __builtin_amdgcn_mfma_f32_16x16x32_bf16(w20, B2, acc[1][0], 0, 0, 0);
      acc[1][1] = __builtin_amdgcn_mfma_f32_16x16x32_bf16(w21, B2, acc[1][1], 0, 0, 0);
    }
  }

  float4 g0v{0,0,0,0}, g1v{0,0,0,0}, b0v{0,0,0,0}, b1v{0,0,0,0};
  if (MODE == 1){
    g0v = ld4(lng + q*4);  g1v = ld4(lng + 16 + q*4);
    b0v = ld4(lnb + q*4);  b1v = ld4(lnb + 16 + q*4);
  }
  #pragma unroll
  for (int t = 0; t < 2; ++t){
    int vox = vb + t*16 + m;
    float x0[4], x1[4];
    #pragma unroll
    for (int r = 0; r < 4; ++r){
      x0[r] = fmaxf(acc[t][0][r], 0.f);
      x1[r] = fmaxf(acc[t][1][r], 0.f);
    }
    if (MODE == 1){
      uint2 sk0 = *(const uint2*)(fin + (size_t)vox*32 + q*4);
      uint2 sk1 = *(const uint2*)(fin + (size_t)vox*32 + 16 + q*4);
      x0[0] += blo(sk0.x); x0[1] += bhi(sk0.x); x0[2] += blo(sk0.y); x0[3] += bhi(sk0.y);
      x1[0] += blo(sk1.x); x1[1] += bhi(sk1.x); x1[2] += blo(sk1.y); x1[3] += bhi(sk1.y);
      float s = (x0[0]+x0[1]+x0[2]+x0[3]) + (x1[0]+x1[1]+x1[2]+x1[3]);
      s += __shfl_xor(s, 16);
      s += __shfl_xor(s, 32);
      float mean = s * (1.f/32.f);
      float v2 = 0.f;
      #pragma unroll
      for (int r = 0; r < 4; ++r){
        x0[r] -= mean; x1[r] -= mean;
        v2 += x0[r]*x0[r] + x1[r]*x1[r];
      }
      v2 += __shfl_xor(v2, 16);
      v2 += __shfl_xor(v2, 32);
      float rs = 1.f / sqrtf(v2*(1.f/32.f) + 1e-5f);
      x0[0] = x0[0]*rs*g0v.x + b0v.x; x0[1] = x0[1]*rs*g0v.y + b0v.y;
      x0[2] = x0[2]*rs*g0v.z + b0v.z; x0[3] = x0[3]*rs*g0v.w + b0v.w;
      x1[0] = x1[0]*rs*g1v.x + b1v.x; x1[1] = x1[1]*rs*g1v.y + b1v.y;
      x1[2] = x1[2]*rs*g1v.z + b1v.z; x1[3] = x1[3]*rs*g1v.w + b1v.w;
    }
    st4b(fout + (size_t)vox*32 + q*4,      float4{x0[0],x0[1],x0[2],x0[3]});
    st4b(fout + (size_t)vox*32 + 16 + q*4, float4{x1[0],x1[1],x1[2],x1[3]});
  }
}

// ---- final subm 32->1 + bn. 4 threads/voxel (8 ch each), 2-tap batches,
// cross-lane reduce. ----
__global__ __launch_bounds__(256) void k_s4(
    const ushort* __restrict__ fin, const float* __restrict__ w4,
    const int* __restrict__ nbr, const unsigned* __restrict__ gmask16,
    const float* __restrict__ bn4g, const float* __restrict__ bn4b,
    float* __restrict__ occ){
  int tid = blockIdx.x*256 + threadIdx.x;
  int n = tid >> 2;
  int part = tid & 3;
  unsigned rem = gmask16[n >> 4];
  float acc = 0.f;
  while (rem){
    int k0 = __ffs(rem) - 1; rem &= rem - 1;
    int k1 = -1;
    if (rem){ k1 = __ffs(rem) - 1; rem &= rem - 1; }
    int i0 = nbr[(size_t)k0*NVOX + n];
    int i1 = (k1 >= 0) ? nbr[(size_t)k1*NVOX + n] : -1;
    uint4 d0 = *(const uint4*)(fin + (size_t)(i0 < 0 ? 0 : i0)*32 + part*8);
    uint4 d1 = {0,0,0,0};
    if (k1 >= 0) d1 = *(const uint4*)(fin + (size_t)(i1 < 0 ? 0 : i1)*32 + part*8);
    if (i0 >= 0){
      float4 wa = ld4(w4 + k0*32 + part*8);
      float4 wb = ld4(w4 + k0*32 + part*8 + 4);
      acc += blo(d0.x)*wa.x + bhi(d0.x)*wa.y + blo(d0.y)*wa.z + bhi(d0.y)*wa.w
           + blo(d0.z)*wb.x + bhi(d0.z)*wb.y + blo(d0.w)*wb.z + bhi(d0.w)*wb.w;
    }
    if (i1 >= 0){
      float4 wa = ld4(w4 + k1*32 + part*8);
      float4 wb = ld4(w4 + k1*32 + part*8 + 4);
      acc += blo(d1.x)*wa.x + bhi(d1.x)*wa.y + blo(d1.y)*wa.z + bhi(d1.y)*wa.w
           + blo(d1.z)*wb.x + bhi(d1.z)*wb.y + blo(d1.w)*wb.z + bhi(d1.w)*wb.w;
    }
  }
  acc += __shfl_xor(acc, 1, 4);
  acc += __shfl_xor(acc, 2, 4);
  if (part == 0) occ[n] = bn4g[0]*acc*INVS + bn4b[0];
}

extern "C" void kernel_launch(void* const* d_in, const int* in_sizes, int n_in,
                              void* d_out, int out_size, void* d_ws, size_t ws_size,
                              hipStream_t stream){
  const float* feats1 = (const float*)d_in[0];
  const float* feats2 = (const float*)d_in[1];
  const float* feats4 = (const float*)d_in[2];
  const int*   coords = (const int*)d_in[3];
  const float* origin = (const float*)d_in[4];
  const float* vsz    = (const float*)d_in[5];
  const float* KR     = (const float*)d_in[6];
  const float* w_f1 = (const float*)d_in[7];  const float* b_f1 = (const float*)d_in[8];
  const float* w_f2 = (const float*)d_in[9];  const float* b_f2 = (const float*)d_in[10];
  const float* w_f4 = (const float*)d_in[11]; const float* b_f4 = (const float*)d_in[12];
  const float* w_dn = (const float*)d_in[13]; const float* b_dn = (const float*)d_in[14];
  const float* w_p[4] = {(const float*)d_in[15], (const float*)d_in[17],
                         (const float*)d_in[19], (const float*)d_in[21]};
  const float* b_p[4] = {(const float*)d_in[16], (const float*)d_in[18],
                         (const float*)d_in[20], (const float*)d_in[22]};
  const float* bn0g = (const float*)d_in[23]; const float* bn0b = (const float*)d_in[24];
  const float* w_elan = (const float*)d_in[25];
  const float* w_s1 = (const float*)d_in[26]; const float* ln1g = (const float*)d_in[27]; const float* ln1b = (const float*)d_in[28];
  const float* w_s2 = (const float*)d_in[29]; const float* ln2g = (const float*)d_in[30]; const float* ln2b = (const float*)d_in[31];
  const float* w_s3 = (const float*)d_in[32]; const float* ln3g = (const float*)d_in[33]; const float* ln3b = (const float*)d_in[34];
  const float* w_s4 = (const float*)d_in[35]; const float* bn4g = (const float*)d_in[36]; const float* bn4b = (const float*)d_in[37];
  const int* stage  = (const int*)d_in[38];
  float* out = (float*)d_out;
  char* base = (char*)d_ws;

  size_t off = 0;
  auto alloc = [&](size_t bytes)->char*{ char* p = base + off; off += (bytes + 255) & ~(size_t)255; return p; };
  ushort* nhwc1 = (ushort*)alloc((size_t)9*30*40*96*2);
  ushort* nhwc2 = (ushort*)alloc((size_t)9*60*80*64*2);
  ushort* nhwc4 = (ushort*)alloc((size_t)9*120*160*32*2);
  ushort* t1    = (ushort*)alloc((size_t)9*30*40*80*2);
  ushort* t4    = (ushort*)alloc((size_t)9*120*160*24*2);
  ushort* fcat  = (ushort*)alloc((size_t)9*60*80*160*2);
  ushort* A     = (ushort*)alloc((size_t)9*60*80*32*2);
  ushort* B     = (ushort*)alloc((size_t)9*60*80*32*2);
  ushort* Fb0   = (ushort*)alloc((size_t)NVOX*32*2);
  ushort* Fb1   = (ushort*)alloc((size_t)NVOX*32*2);
  int*    nbr   = (int*)alloc((size_t)27*NVOX*4);
  int*    grid  = (int*)alloc((size_t)GS*GS*GS*4);
  int*    scn   = (int*)alloc((size_t)NVOX*3*4);
  unsigned* gmask16 = (unsigned*)alloc((size_t)(NVOX/16)*4);
  ushort* wf1   = (ushort*)alloc(9*3*80*32*2);
  ushort* wf2   = (ushort*)alloc(9*2*48*32*2);
  ushort* wf4   = (ushort*)alloc(9*1*32*32*2);
  ushort* wdn   = (ushort*)alloc(1*5*32*32*2);
  ushort* wp0   = (ushort*)alloc(9*1*32*32*2);
  ushort* wp1   = (ushort*)alloc(9*1*32*32*2);
  ushort* wp2   = (ushort*)alloc(9*1*32*32*2);
  ushort* wp3   = (ushort*)alloc(9*1*32*32*2);
  ushort* w2e   = (ushort*)alloc(27*1024*2);
  ushort* w2s1  = (ushort*)alloc(27*1024*2);
  ushort* w2s2  = (ushort*)alloc(27*1024*2);
  ushort* w2s3  = (ushort*)alloc(27*1024*2);
  ushort* sidx  = (ushort*)alloc((size_t)VN*NVOX*2);     // 2.36 MB
  float4* swf   = (float4*)alloc((size_t)VN*NVOX*16);    // 18.9 MB, fp32 weights

  // 1. mega prep
  k_prep<<<8012,256,0,stream>>>(
      w_f1, w_f2, w_f4, w_dn, w_p[0], w_p[1], w_p[2], w_p[3],
      w_elan, w_s1, w_s2, w_s3,
      wf1, wf2, wf4, wdn, wp0, wp1, wp2, wp3, w2e, w2s1, w2s2, w2s3, grid,
      feats1, feats2, feats4, nhwc1, nhwc2, nhwc4);

  // 2. head convs + scatter (projection once/voxel)
  k_heads<<<169 + 720 + 675 + 512,256,0,stream>>>(
      nhwc1, wf1, b_f1, t1,
      nhwc2, wf2, b_f2, fcat,
      nhwc4, wf4, b_f4, t4,
      coords, stage, grid, scn, out + NVOX,
      origin, vsz, KR, sidx, swf, out + 5*NVOX);

  // 3. respool + nbr build
  k_respool_nbr<<<5063 + 2048,256,0,stream>>>(t1, t4, fcat, scn, grid, nbr, gmask16);

  // 4-6. fused down+p0, p1, fused p2+p3
  k_down_p0<<<675,256,0,stream>>>(fcat, wdn, b_dn, wp0, b_p[0], B);
  k_conv_lds4<<<675,256,0,stream>>>(B, wp1, b_p[1], A, B);
  k_p2_p3<<<675,256,0,stream>>>(A, wp2, b_p[2], wp3, b_p[3], B);

  // 7. sampling -> F0 (table-driven, fp32 weights); fuse result now in B
  k_sample<<<NVOX/32,256,0,stream>>>(B, sidx, swf, out + 5*NVOX, bn0g, bn0b, Fb0);

  // 8-11. sparse conv stack (pipelined batches)
  k_subm_mfma<0><<<NVOX/128,256,0,stream>>>(Fb0, w2e,  nbr, gmask16, nullptr, nullptr, Fb1);
  k_subm_mfma<1><<<NVOX/128,256,0,stream>>>(Fb1, w2s1, nbr, gmask16, ln1g, ln1b, Fb0);
  k_subm_mfma<1><<<NVOX/128,256,0,stream>>>(Fb0, w2s2, nbr, gmask16, ln2g, ln2b, Fb1);
  k_subm_mfma<1><<<NVOX/128,256,0,stream>>>(Fb1, w2s3, nbr, gmask16, ln3g, ln3b, Fb0);

  // 12. final head
  k_s4<<<NVOX/64,256,0,stream>>>(Fb0, w_s4, nbr, gmask16, bn4g, bn4b, out);
}